// Round 20
// 380.636 us; speedup vs baseline: 1.5651x; 1.0287x over previous
//
#include <hip/hip_runtime.h>
#include <math.h>

// ---------------------------------------------------------------------------
// EATN forward. Layout: activations (B, C, N), N = 1024 contiguous.
// B=32, C=128 (144 stem), HEADS=16, HD=8.
// Round 20: swsa_po widened to 512-thread blocks owning 128 q-rows (staging
// and barriers per q-row halved; grid 256); swsa1 output switched to bf16
// ch-major (mean reads bf16). Everything else identical to R19.
// ---------------------------------------------------------------------------

static constexpr int NPIX = 1024;

typedef __attribute__((ext_vector_type(8))) short bf16x8;
typedef __attribute__((ext_vector_type(4))) float f32x4;
typedef __attribute__((ext_vector_type(8))) unsigned short u16x8;
typedef __attribute__((ext_vector_type(4))) unsigned short u16x4;

static __device__ __forceinline__ unsigned short f2bf(float f) {
    unsigned u = __builtin_bit_cast(unsigned, f);
    unsigned r = (u + 0x7fffu + ((u >> 16) & 1u)) >> 16;
    return (unsigned short)r;
}
static __device__ __forceinline__ float bf2f(unsigned short u) {
    unsigned v = ((unsigned)u) << 16;
    return __builtin_bit_cast(float, v);
}

// ------------------------- conv weight prepack (all 4, one launch) ---------
__global__ __launch_bounds__(256) void prepack_convs(
    const float* __restrict__ ssfe_w, const float* __restrict__ cs_w,
    const float* __restrict__ lfe0_w, const float* __restrict__ lfe1_w,
    unsigned short* __restrict__ wssfe, unsigned short* __restrict__ wcs,
    unsigned short* __restrict__ wlfe0, unsigned short* __restrict__ wlfe1)
{
    int idx = blockIdx.x * 256 + threadIdx.x;
    const float* src;
    unsigned short* dst;
    int k, Cout, CIN, CINP;
    if (idx < 207360) {
        src = ssfe_w; dst = wssfe; k = idx; Cout = 144; CIN = 144; CINP = 160;
    } else if (idx < 391680) {
        src = cs_w; dst = wcs; k = idx - 207360; Cout = 128; CIN = 144; CINP = 160;
    } else if (idx < 539136) {
        src = lfe0_w; dst = wlfe0; k = idx - 391680; Cout = 128; CIN = 128; CINP = 128;
    } else if (idx < 686592) {
        src = lfe1_w; dst = wlfe1; k = idx - 539136; Cout = 128; CIN = 128; CINP = 128;
    } else return;
    int ci = k % CINP;
    int rem = k / CINP;
    int co = rem % Cout;
    int tap = rem / Cout;
    float v = (ci < CIN) ? src[((size_t)co * CIN + ci) * 9 + tap] : 0.f;
    dst[k] = f2bf(v);
}

// ------------------------- 1x1 + mlp weights prepack (one launch) ----------
__global__ __launch_bounds__(256) void prepack_lins(
    const float* __restrict__ cc_w, const float* __restrict__ pi0_w,
    const float* __restrict__ pi1_w, const float* __restrict__ po0_w,
    const float* __restrict__ po1_w, const float* __restrict__ w1,
    const float* __restrict__ w2, unsigned short* __restrict__ o)
{
    int idx = blockIdx.x * 256 + threadIdx.x;
    if (idx >= 233472) return;
    float v;
    if (idx < 20480) {
        int ci = idx % 160, co = idx / 160;
        v = (ci < 144) ? cc_w[co * 144 + ci] : 0.f;
    } else if (idx < 53248) {
        v = pi0_w[idx - 20480];
    } else if (idx < 69632) {
        v = pi1_w[idx - 53248];
    } else if (idx < 86016) {
        v = po0_w[idx - 69632];
    } else if (idx < 102400) {
        v = po1_w[idx - 86016];
    } else if (idx < 167936) {
        v = w1[idx - 102400];
    } else {
        v = w2[idx - 167936];
    }
    o[idx] = f2bf(v);
}

// ------------------------- x fp32 (B,144,1024) -> bf16 px-major (B,1024,160)
__global__ __launch_bounds__(256) void cvt_xT_kernel(
    const float* __restrict__ x, unsigned short* __restrict__ xT0)
{
    __shared__ unsigned short T[64 * 168];
    const int tid = threadIdx.x;
    const int b = blockIdx.x;
    const int px0 = blockIdx.y << 6;
    const float* xb = x + ((size_t)b * 144 << 10) + px0;

#pragma unroll 1
    for (int idx = tid; idx < 72 * 64; idx += 256) {
        const int c2 = idx >> 6, px = idx & 63;
        float a = xb[((size_t)(2 * c2) << 10) + px];
        float c = xb[((size_t)(2 * c2 + 1) << 10) + px];
        *(unsigned*)&T[px * 168 + 2 * c2] =
            (unsigned)f2bf(a) | ((unsigned)f2bf(c) << 16);
    }
#pragma unroll 1
    for (int idx = tid; idx < 64 * 8; idx += 256) {
        const int px = idx >> 3, pr = idx & 7;
        *(unsigned*)&T[px * 168 + 144 + pr * 2] = 0u;
    }
    __syncthreads();

#pragma unroll 1
    for (int idx = tid; idx < 64 * 20; idx += 256) {
        const int px = idx / 20;
        const int chunk = idx - px * 20;
        *(u16x8*)(xT0 + ((size_t)((b << 10) + px0 + px)) * 160 + chunk * 8) =
            *(const u16x8*)&T[px * 168 + chunk * 8];
    }
}

// ------------------------- ssfe conv: bf16 in (pitch 160) -> bf16 out ------
__global__ __launch_bounds__(256) void conv3x3_ssfe_kernel(
    const unsigned short* __restrict__ xT,
    const unsigned short* __restrict__ wrep,   // [9][144][160]
    const float* __restrict__ g, const float* __restrict__ bb,
    unsigned short* __restrict__ outT)
{
    constexpr int CINP = 160, PITCH = 168, NCHK = 20;
    __shared__ unsigned short X[130 * PITCH];
    const int tid = threadIdx.x;
    const int b = blockIdx.x, gr = blockIdx.y;
    const int pbase = gr << 6;
    const int gbase = pbase - 33;
    const int wid = tid >> 6, lane = tid & 63;
    const int ll = lane & 15, lq = lane >> 4;
    const unsigned short* xb = xT + ((size_t)b << 10) * CINP;

#pragma unroll 1
    for (int idx = tid; idx < 130 * NCHK; idx += 256) {
        const int row = idx / NCHK;
        const int chunk = idx - row * NCHK;
        const int gp = gbase + row;
        u16x8 v = {};
        if (gp >= 0 && gp < 1024)
            v = *(const u16x8*)(xb + (size_t)gp * CINP + chunk * 8);
        *(u16x8*)&X[row * PITCH + chunk * 8] = v;
    }
    __syncthreads();

    if (wid == 3) {
#pragma unroll
        for (int j = 0; j < 4; ++j) {
            const int px = pbase + j * 16 + ll;
            u16x4 z = {};
            *(u16x4*)(outT + ((size_t)((b << 10) + px)) * 160 + 144 + lq * 4) = z;
        }
        return;
    }

    const int co0w = wid * 48;
    f32x4 acc[3][4];
#pragma unroll
    for (int i = 0; i < 3; ++i)
#pragma unroll
        for (int j = 0; j < 4; ++j)
#pragma unroll
            for (int r = 0; r < 4; ++r) acc[i][j][r] = 0.f;

#pragma unroll
    for (int tap = 0; tap < 9; ++tap) {
        const int soff = (tap / 3) * 32 + (tap % 3);
        const int dx = tap % 3;
#pragma unroll
        for (int kc = 0; kc < CINP / 32; ++kc) {
            bf16x8 bfv[4];
#pragma unroll
            for (int j = 0; j < 4; ++j) {
                const int p = j * 16 + ll;
                bf16x8 v = *(const bf16x8*)&X[(p + soff) * PITCH + kc * 32 + lq * 8];
                const bool zed = (dx == 0 && (j & 1) == 0 && ll == 0) ||
                                 (dx == 2 && (j & 1) == 1 && ll == 15);
                if (zed) { bf16x8 z = {}; v = z; }
                bfv[j] = v;
            }
            const unsigned short* wb =
                wrep + ((size_t)tap * 144 + co0w) * CINP + kc * 32 + lq * 8;
#pragma unroll
            for (int i = 0; i < 3; ++i) {
                bf16x8 af = *(const bf16x8*)(wb + (size_t)(i * 16 + ll) * CINP);
#pragma unroll
                for (int j = 0; j < 4; ++j)
                    acc[i][j] = __builtin_amdgcn_mfma_f32_16x16x32_bf16(
                        af, bfv[j], acc[i][j], 0, 0, 0);
            }
        }
    }

#pragma unroll
    for (int i = 0; i < 3; ++i) {
        const int cob = co0w + i * 16 + lq * 4;
        float gv[4], bv[4];
#pragma unroll
        for (int r = 0; r < 4; ++r) { gv[r] = g[cob + r]; bv[r] = bb[cob + r]; }
#pragma unroll
        for (int j = 0; j < 4; ++j) {
            const int px = pbase + j * 16 + ll;
            u16x4 tp;
#pragma unroll
            for (int r = 0; r < 4; ++r)
                tp[r] = f2bf(fmaxf(acc[i][j][r] * gv[r] + bv[r], 0.f));
            *(u16x4*)(outT + ((size_t)((b << 10) + px)) * 160 + cob) = tp;
        }
    }
}

// ------------------------- conv3x3 bf16->bf16, 64px x 128co blocks ---------
template <int CINP>
__global__ __launch_bounds__(256) void conv3x3_lds_kernel(
    const unsigned short* __restrict__ xT,
    const unsigned short* __restrict__ wrep,
    const float* __restrict__ g, const float* __restrict__ bb,
    const unsigned short* __restrict__ resT,
    unsigned short* __restrict__ outT, int Cout)
{
    constexpr int PITCH = CINP + 8;
    constexpr int NCHK = CINP / 8;
    __shared__ unsigned short X[130 * PITCH];
    const int tid = threadIdx.x;
    const int b = blockIdx.x, gr = blockIdx.y;
    const int pbase = gr << 6;
    const int gbase = pbase - 33;
    const int wid = tid >> 6, lane = tid & 63;
    const int ll = lane & 15, lq = lane >> 4;
    const int co0w = wid << 5;
    const unsigned short* xb = xT + ((size_t)b << 10) * CINP;

#pragma unroll 1
    for (int idx = tid; idx < 130 * NCHK; idx += 256) {
        const int row = idx / NCHK;
        const int chunk = idx - row * NCHK;
        const int gp = gbase + row;
        u16x8 v = {};
        if (gp >= 0 && gp < 1024)
            v = *(const u16x8*)(xb + (size_t)gp * CINP + chunk * 8);
        *(u16x8*)&X[row * PITCH + chunk * 8] = v;
    }
    __syncthreads();

    f32x4 acc[2][4];
#pragma unroll
    for (int i = 0; i < 2; ++i)
#pragma unroll
        for (int j = 0; j < 4; ++j)
#pragma unroll
            for (int r = 0; r < 4; ++r) acc[i][j][r] = 0.f;

#pragma unroll
    for (int tap = 0; tap < 9; ++tap) {
        const int soff = (tap / 3) * 32 + (tap % 3);
        const int dx = tap % 3;
#pragma unroll
        for (int kc = 0; kc < CINP / 32; ++kc) {
            bf16x8 bfv[4];
#pragma unroll
            for (int j = 0; j < 4; ++j) {
                const int p = j * 16 + ll;
                bf16x8 v = *(const bf16x8*)&X[(p + soff) * PITCH + kc * 32 + lq * 8];
                const bool zed = (dx == 0 && (j & 1) == 0 && ll == 0) ||
                                 (dx == 2 && (j & 1) == 1 && ll == 15);
                if (zed) { bf16x8 z = {}; v = z; }
                bfv[j] = v;
            }
            const unsigned short* wb =
                wrep + ((size_t)tap * Cout + co0w) * CINP + kc * 32 + lq * 8;
#pragma unroll
            for (int i = 0; i < 2; ++i) {
                bf16x8 af = *(const bf16x8*)(wb + (size_t)(i * 16 + ll) * CINP);
#pragma unroll
                for (int j = 0; j < 4; ++j)
                    acc[i][j] = __builtin_amdgcn_mfma_f32_16x16x32_bf16(
                        af, bfv[j], acc[i][j], 0, 0, 0);
            }
        }
    }

#pragma unroll
    for (int i = 0; i < 2; ++i) {
        const int cob = co0w + i * 16 + lq * 4;
        float gv[4], bv[4];
#pragma unroll
        for (int r = 0; r < 4; ++r) { gv[r] = g[cob + r]; bv[r] = bb[cob + r]; }
#pragma unroll
        for (int j = 0; j < 4; ++j) {
            const int px = pbase + j * 16 + ll;
            const size_t rowT = ((size_t)((b << 10) + px)) << 7;
            u16x4 rv = {};
            if (resT) rv = *(const u16x4*)(resT + rowT + cob);
            u16x4 tp;
#pragma unroll
            for (int r = 0; r < 4; ++r) {
                float v = fmaxf(acc[i][j][r] * gv[r] + bv[r], 0.f);
                if (resT) v += bf2f(rv[r]);
                tp[r] = f2bf(v);
            }
            *(u16x4*)(outT + rowT + cob) = tp;
        }
    }
}

// ------------------------- conv3x3 (CIN=128) + fused pi 1x1 ---------------
template <int PI_COUT>
__global__ __launch_bounds__(256) void conv3x3_pi_kernel(
    const unsigned short* __restrict__ xT,
    const unsigned short* __restrict__ wrep,
    const float* __restrict__ g, const float* __restrict__ bb,
    const unsigned short* __restrict__ resT,
    unsigned short* __restrict__ outT,
    const unsigned short* __restrict__ wpi, const float* __restrict__ pi_b,
    const float* __restrict__ pig, const float* __restrict__ pibb,
    unsigned short* __restrict__ qTout, unsigned short* __restrict__ vout)
{
    constexpr int CINP = 128, PITCH = 136, NCHK = 16;
    __shared__ unsigned short X[130 * PITCH];   // head reused as Y[64][128]
    unsigned short* Y = X;
    const int tid = threadIdx.x;
    const int b = blockIdx.x, gr = blockIdx.y;
    const int pbase = gr << 6;
    const int gbase = pbase - 33;
    const int wid = tid >> 6, lane = tid & 63;
    const int ll = lane & 15, lq = lane >> 4;
    const int co0w = wid << 5;
    const unsigned short* xb = xT + ((size_t)b << 10) * CINP;

#pragma unroll 1
    for (int idx = tid; idx < 130 * NCHK; idx += 256) {
        const int row = idx / NCHK;
        const int chunk = idx - row * NCHK;
        const int gp = gbase + row;
        u16x8 v = {};
        if (gp >= 0 && gp < 1024)
            v = *(const u16x8*)(xb + (size_t)gp * CINP + chunk * 8);
        *(u16x8*)&X[row * PITCH + chunk * 8] = v;
    }
    __syncthreads();

    f32x4 acc[2][4];
#pragma unroll
    for (int i = 0; i < 2; ++i)
#pragma unroll
        for (int j = 0; j < 4; ++j)
#pragma unroll
            for (int r = 0; r < 4; ++r) acc[i][j][r] = 0.f;

#pragma unroll
    for (int tap = 0; tap < 9; ++tap) {
        const int soff = (tap / 3) * 32 + (tap % 3);
        const int dx = tap % 3;
#pragma unroll
        for (int kc = 0; kc < CINP / 32; ++kc) {
            bf16x8 bfv[4];
#pragma unroll
            for (int j = 0; j < 4; ++j) {
                const int p = j * 16 + ll;
                bf16x8 v = *(const bf16x8*)&X[(p + soff) * PITCH + kc * 32 + lq * 8];
                const bool zed = (dx == 0 && (j & 1) == 0 && ll == 0) ||
                                 (dx == 2 && (j & 1) == 1 && ll == 15);
                if (zed) { bf16x8 z = {}; v = z; }
                bfv[j] = v;
            }
            const unsigned short* wb =
                wrep + ((size_t)tap * 128 + co0w) * CINP + kc * 32 + lq * 8;
#pragma unroll
            for (int i = 0; i < 2; ++i) {
                bf16x8 af = *(const bf16x8*)(wb + (size_t)(i * 16 + ll) * CINP);
#pragma unroll
                for (int j = 0; j < 4; ++j)
                    acc[i][j] = __builtin_amdgcn_mfma_f32_16x16x32_bf16(
                        af, bfv[j], acc[i][j], 0, 0, 0);
            }
        }
    }
    __syncthreads();   // all waves done reading X; safe to overwrite with Y

    // conv epilogue: write outT (global) and Y (LDS, swizzled)
#pragma unroll
    for (int i = 0; i < 2; ++i) {
        const int cob = co0w + i * 16 + lq * 4;
        float gv[4], bv[4];
#pragma unroll
        for (int r = 0; r < 4; ++r) { gv[r] = g[cob + r]; bv[r] = bb[cob + r]; }
#pragma unroll
        for (int j = 0; j < 4; ++j) {
            const int pxl = j * 16 + ll;
            const int px = pbase + pxl;
            const size_t rowT = ((size_t)((b << 10) + px)) << 7;
            u16x4 rv = *(const u16x4*)(resT + rowT + cob);
            u16x4 tp;
#pragma unroll
            for (int r = 0; r < 4; ++r) {
                float v = fmaxf(acc[i][j][r] * gv[r] + bv[r], 0.f) + bf2f(rv[r]);
                tp[r] = f2bf(v);
            }
            *(u16x4*)(outT + rowT + cob) = tp;
            const int sw4 = ((pxl >> 2) & 3) << 4;
            *(u16x4*)&Y[pxl * 128 + (cob ^ sw4)] = tp;
        }
    }
    __syncthreads();

    // pi GEMM: out = wpi @ Y
    constexpr int NI = PI_COUT / 64;           // 4 (256-out) or 2 (128-out)
    const int co0p = wid * (PI_COUT / 4);      // 64*wid or 32*wid
    f32x4 acc2[NI][4];
#pragma unroll
    for (int i = 0; i < NI; ++i)
#pragma unroll
        for (int j = 0; j < 4; ++j)
#pragma unroll
            for (int r = 0; r < 4; ++r) acc2[i][j][r] = 0.f;

#pragma unroll
    for (int kk = 0; kk < 4; ++kk) {
        bf16x8 af[NI], bfv[4];
#pragma unroll
        for (int i = 0; i < NI; ++i)
            af[i] = *(const bf16x8*)(wpi + (size_t)(co0p + i * 16 + ll) * 128 + kk * 32 + lq * 8);
#pragma unroll
        for (int j = 0; j < 4; ++j) {
            const int pxl = j * 16 + ll;
            const int sw4 = ((pxl >> 2) & 3) << 4;
            bfv[j] = *(const bf16x8*)&Y[pxl * 128 + ((kk * 32 + lq * 8) ^ sw4)];
        }
#pragma unroll
        for (int i = 0; i < NI; ++i)
#pragma unroll
            for (int j = 0; j < 4; ++j)
                acc2[i][j] = __builtin_amdgcn_mfma_f32_16x16x32_bf16(af[i], bfv[j], acc2[i][j], 0, 0, 0);
    }

#pragma unroll
    for (int i = 0; i < NI; ++i) {
        const int cob = co0p + i * 16 + lq * 4;
        float b0v[4], gv[4], bv[4];
#pragma unroll
        for (int r = 0; r < 4; ++r) {
            b0v[r] = pi_b[cob + r];
            gv[r] = pig[cob + r];
            bv[r] = pibb[cob + r];
        }
#pragma unroll
        for (int j = 0; j < 4; ++j) {
            const int px = pbase + j * 16 + ll;
            float vv[4];
#pragma unroll
            for (int r = 0; r < 4; ++r)
                vv[r] = (acc2[i][j][r] + b0v[r]) * gv[r] + bv[r];
            if (PI_COUT == 256 && cob < 128) {
                u16x4 tp;
#pragma unroll
                for (int r = 0; r < 4; ++r) tp[r] = f2bf(vv[r]);
                *(u16x4*)(qTout + (((size_t)((b << 10) + px)) << 7) + cob) = tp;
            } else {
                const int cv = (PI_COUT == 256) ? cob - 128 : cob;
#pragma unroll
                for (int r = 0; r < 4; ++r)
                    vout[((size_t)(b * 128 + cv + r) << 10) + px] = f2bf(vv[r]);
            }
        }
    }
}

// ------------------------- cc 1x1 (160->128) + fused LayerNorm -------------
__global__ __launch_bounds__(256) void cc_ln_kernel(
    const unsigned short* __restrict__ xT, const unsigned short* __restrict__ wbf,
    const float* __restrict__ g, const float* __restrict__ bb,
    const float* __restrict__ ln_g, const float* __restrict__ ln_b,
    float* __restrict__ t, unsigned short* __restrict__ out_bf,
    unsigned short* __restrict__ outT)
{
    __shared__ float Ssum[4][64];
    __shared__ float Ssq[4][64];
    const int tid = threadIdx.x;
    const int b = blockIdx.x;
    const int n0 = blockIdx.y << 6;
    const int wid = tid >> 6, lane = tid & 63;
    const int ll = lane & 15, lq = lane >> 4;
    const unsigned short* xb = xT + (size_t)((b << 10) + n0) * 160;

    f32x4 acc[2][4];
#pragma unroll
    for (int i = 0; i < 2; ++i)
#pragma unroll
        for (int j = 0; j < 4; ++j)
#pragma unroll
            for (int r = 0; r < 4; ++r) acc[i][j][r] = 0.f;

#pragma unroll
    for (int kk = 0; kk < 5; ++kk) {
        bf16x8 af[2], bfv[4];
#pragma unroll
        for (int i = 0; i < 2; ++i)
            af[i] = *(const bf16x8*)(wbf + (size_t)(wid * 32 + i * 16 + ll) * 160 + kk * 32 + lq * 8);
#pragma unroll
        for (int j = 0; j < 4; ++j)
            bfv[j] = *(const bf16x8*)(xb + (size_t)(j * 16 + ll) * 160 + kk * 32 + lq * 8);
#pragma unroll
        for (int i = 0; i < 2; ++i)
#pragma unroll
            for (int j = 0; j < 4; ++j)
                acc[i][j] = __builtin_amdgcn_mfma_f32_16x16x32_bf16(af[i], bfv[j], acc[i][j], 0, 0, 0);
    }

    float vv[2][4][4];
    float sj[4] = {0.f, 0.f, 0.f, 0.f};
    float sqj[4] = {0.f, 0.f, 0.f, 0.f};
#pragma unroll
    for (int i = 0; i < 2; ++i) {
        const int cob = wid * 32 + i * 16 + lq * 4;
        float gv[4], bv[4];
#pragma unroll
        for (int r = 0; r < 4; ++r) { gv[r] = g[cob + r]; bv[r] = bb[cob + r]; }
#pragma unroll
        for (int j = 0; j < 4; ++j) {
            const int px = n0 + j * 16 + ll;
#pragma unroll
            for (int r = 0; r < 4; ++r) {
                const float val = fmaxf(acc[i][j][r] * gv[r] + bv[r], 0.f);
                vv[i][j][r] = val;
                t[((size_t)((b << 7) + cob + r) << 10) + px] = val;
                sj[j] += val;
                sqj[j] += val * val;
            }
        }
    }
#pragma unroll
    for (int j = 0; j < 4; ++j) {
        sj[j] += __shfl_xor(sj[j], 16);
        sj[j] += __shfl_xor(sj[j], 32);
        sqj[j] += __shfl_xor(sqj[j], 16);
        sqj[j] += __shfl_xor(sqj[j], 32);
    }
    if (lq == 0) {
#pragma unroll
        for (int j = 0; j < 4; ++j) {
            Ssum[wid][j * 16 + ll] = sj[j];
            Ssq[wid][j * 16 + ll] = sqj[j];
        }
    }
    __syncthreads();

    float mu[4], rst[4];
#pragma unroll
    for (int j = 0; j < 4; ++j) {
        const int p = j * 16 + ll;
        const float s = Ssum[0][p] + Ssum[1][p] + Ssum[2][p] + Ssum[3][p];
        const float sq = Ssq[0][p] + Ssq[1][p] + Ssq[2][p] + Ssq[3][p];
        mu[j] = s * 0.0078125f;
        rst[j] = rsqrtf(sq * 0.0078125f - mu[j] * mu[j] + 1e-5f);
    }

#pragma unroll
    for (int i = 0; i < 2; ++i) {
        const int cob = wid * 32 + i * 16 + lq * 4;
        float lg[4], lb[4];
#pragma unroll
        for (int r = 0; r < 4; ++r) { lg[r] = ln_g[cob + r]; lb[r] = ln_b[cob + r]; }
#pragma unroll
        for (int j = 0; j < 4; ++j) {
            const int px = n0 + j * 16 + ll;
            u16x4 tp;
#pragma unroll
            for (int r = 0; r < 4; ++r) {
                const float y = (vv[i][j][r] - mu[j]) * rst[j] * lg[r] + lb[r];
                const unsigned short h = f2bf(y);
                out_bf[((size_t)((b << 7) + cob + r) << 10) + px] = h;
                tp[r] = h;
            }
            *(u16x4*)(outT + (((size_t)((b << 10) + px)) << 7) + cob) = tp;
        }
    }
}

// ------------------------- Gram matrix + row sums (merged launch) ----------
__global__ __launch_bounds__(256) void gram_sums_kernel(
    const unsigned short* __restrict__ Xbf, float* __restrict__ G,
    float* __restrict__ S)
{
    __shared__ unsigned short Xs[128 * 128];
    const int tid = threadIdx.x;
    if (blockIdx.x >= 128) {
        const int b = blockIdx.x - 128;
        const int ch = tid >> 1, half = tid & 1;
        const unsigned short* p = Xbf + ((size_t)b << 17) + ((size_t)ch << 10) + half * 512;
        float s = 0.f;
#pragma unroll 4
        for (int i = 0; i < 64; ++i) {
            u16x8 v = *(const u16x8*)(p + i * 8);
#pragma unroll
            for (int e = 0; e < 8; ++e) s += bf2f(v[e]);
        }
        s += __shfl_xor(s, 1);
        if (half == 0) S[(b << 7) + ch] = s;
        return;
    }
    const int b = blockIdx.x >> 2;
    const int rg = blockIdx.x & 3;
    const int wid = tid >> 6, lane = tid & 63;
    const int lq = lane >> 4, ll = lane & 15;
    const unsigned short* Xb = Xbf + ((size_t)b << 17);

    f32x4 acc[2][2];
#pragma unroll
    for (int mi = 0; mi < 2; ++mi)
#pragma unroll
        for (int ci = 0; ci < 2; ++ci)
#pragma unroll
            for (int r = 0; r < 4; ++r) acc[mi][ci][r] = 0.f;

#pragma unroll 1
    for (int nt = 0; nt < 8; ++nt) {
        const int n0 = nt << 7;
#pragma unroll
        for (int p = 0; p < 8; ++p) {
            const int ch = (p << 4) + (tid >> 4);
            const int seg = (tid & 15) << 3;
            *(u16x8*)&Xs[ch * 128 + (seg ^ ((ch & 7) << 3))] =
                *(const u16x8*)(Xb + ((size_t)ch << 10) + n0 + seg);
        }
        __syncthreads();
#pragma unroll
        for (int ks = 0; ks < 4; ++ks) {
            bf16x8 af[2], bf_[2];
#pragma unroll
            for (int mi = 0; mi < 2; ++mi) {
                const int ar = (rg << 5) + mi * 16 + ll;
                af[mi] = *(const bf16x8*)&Xs[ar * 128 + ((ks * 32 + lq * 8) ^ ((ar & 7) << 3))];
            }
#pragma unroll
            for (int ci = 0; ci < 2; ++ci) {
                const int br = (wid << 5) + ci * 16 + ll;
                bf_[ci] = *(const bf16x8*)&Xs[br * 128 + ((ks * 32 + lq * 8) ^ ((br & 7) << 3))];
            }
#pragma unroll
            for (int mi = 0; mi < 2; ++mi)
#pragma unroll
                for (int ci = 0; ci < 2; ++ci)
                    acc[mi][ci] = __builtin_amdgcn_mfma_f32_16x16x32_bf16(
                        af[mi], bf_[ci], acc[mi][ci], 0, 0, 0);
        }
        __syncthreads();
    }
    float* Gb = G + ((size_t)b << 14);
#pragma unroll
    for (int mi = 0; mi < 2; ++mi)
#pragma unroll
        for (int ci = 0; ci < 2; ++ci)
#pragma unroll
            for (int r = 0; r < 4; ++r) {
                const int row = (rg << 5) + mi * 16 + lq * 4 + r;
                const int col = (wid << 5) + ci * 16 + ll;
                Gb[row * 128 + col] = acc[mi][ci][r];
            }
}

// ------------------------- GISSA stage-1 matrices (bf16 M1) ----------------
__global__ __launch_bounds__(64) void mats1_kernel(
    const float* __restrict__ G, const float* __restrict__ S,
    const float* __restrict__ qkv_w, const float* __restrict__ qkv_b,
    const float* __restrict__ g, const float* __restrict__ bb,
    unsigned short* __restrict__ M1, float* __restrict__ c1)
{
    const int lane = threadIdx.x;
    const int b = blockIdx.x >> 4, h = blockIdx.x & 15;
    const float* Gb = G + ((size_t)b << 14);
    const float* Sb = S + (b << 7);
    const int d = lane >> 3, e = lane & 7;
    const int qch = h * 8 + d, kch = 128 + h * 8 + e;
    const int qoff = (qch / 24) * 8, koff = (kch / 24) * 8;
    float wq[8], wk[8];
#pragma unroll
    for (int i = 0; i < 8; ++i) {
        wq[i] = qkv_w[qch * 8 + i];
        wk[i] = qkv_w[kch * 8 + i];
    }
    float s = 0.f;
#pragma unroll
    for (int i = 0; i < 8; ++i) {
        float gu = 0.f;
#pragma unroll
        for (int j = 0; j < 8; ++j) gu += Gb[(qoff + i) * 128 + koff + j] * wk[j];
        s += wq[i] * gu;
    }
    const float bq = qkv_b[qch], bk = qkv_b[kch];
    float swk = 0.f, swq = 0.f;
#pragma unroll
    for (int j = 0; j < 8; ++j) { swk += wk[j] * Sb[koff + j]; swq += wq[j] * Sb[qoff + j]; }
    s += bq * swk + bk * swq + 1024.f * bq * bk;
    s *= 0.35355339059327373f;
    float a = (s > 0.f) ? sqrtf(s + 1e-5f) : ((s < 0.f) ? -sqrtf(1e-5f - s) : 0.f);
    float mx = a;
    mx = fmaxf(mx, __shfl_xor(mx, 1));
    mx = fmaxf(mx, __shfl_xor(mx, 2));
    mx = fmaxf(mx, __shfl_xor(mx, 4));
    float p = __expf(a - mx);
    float den = p;
    den += __shfl_xor(den, 1);
    den += __shfl_xor(den, 2);
    den += __shfl_xor(den, 4);
    const float A = p / den;

    const int l = e;
    const int cp = d * 16 + h;
    float row[16];
#pragma unroll
    for (int j = 0; j < 16; ++j) row[j] = 0.f;
    float cacc = 0.f;
#pragma unroll
    for (int e2 = 0; e2 < 8; ++e2) {
        const float Ae = __shfl(A, d * 8 + e2);
        const int vch = 256 + h * 8 + e2;
        const int voff = (vch / 24) * 8;
        cacc += Ae * qkv_b[vch];
        if ((voff >> 4) == l) {
            const int base = voff & 15;
#pragma unroll
            for (int j = 0; j < 8; ++j) row[base + j] += Ae * qkv_w[vch * 8 + j];
        }
    }
    const int idc = h * 8 + d;
    if ((idc >> 4) == l) row[idc & 15] += 1.f;
    const float gg = g[cp];
    unsigned short* mrow = M1 + ((size_t)b << 14) + cp * 128 + l * 16;
#pragma unroll
    for (int j = 0; j < 16; ++j) mrow[j] = f2bf(gg * row[j]);
    if (l == 0) c1[(b << 7) + cp] = gg * cacc + bb[cp];
}

// ------------------------- GISSA stage-2 matrices (bf16 M2) ----------------
__global__ __launch_bounds__(256) void mats2_kernel(
    const float* __restrict__ G, const float* __restrict__ S,
    const float* __restrict__ qkv2_w, const float* __restrict__ qkv2_b,
    unsigned short* __restrict__ M2, float* __restrict__ c2)
{
    const int tid = threadIdx.x;
    const int b = blockIdx.x >> 3, d = blockIdx.x & 7;
    const float* Gb = G + ((size_t)b << 14);
    const float* Sb = S + (b << 7);
    const int h = tid >> 4, gq = tid & 15;
    const int q2ch = d * 16 + h, k2ch = 128 + d * 16 + gq;
    const int qoff = (q2ch / 48) * 16, koff = (k2ch / 48) * 16;
    float wq[16], wk[16];
#pragma unroll
    for (int i = 0; i < 16; ++i) {
        wq[i] = qkv2_w[q2ch * 16 + i];
        wk[i] = qkv2_w[k2ch * 16 + i];
    }
    float s = 0.f;
#pragma unroll
    for (int i = 0; i < 16; ++i) {
        float gu = 0.f;
#pragma unroll
        for (int j = 0; j < 16; ++j) gu += Gb[(qoff + i) * 128 + koff + j] * wk[j];
        s += wq[i] * gu;
    }
    const float bq = qkv2_b[q2ch], bk = qkv2_b[k2ch];
    float swk = 0.f, swq = 0.f;
#pragma unroll
    for (int j = 0; j < 16; ++j) { swk += wk[j] * Sb[koff + j]; swq += wq[j] * Sb[qoff + j]; }
    s += bq * swk + bk * swq + 1024.f * bq * bk;
    s *= 0.25f;
    float a = (s > 0.f) ? sqrtf(s + 1e-5f) : ((s < 0.f) ? -sqrtf(1e-5f - s) : 0.f);
    float mx = a;
    mx = fmaxf(mx, __shfl_xor(mx, 1));
    mx = fmaxf(mx, __shfl_xor(mx, 2));
    mx = fmaxf(mx, __shfl_xor(mx, 4));
    mx = fmaxf(mx, __shfl_xor(mx, 8));
    float p = __expf(a - mx);
    float den = p;
    den += __shfl_xor(den, 1);
    den += __shfl_xor(den, 2);
    den += __shfl_xor(den, 4);
    den += __shfl_xor(den, 8);
    const float A2 = p / den;

    const int l = gq;
    float row[8];
#pragma unroll
    for (int j = 0; j < 8; ++j) row[j] = 0.f;
    float cacc = 0.f;
#pragma unroll
    for (int g2 = 0; g2 < 16; ++g2) {
        const float Ag = __shfl(A2, (tid & 48) + g2);
        const int v2ch = 256 + d * 16 + g2;
        const int voff = (v2ch / 48) * 16;
        cacc += Ag * qkv2_b[v2ch];
        if ((l >> 1) == (voff >> 4)) {
            const int base = (l & 1) * 8;
#pragma unroll
            for (int j = 0; j < 8; ++j) row[j] += Ag * qkv2_w[v2ch * 16 + base + j];
        }
    }
    const int c = h * 8 + d;
    unsigned short* mrow = M2 + ((size_t)b << 14) + c * 128 + l * 8;
#pragma unroll
    for (int j = 0; j < 8; ++j) mrow[j] = f2bf(row[j]);
    if (l == 0) c2[(b << 7) + c] = cacc;
}

// ------------------------- apply1: y = M1 x + c1 (MFMA) --------------------
__global__ __launch_bounds__(256) void apply1_mfma_kernel(
    const unsigned short* __restrict__ curT, const unsigned short* __restrict__ M1bf,
    const float* __restrict__ c1, unsigned short* __restrict__ ybufb,
    unsigned short* __restrict__ yrbf, unsigned short* __restrict__ yrT)
{
    const int tid = threadIdx.x;
    const int b = blockIdx.x >> 3;
    const int n0 = (blockIdx.x & 7) << 7;
    const int wid = tid >> 6, lane = tid & 63;
    const int wr = wid >> 1, wc = wid & 1;
    const int ll = lane & 15, lq = lane >> 4;
    const unsigned short* Mb = M1bf + ((size_t)b << 14);
    const unsigned short* xb = curT + (((size_t)b << 10) + n0 + wc * 64) * 128;

    f32x4 acc[4][4];
#pragma unroll
    for (int i = 0; i < 4; ++i)
#pragma unroll
        for (int j = 0; j < 4; ++j)
#pragma unroll
            for (int r = 0; r < 4; ++r) acc[i][j][r] = 0.f;

#pragma unroll
    for (int kk = 0; kk < 4; ++kk) {
        bf16x8 af[4], bfv[4];
#pragma unroll
        for (int i = 0; i < 4; ++i)
            af[i] = *(const bf16x8*)(Mb + (size_t)(wr * 64 + i * 16 + ll) * 128 + kk * 32 + lq * 8);
#pragma unroll
        for (int j = 0; j < 4; ++j)
            bfv[j] = *(const bf16x8*)(xb + (size_t)(j * 16 + ll) * 128 + kk * 32 + lq * 8);
#pragma unroll
        for (int i = 0; i < 4; ++i)
#pragma unroll
            for (int j = 0; j < 4; ++j)
                acc[i][j] = __builtin_amdgcn_mfma_f32_16x16x32_bf16(af[i], bfv[j], acc[i][j], 0, 0, 0);
    }

#pragma unroll
    for (int i = 0; i < 4; ++i) {
        const int cob = wr * 64 + i * 16 + lq * 4;
        float c1v[4];
#pragma unroll
        for (int r = 0; r < 4; ++r) c1v[r] = c1[(b << 7) + cob + r];
#pragma unroll
        for (int j = 0; j < 4; ++j) {
            const int px = n0 + wc * 64 + j * 16 + ll;
            u16x4 tp;
#pragma unroll
            for (int r = 0; r < 4; ++r) {
                const int co = cob + r;
                const float v = acc[i][j][r] + c1v[r];
                const size_t oi = ((size_t)(b * 128 + co) << 10) + px;
                ybufb[oi] = f2bf(v);
                const unsigned short h = f2bf(fmaxf(v, 0.f));
                yrbf[oi] = h;
                tp[r] = h;
            }
            *(u16x4*)(yrT + (((size_t)b << 10) + px) * 128 + cob) = tp;
        }
    }
}

// ------------------------- apply2: t += M2 relu(y) + c2 + y (MFMA) ---------
__global__ __launch_bounds__(256) void apply2_mfma_kernel(
    const unsigned short* __restrict__ yrT, const unsigned short* __restrict__ M2bf,
    const float* __restrict__ c2, const unsigned short* __restrict__ ybufb,
    float* __restrict__ t)
{
    const int tid = threadIdx.x;
    const int b = blockIdx.x >> 3;
    const int n0 = (blockIdx.x & 7) << 7;
    const int wid = tid >> 6, lane = tid & 63;
    const int wr = wid >> 1, wc = wid & 1;
    const int ll = lane & 15, lq = lane >> 4;
    const unsigned short* Mb = M2bf + ((size_t)b << 14);
    const unsigned short* xb = yrT + (((size_t)b << 10) + n0 + wc * 64) * 128;

    f32x4 acc[4][4];
#pragma unroll
    for (int i = 0; i < 4; ++i)
#pragma unroll
        for (int j = 0; j < 4; ++j)
#pragma unroll
            for (int r = 0; r < 4; ++r) acc[i][j][r] = 0.f;

#pragma unroll
    for (int kk = 0; kk < 4; ++kk) {
        bf16x8 af[4], bfv[4];
#pragma unroll
        for (int i = 0; i < 4; ++i)
            af[i] = *(const bf16x8*)(Mb + (size_t)(wr * 64 + i * 16 + ll) * 128 + kk * 32 + lq * 8);
#pragma unroll
        for (int j = 0; j < 4; ++j)
            bfv[j] = *(const bf16x8*)(xb + (size_t)(j * 16 + ll) * 128 + kk * 32 + lq * 8);
#pragma unroll
        for (int i = 0; i < 4; ++i)
#pragma unroll
            for (int j = 0; j < 4; ++j)
                acc[i][j] = __builtin_amdgcn_mfma_f32_16x16x32_bf16(af[i], bfv[j], acc[i][j], 0, 0, 0);
    }

#pragma unroll
    for (int i = 0; i < 4; ++i) {
        const int cob = wr * 64 + i * 16 + lq * 4;
        float c2v[4];
#pragma unroll
        for (int r = 0; r < 4; ++r) c2v[r] = c2[(b << 7) + cob + r];
#pragma unroll
        for (int j = 0; j < 4; ++j) {
            const int px = n0 + wc * 64 + j * 16 + ll;
#pragma unroll
            for (int r = 0; r < 4; ++r) {
                const size_t oi = ((size_t)(b * 128 + cob + r) << 10) + px;
                t[oi] += acc[i][j][r] + c2v[r] + bf2f(ybufb[oi]);
            }
        }
    }
}

// ------------------------- fused LN2 + MLP via bf16 MFMA -------------------
__global__ __launch_bounds__(256) void mlp_mfma_kernel(
    float* __restrict__ t, const float* __restrict__ ln_g,
    const float* __restrict__ ln_b, const unsigned short* __restrict__ w1bf,
    const float* __restrict__ b1, const unsigned short* __restrict__ w2bf,
    const float* __restrict__ b2)
{
    __shared__ unsigned char lds[16384 + 65536];
    unsigned char* xnb = lds;
    unsigned char* hb = lds + 16384;

    const int tid = threadIdx.x;
    const int b = blockIdx.x >> 4;
    const int n0 = (blockIdx.x & 15) << 6;
    float* tb = t + ((size_t)b << 17) + n0;

    {
        const int px = tid >> 2, q = tid & 3;
        float v[32];
        float s = 0.f, sq = 0.f;
#pragma unroll
        for (int k = 0; k < 32; ++k) {
            float x = tb[((size_t)(q * 32 + k) << 10) + px];
            v[k] = x;
            s += x;
            sq += x * x;
        }
        s += __shfl_xor(s, 1); s += __shfl_xor(s, 2);
        sq += __shfl_xor(sq, 1); sq += __shfl_xor(sq, 2);
        const float mu = s * 0.0078125f;
        const float rstd = rsqrtf(sq * 0.0078125f - mu * mu + 1e-5f);
        const int sw = (px & 7) << 4;
#pragma unroll
        for (int cc = 0; cc < 4; ++cc) {
            u16x8 pk;
#pragma unroll
            for (int e = 0; e < 8; ++e) {
                int c = q * 32 + cc * 8 + e;
                float xv = (v[cc * 8 + e] - mu) * rstd * ln_g[c] + ln_b[c];
                pk[e] = f2bf(xv);
            }
            *(u16x8*)(xnb + px * 256 + ((q * 64 + cc * 16) ^ sw)) = pk;
        }
    }
    __syncthreads();

    const int wid = tid >> 6, lane = tid & 63;
    const int lr = lane & 15, lk = lane >> 4;

#pragma unroll 1
    for (int pass = 0; pass < 2; ++pass) {
        const int hidbase = (wid << 7) + (pass << 6);
        f32x4 acc[4][4];
#pragma unroll
        for (int i = 0; i < 4; ++i)
#pragma unroll
            for (int j = 0; j < 4; ++j)
#pragma unroll
                for (int r = 0; r < 4; ++r) acc[i][j][r] = 0.f;
#pragma unroll
        for (int kk = 0; kk < 4; ++kk) {
            bf16x8 af[4], bfr[4];
#pragma unroll
            for (int i = 0; i < 4; ++i)
                af[i] = *(const bf16x8*)(w1bf + (size_t)(hidbase + i * 16 + lr) * 128 + kk * 32 + lk * 8);
#pragma unroll
            for (int j = 0; j < 4; ++j) {
                const int px = j * 16 + lr;
                bfr[j] = *(const bf16x8*)(xnb + px * 256 + ((kk * 64 + lk * 16) ^ ((px & 7) << 4)));
            }
#pragma unroll
            for (int i = 0; i < 4; ++i)
#pragma unroll
                for (int j = 0; j < 4; ++j)
                    acc[i][j] = __builtin_amdgcn_mfma_f32_16x16x32_bf16(af[i], bfr[j], acc[i][j], 0, 0, 0);
        }
#pragma unroll
        for (int i = 0; i < 4; ++i) {
            const int hid0 = hidbase + i * 16 + lk * 4;
            float bi[4];
#pragma unroll
            for (int r = 0; r < 4; ++r) bi[r] = b1[hid0 + r];
#pragma unroll
            for (int j = 0; j < 4; ++j) {
                const int px = j * 16 + lr;
                u16x4 pk;
#pragma unroll
                for (int r = 0; r < 4; ++r) {
                    float x = acc[i][j][r] + bi[r];
                    float u = 1.5957691f * x * (1.f + 0.044715f * x * x);
                    float gv = x / (1.f + __expf(-u));
                    pk[r] = f2bf(gv);
                }
                *(u16x4*)(hb + px * 1024 + ((hid0 * 2) ^ ((px & 7) << 4))) = pk;
            }
        }
    }
    __syncthreads();

    f32x4 acc2[2][4];
#pragma unroll
    for (int i = 0; i < 2; ++i)
#pragma unroll
        for (int j = 0; j < 4; ++j)
#pragma unroll
            for (int r = 0; r < 4; ++r) acc2[i][j][r] = 0.f;
#pragma unroll 2
    for (int ks = 0; ks < 16; ++ks) {
        bf16x8 af[2], bfr[4];
#pragma unroll
        for (int i = 0; i < 2; ++i)
            af[i] = *(const bf16x8*)(w2bf + (size_t)((wid << 5) + i * 16 + lr) * 512 + ks * 32 + lk * 8);
#pragma unroll
        for (int j = 0; j < 4; ++j) {
            const int px = j * 16 + lr;
            bfr[j] = *(const bf16x8*)(hb + px * 1024 + ((ks * 64 + lk * 16) ^ ((px & 7) << 4)));
        }
#pragma unroll
        for (int i = 0; i < 2; ++i)
#pragma unroll
            for (int j = 0; j < 4; ++j)
                acc2[i][j] = __builtin_amdgcn_mfma_f32_16x16x32_bf16(af[i], bfr[j], acc2[i][j], 0, 0, 0);
    }
#pragma unroll
    for (int i = 0; i < 2; ++i) {
        const int cb = (wid << 5) + i * 16 + lk * 4;
        float b2v[4];
#pragma unroll
        for (int r = 0; r < 4; ++r) b2v[r] = b2[cb + r];
#pragma unroll
        for (int j = 0; j < 4; ++j) {
            const int px = j * 16 + lr;
#pragma unroll
            for (int r = 0; r < 4; ++r) {
                const size_t off = ((size_t)(cb + r) << 10) + px;
                tb[off] += acc2[i][j][r] + b2v[r];
            }
        }
    }
}

// ------------------------- flash SWSA + fused po GEMM (512 thr) ------------
// 128 q-rows per block (8 waves x 16); grid 256 = (N/128)*B, b = idx&31.
// LDS: K [128][128] (whole region reused for P, then yv [128px][128c]) + V.
// REUSE==0: online softmax + stats out. REUSE==1: stats-driven direct exp.
// Output: outT (bf16 px-major) and/or outB (bf16 ch-major).
template <int REUSE>
__global__ __launch_bounds__(512) void swsa_po_kernel(
    const unsigned short* __restrict__ qT, const unsigned short* __restrict__ vbf,
    const unsigned short* __restrict__ wpo, const float* __restrict__ po_b,
    const unsigned short* __restrict__ resT,
    unsigned short* __restrict__ outT, unsigned short* __restrict__ outB,
    float fscale, float* __restrict__ statsM, float* __restrict__ statsL)
{
    __shared__ unsigned short K_lds[128 * 128];
    __shared__ unsigned short V_lds[128 * 128];
    const int tid = threadIdx.x;
    const int b = blockIdx.x & 31;
    const int n0 = (blockIdx.x >> 5) << 7;
    const int wid = tid >> 6, lane = tid & 63;     // wid 0..7
    const int lq = lane >> 4, ll = lane & 15;
    const unsigned short* qTb = qT + ((size_t)b << 17);
    const unsigned short* vb = vbf + ((size_t)b << 17);
    const int rowbase = n0 + wid * 16 + lq * 4;    // this lane's 4 q-rows

    bf16x8 aq[4];
    {
        const int row = n0 + wid * 16 + ll;
#pragma unroll
        for (int kk = 0; kk < 4; ++kk)
            aq[kk] = *(const bf16x8*)(qTb + ((size_t)row << 7) + kk * 32 + lq * 8);
    }

    float mrun[4], lrun[4];
    if (REUSE) {
#pragma unroll
        for (int r = 0; r < 4; ++r) {
            mrun[r] = statsM[(b << 10) + rowbase + r];
            lrun[r] = statsL[(b << 10) + rowbase + r];
        }
    } else {
#pragma unroll
        for (int i = 0; i < 4; ++i) { mrun[i] = -INFINITY; lrun[i] = 0.f; }
    }
    f32x4 yacc[8];
#pragma unroll
    for (int cj = 0; cj < 8; ++cj)
#pragma unroll
        for (int r = 0; r < 4; ++r) yacc[cj][r] = 0.f;

#pragma unroll 1
    for (int mt = 0; mt < 8; ++mt) {
        const int m0 = mt << 7;
        for (int ch = tid; ch < 2048; ch += 512) {
            const int rr = ch >> 4, e0 = (ch & 15) << 3;
            const int sw = (rr & 7) << 3;
            *(u16x8*)&K_lds[rr * 128 + (e0 ^ sw)] =
                *(const u16x8*)(qTb + ((size_t)(m0 + rr) << 7) + e0);
            *(u16x8*)&V_lds[rr * 128 + (e0 ^ sw)] =
                *(const u16x8*)(vb + ((size_t)rr << 10) + m0 + e0);
        }
        __syncthreads();

        // QK^T
        f32x4 sacc[8];
#pragma unroll
        for (int j = 0; j < 8; ++j)
#pragma unroll
            for (int r = 0; r < 4; ++r) sacc[j][r] = 0.f;
#pragma unroll
        for (int j = 0; j < 8; ++j) {
            const int ml = j * 16 + ll;
            const int swk = (ml & 7) << 3;
#pragma unroll
            for (int kk = 0; kk < 4; ++kk) {
                bf16x8 bk = *(const bf16x8*)&K_lds[ml * 128 + ((kk * 32 + lq * 8) ^ swk)];
                sacc[j] = __builtin_amdgcn_mfma_f32_16x16x32_bf16(aq[kk], bk, sacc[j], 0, 0, 0);
            }
        }
        __syncthreads();   // K reads done; whole K region becomes P (128 rows)

        if (REUSE) {
#pragma unroll
            for (int r = 0; r < 4; ++r) {
                const int nbw = wid * 16 + lq * 4 + r;
                const int sw4 = ((nbw >> 2) & 3) << 4;
                const float mn = mrun[r];
#pragma unroll
                for (int j = 0; j < 8; ++j) {
                    float p = __expf(sacc[j][r] * 0.08838834764831845f - mn);
                    K_lds[nbw * 128 + ((j * 16 + ll) ^ sw4)] = f2bf(p);
                }
            }
        } else {
            float pmax[4];
#pragma unroll
            for (int i = 0; i < 4; ++i) pmax[i] = -INFINITY;
#pragma unroll
            for (int j = 0; j < 8; ++j)
#pragma unroll
                for (int r = 0; r < 4; ++r) {
                    float s = sacc[j][r] * 0.08838834764831845f;
                    sacc[j][r] = s;
                    pmax[r] = fmaxf(pmax[r], s);
                }
            float alpha[4];
#pragma unroll
            for (int i = 0; i < 4; ++i) {
                float m = pmax[i];
                m = fmaxf(m, __shfl_xor(m, 1));
                m = fmaxf(m, __shfl_xor(m, 2));
                m = fmaxf(m, __shfl_xor(m, 4));
                m = fmaxf(m, __shfl_xor(m, 8));
                const float mn = fmaxf(mrun[i], m);
                alpha[i] = __expf(mrun[i] - mn);
                mrun[i] = mn;
            }
            float psum[4];
#pragma unroll
            for (int r = 0; r < 4; ++r) {
                const int nbw = wid * 16 + lq * 4 + r;
                const int sw4 = ((nbw >> 2) & 3) << 4;
                const float mn = mrun[r];
                float ps = 0.f;
#pragma unroll
                for (int j = 0; j < 8; ++j) {
                    float p = __expf(sacc[j][r] - mn);
                    ps += p;
                    K_lds[nbw * 128 + ((j * 16 + ll) ^ sw4)] = f2bf(p);
                }
                psum[r] = ps;
            }
#pragma unroll
            for (int i = 0; i < 4; ++i) {
                float s = psum[i];
                s += __shfl_xor(s, 1);
                s += __shfl_xor(s, 2);
                s += __shfl_xor(s, 4);
                s += __shfl_xor(s, 8);
                lrun[i] = lrun[i] * alpha[i] + s;
            }
#pragma unroll
            for (int cj = 0; cj < 8; ++cj)
#pragma unroll
                for (int r = 0; r < 4; ++r) yacc[cj][r] *= alpha[r];
        }

        bf16x8 ap[4];
        {
            const int nb = wid * 16 + ll;
            const int sw4 = ((nb >> 2) & 3) << 4;
#pragma unroll
            for (int mk = 0; mk < 4; ++mk)
                ap[mk] = *(const bf16x8*)&K_lds[nb * 128 + ((mk * 32 + lq * 8) ^ sw4)];
        }
#pragma unroll
        for (int cj = 0; cj < 8; ++cj) {
            const int cl = cj * 16 + ll;
            const int sw = (cl & 7) << 3;
#pragma unroll
            for (int mk = 0; mk < 4; ++mk) {
                bf16x8 bv = *(const bf16x8*)&V_lds[cl * 128 + ((mk * 32 + lq * 8) ^ sw)];
                yacc[cj] = __builtin_amdgcn_mfma_f32_16x16x32_bf16(ap[mk], bv, yacc[cj], 0, 0, 0);
            }
        }
        __syncthreads();   // PV reads done; safe to restage
    }

    if (!REUSE) {
        if (ll == 0) {
#pragma unroll
            for (int r = 0; r < 4; ++r) {
                statsM[(b << 10) + rowbase + r] = mrun[r];
                statsL[(b << 10) + rowbase + r] = lrun[r];
            }
        }
    }

    // ---- fused po: yv (normalized) -> K_lds [128px][128c], then GEMM ------
    {
        float inv[4];
#pragma unroll
        for (int r = 0; r < 4; ++r) inv[r] = fscale / lrun[r];
        const int rw0 = wid * 16 + lq * 4;
#pragma unroll
        for (int cj = 0; cj < 8; ++cj) {
            const int c = cj * 16 + ll;
#pragma unroll
            for (int r = 0; r < 4; ++r) {
                const int row = rw0 + r;
                const int sw4 = ((row >> 2) & 3) << 4;
                K_lds[row * 128 + (c ^ sw4)] = f2bf(yacc[cj][r] * inv[r]);
            }
        }
    }
    __syncthreads();

    // po GEMM: each wave computes 16 co x 128 px.
    f32x4 acc2[8];
#pragma unroll
    for (int j = 0; j < 8; ++j)
#pragma unroll
        for (int r = 0; r < 4; ++r) acc2[j][r] = 0.f;
#pragma unroll
    for (int kk = 0; kk < 4; ++kk) {
        bf16x8 af = *(const bf16x8*)(wpo + (size_t)(wid * 16 + ll) * 128 + kk * 32 + lq * 8);
#pragma unroll
        for (int j = 0; j < 8; ++j) {
            const int row = j * 16 + ll;
            const int sw4 = ((row >> 2) & 3) << 4;
            bf16x8 bfv = *(const bf16x8*)&K_lds[row * 128 + ((kk * 32 + lq * 8) ^ sw4)];
            acc2[j] = __builtin_amdgcn_mfma_f32_16x16x32_bf16(af, bfv, acc2[j], 0, 0, 0);
        }
    }

    {
        const int cob = wid * 16 + lq * 4;
        float pob[4];
#pragma unroll
        for (int r = 0; r < 4; ++r) pob[r] = po_b[cob + r];
#pragma unroll
        for (int j = 0; j < 8; ++j) {
            const int px = n0 + j * 16 + ll;
            const size_t rowT = ((size_t)((b << 10) + px)) << 7;
            u16x4 rv = *(const u16x4*)(resT + rowT + cob);
            float vv[4];
#pragma unroll
            for (int r = 0; r < 4; ++r)
                vv[r] = acc2[j][r] + pob[r] + bf2f(rv[r]);
            if (outT) {
                u16x4 tp;
#pragma unroll
                for (int r = 0; r < 4; ++r) tp[r] = f2bf(vv[r]);
                *(u16x4*)(outT + rowT + cob) = tp;
            }
            if (outB) {
#pragma unroll
                for (int r = 0; r < 4; ++r)
                    outB[((size_t)(b * 128 + cob + r) << 10) + px] = f2bf(vv[r]);
            }
        }
    }
}

// ------------------------- final: mean (stage 1) ---------------------------
// xc fp32 (ch-major), xp bf16 (ch-major)
__global__ __launch_bounds__(256) void mean_kernel(
    const float* __restrict__ xc, const unsigned short* __restrict__ xp,
    const float* __restrict__ lamuda, float* __restrict__ meanb)
{
    const int wid = threadIdx.x >> 6, lane = threadIdx.x & 63;
    const int row = (blockIdx.x << 2) + wid;
    const float lmd = 1.f / (1.f + __expf(-lamuda[0]));
    const float* a = xc + ((size_t)row << 10) + (lane << 2);
    const unsigned short* d = xp + ((size_t)row << 10) + (lane << 4);
    float s = 0.f;
#pragma unroll
    for (int i = 0; i < 4; ++i) {
        float4 va = *(const float4*)(a + (i << 8));
        s += lmd * (va.x + va.y + va.z + va.w);
    }
    float sp = 0.f;
#pragma unroll
    for (int i = 0; i < 2; ++i) {
        u16x8 v = *(const u16x8*)(d + i * 8);
#pragma unroll
        for (int e = 0; e < 8; ++e) sp += bf2f(v[e]);
    }
    s += (1.f - lmd) * sp;
#pragma unroll
    for (int o = 1; o < 64; o <<= 1) s += __shfl_xor(s, o);
    if (lane == 0) meanb[row] = s * (1.f / 1024.f);
}

// ------------------------- final: fc (stage 2) -----------------------------
__global__ __launch_bounds__(256) void fc_kernel(
    const float* __restrict__ meanb, const float* __restrict__ fc_w,
    float* __restrict__ outp)
{
    const int idx = blockIdx.x * 256 + threadIdx.x;
    if (idx >= 512) return;
    const int b = idx >> 4, o = idx & 15;
    float s = 0.f;
#pragma unroll 4
    for (int c = 0; c < 128; ++c) s += fc_w[o * 128 + c] * meanb[b * 128 + c];
    outp[b * 16 + o] = s;
}

// ---------------------------------------------------------------------------
extern "C" void kernel_launch(void* const* d_in, const int* in_sizes, int n_in,
                              void* d_out, int out_size, void* d_ws, size_t ws_size,
                              hipStream_t stream)
{
    (void)in_sizes; (void)n_in; (void)out_size; (void)ws_size;

    const float* x       = (const float*)d_in[0];
    const float* ssfe_w  = (const float*)d_in[1];
    const float* ssfe_g  = (const float*)d_in[2];
    const float* ssfe_b  = (const float*)d_in[3];
    const float* cc_w    = (const float*)d_in[4];
    const float* cc_g    = (const float*)d_in[5];
    const float* cc_b    = (const float*)d_in[6];
    const float* ln1_g   = (const float*)d_in[7];
    const float* ln1_b   = (const float*)d_in[8];
    const float* qkv_w   = (const float*)d_in[9];
    const float* qkv_b   = (const float*)d_in[10];
    const float* gbn_g   = (const float*)d_in[11];
    const float* gbn_b   = (const float*)d_in[12];
    const float* qkv2_w  = (const float*)d_in[13];
    const float* qkv2_b  = (const float*)d_in[14];
    const float* ln2_g   = (const float*)d_in[15];
    const float* ln2_b   = (const float*)d_in[16];
    const float* mlp_w1  = (const float*)d_in[17];
    const float* mlp_b1  = (const float*)d_in[18];
    const float* mlp_w2  = (const float*)d_in[19];
    const float* mlp_b2  = (const float*)d_in[20];
    const float* cs_w    = (const float*)d_in[21];
    const float* cs_g    = (const float*)d_in[22];
    const float* cs_b    = (const float*)d_in[23];
    const float* lfe0_w  = (const float*)d_in[24];
    const float* lfe0_g  = (const float*)d_in[25];
    const float* lfe0_b  = (const float*)d_in[26];
    const float* s0_pi_w = (const float*)d_in[27];
    const float* s0_pi_b = (const float*)d_in[28];
    const float* s0_bn_g = (const float*)d_in[29];
    const float* s0_bn_b = (const float*)d_in[30];
    const float* s0_po_w = (const float*)d_in[31];
    const float* s0_po_b = (const float*)d_in[32];
    const float* lfe1_w  = (const float*)d_in[33];
    const float* lfe1_g  = (const float*)d_in[34];
    const float* lfe1_b  = (const float*)d_in[35];
    const float* s1_pi_w = (const float*)d_in[36];
    const float* s1_pi_b = (const float*)d_in[37];
    const float* s1_bn_g = (const float*)d_in[38];
    const float* s1_bn_b = (const float*)d_in[39];
    const float* s1_po_w = (const float*)d_in[40];
    const float* s1_po_b = (const float*)d_in[41];
    const float* lamuda  = (const float*)d_in[42];
    const float* fc_w    = (const float*)d_in[43];
    float* out = (float*)d_out;
    float* ws = (float*)d_ws;

    // workspace regions (floats)
    float* xs = ws;                    // scratch (wlfe1 weights)
    float* t  = ws + 4718592;          // (B,128,N) residual stream / xc
    float* Qr = ws + 13107200;         // 12.58M floats, phase-overlaid
    float* P2 = ws + 25690112;         // (B,128,N)
    float* P3 = ws + 29884416;         // (B,128,N)

    // stem phase (Qr head): xT0 dead before cc_ln writes curbf/curT
    unsigned short* xT0 = (unsigned short*)Qr;                 // (B,1024,160)

    // GISSA phase (Qr)
    unsigned short* curbf = (unsigned short*)Qr;               // (B,128,1024)
    unsigned short* curT  = (unsigned short*)(Qr + 2097152);   // (B,1024,128)
    unsigned short* yrbf  = (unsigned short*)(Qr + 4194304);   // (B,128,1024)
    unsigned short* yrT   = (unsigned short*)(Qr + 6291456);   // (B,1024,128)
    unsigned short* xsT   = (unsigned short*)(Qr + 8388608);   // (B,1024,160)
    unsigned short* ybufb = (unsigned short*)P2;               // (B,128,1024) bf16

    // swsa phase (Qr overlay) — R15-proven aliasing
    unsigned short* xpT   = (unsigned short*)Qr;               // cs->lfe0 (+res)
    unsigned short* v0    = (unsigned short*)(Qr + 2097152);
    unsigned short* v1    = (unsigned short*)(Qr + 4194304);   // pi1->swsa1
    unsigned short* xp3T  = (unsigned short*)(Qr + 6291456);   // swsa0(po0)->lfe1 (+res)
    unsigned short* xp2T  = (unsigned short*)(Qr + 8388608);   // lfe0->pi0, swsa0-res
    unsigned short* xp4T  = (unsigned short*)(Qr + 8388608);   // lfe1->pi1, swsa1-res
    // qT0 lives in P2 (free after GISSA; ybufb dead after apply2)
    unsigned short* qT0   = (unsigned short*)P2;               // (B,1024,128)
    // swsa1 bf16 ch-major output (mean reads it); P3 scratch is dead by then
    unsigned short* xpb   = (unsigned short*)P3;               // (B,128,1024) bf16

    // permanently-free Qr tail: packed 1x1+mlp weights + meanb + swsa stats
    unsigned short* linw  = (unsigned short*)(Qr + 11010048);  // 233472 u16
    unsigned short* wcc   = linw;                 // [128][160]
    unsigned short* wpi0  = linw + 20480;         // [256][128]
    unsigned short* wpi1  = linw + 53248;         // [128][128]
    unsigned short* wpo0  = linw + 69632;         // [128][128]
    unsigned short* wpo1  = linw + 86016;         // [128][128]
    unsigned short* w1bf  = linw + 102400;        // [512][128]
    unsigned short* w2bf  = linw + 167936;        // [128][512]
    float* meanb  = Qr + 11200000;                // 4096 floats
    float* statsM = Qr + 11204096;                // 32768 floats (B*N)
    float* statsL = Qr + 11236864;                // 32768 floats

    // small mats in P3 (dead before swsa1 writes P3)
    float* Gbuf  = P3 + 1048576;
    float* Sbuf  = P3 + 1572864;
    unsigned short* M1bf = (unsigned short*)(P3 + 1576960);
    float* c1buf = P3 + 1839104;
    unsigned short* M2bf = (unsigned short*)(P3 + 1843200);
    float* c2buf = P3 + 2105344;

    unsigned short* wssfe = (unsigned short*)P3;             // 9*144*160
    unsigned short* wcs   = (unsigned short*)(P3 + 131072);  // 9*128*160
    unsigned short* wlfe0 = (unsigned short*)(P3 + 262144);  // 9*128*128
    unsigned short* wlfe1 = (unsigned short*)xs;             // 9*128*128

    const dim3 blk(256);

    prepack_convs<<<dim3((686592 + 255) / 256), blk, 0, stream>>>(
        ssfe_w, cs_w, lfe0_w, lfe1_w, wssfe, wcs, wlfe0, wlfe1);
    prepack_lins<<<dim3((233472 + 255) / 256), blk, 0, stream>>>(
        cc_w, s0_pi_w, s1_pi_w, s0_po_w, s1_po_w, mlp_w1, mlp_w2, linw);

    // x -> bf16 px-major; xsT = cbr3(xT0, ssfe)
    cvt_xT_kernel<<<dim3(32, 16), blk, 0, stream>>>(x, xT0);
    conv3x3_ssfe_kernel<<<dim3(32, 16), blk, 0, stream>>>(
        xT0, wssfe, ssfe_g, ssfe_b, xsT);

    // ---- cc 1x1 + fused LN1: t (fp32), curbf, curT ----
    cc_ln_kernel<<<dim3(32, 16), blk, 0, stream>>>(
        xsT, wcc, cc_g, cc_b, ln1_g, ln1_b, t, curbf, curT);

    // ---- GISSA via Gram trick ----
    gram_sums_kernel<<<dim3(160), blk, 0, stream>>>(curbf, Gbuf, Sbuf);
    mats1_kernel<<<dim3(512), dim3(64), 0, stream>>>(Gbuf, Sbuf, qkv_w, qkv_b, gbn_g, gbn_b, M1bf, c1buf);
    apply1_mfma_kernel<<<dim3(256), blk, 0, stream>>>(curT, M1bf, c1buf, ybufb, yrbf, yrT);
    gram_sums_kernel<<<dim3(160), blk, 0, stream>>>(yrbf, Gbuf, Sbuf);
    mats2_kernel<<<dim3(256), blk, 0, stream>>>(Gbuf, Sbuf, qkv2_w, qkv2_b, M2bf, c2buf);
    apply2_mfma_kernel<<<dim3(256), blk, 0, stream>>>(yrT, M2bf, c2buf, ybufb, t);

    mlp_mfma_kernel<<<dim3(512), blk, 0, stream>>>(t, ln2_g, ln2_b, w1bf, mlp_b1, w2bf, mlp_b2);

    // ---- xp branch, all-bf16 ----
    conv3x3_lds_kernel<160><<<dim3(32, 16), blk, 0, stream>>>(
        xsT, wcs, cs_g, cs_b, nullptr, xpT, 128);
    conv3x3_pi_kernel<256><<<dim3(32, 16), blk, 0, stream>>>(
        xpT, wlfe0, lfe0_g, lfe0_b, xpT, xp2T,
        wpi0, s0_pi_b, s0_bn_g, s0_bn_b, qT0, v0);
    // swsa0 + po0 (+stats): xp3T = po0(softmax(qq^T)v0) + po_b + xp2T
    swsa_po_kernel<0><<<dim3(256), dim3(512), 0, stream>>>(
        qT0, v0, wpo0, s0_po_b, xp2T, xp3T, nullptr, 1.0f, statsM, statsL);
    conv3x3_pi_kernel<128><<<dim3(32, 16), blk, 0, stream>>>(
        xp3T, wlfe1, lfe1_g, lfe1_b, xp3T, xp4T,
        wpi1, s1_pi_b, s1_bn_g, s1_bn_b, nullptr, v1);
    // swsa1 + po1 (stats reuse): xpb (bf16 ch-major) = po1(...) + po_b + xp4T
    swsa_po_kernel<1><<<dim3(256), dim3(512), 0, stream>>>(
        qT0, v1, wpo1, s1_po_b, xp4T, nullptr, xpb, 0.08838834764831845f, statsM, statsL);

    mean_kernel<<<dim3(1024), blk, 0, stream>>>(t, xpb, lamuda, meanb);
    fc_kernel<<<dim3(2), blk, 0, stream>>>(meanb, fc_w, out);
}

// Round 21
// 375.977 us; speedup vs baseline: 1.5845x; 1.0124x over previous
//
#include <hip/hip_runtime.h>
#include <math.h>

// ---------------------------------------------------------------------------
// EATN forward. Layout: activations (B, C, N), N = 1024 contiguous.
// B=32, C=128 (144 stem), HEADS=16, HD=8.
// Round 21: swsa_po double-buffers K/V staging (128 KB LDS, prefetch tile
// t+1 during compute of tile t; 2 barriers/tile instead of 3). Everything
// else identical to R20.
// ---------------------------------------------------------------------------

static constexpr int NPIX = 1024;

typedef __attribute__((ext_vector_type(8))) short bf16x8;
typedef __attribute__((ext_vector_type(4))) float f32x4;
typedef __attribute__((ext_vector_type(8))) unsigned short u16x8;
typedef __attribute__((ext_vector_type(4))) unsigned short u16x4;

static __device__ __forceinline__ unsigned short f2bf(float f) {
    unsigned u = __builtin_bit_cast(unsigned, f);
    unsigned r = (u + 0x7fffu + ((u >> 16) & 1u)) >> 16;
    return (unsigned short)r;
}
static __device__ __forceinline__ float bf2f(unsigned short u) {
    unsigned v = ((unsigned)u) << 16;
    return __builtin_bit_cast(float, v);
}

// ------------------------- conv weight prepack (all 4, one launch) ---------
__global__ __launch_bounds__(256) void prepack_convs(
    const float* __restrict__ ssfe_w, const float* __restrict__ cs_w,
    const float* __restrict__ lfe0_w, const float* __restrict__ lfe1_w,
    unsigned short* __restrict__ wssfe, unsigned short* __restrict__ wcs,
    unsigned short* __restrict__ wlfe0, unsigned short* __restrict__ wlfe1)
{
    int idx = blockIdx.x * 256 + threadIdx.x;
    const float* src;
    unsigned short* dst;
    int k, Cout, CIN, CINP;
    if (idx < 207360) {
        src = ssfe_w; dst = wssfe; k = idx; Cout = 144; CIN = 144; CINP = 160;
    } else if (idx < 391680) {
        src = cs_w; dst = wcs; k = idx - 207360; Cout = 128; CIN = 144; CINP = 160;
    } else if (idx < 539136) {
        src = lfe0_w; dst = wlfe0; k = idx - 391680; Cout = 128; CIN = 128; CINP = 128;
    } else if (idx < 686592) {
        src = lfe1_w; dst = wlfe1; k = idx - 539136; Cout = 128; CIN = 128; CINP = 128;
    } else return;
    int ci = k % CINP;
    int rem = k / CINP;
    int co = rem % Cout;
    int tap = rem / Cout;
    float v = (ci < CIN) ? src[((size_t)co * CIN + ci) * 9 + tap] : 0.f;
    dst[k] = f2bf(v);
}

// ------------------------- 1x1 + mlp weights prepack (one launch) ----------
__global__ __launch_bounds__(256) void prepack_lins(
    const float* __restrict__ cc_w, const float* __restrict__ pi0_w,
    const float* __restrict__ pi1_w, const float* __restrict__ po0_w,
    const float* __restrict__ po1_w, const float* __restrict__ w1,
    const float* __restrict__ w2, unsigned short* __restrict__ o)
{
    int idx = blockIdx.x * 256 + threadIdx.x;
    if (idx >= 233472) return;
    float v;
    if (idx < 20480) {
        int ci = idx % 160, co = idx / 160;
        v = (ci < 144) ? cc_w[co * 144 + ci] : 0.f;
    } else if (idx < 53248) {
        v = pi0_w[idx - 20480];
    } else if (idx < 69632) {
        v = pi1_w[idx - 53248];
    } else if (idx < 86016) {
        v = po0_w[idx - 69632];
    } else if (idx < 102400) {
        v = po1_w[idx - 86016];
    } else if (idx < 167936) {
        v = w1[idx - 102400];
    } else {
        v = w2[idx - 167936];
    }
    o[idx] = f2bf(v);
}

// ------------------------- x fp32 (B,144,1024) -> bf16 px-major (B,1024,160)
__global__ __launch_bounds__(256) void cvt_xT_kernel(
    const float* __restrict__ x, unsigned short* __restrict__ xT0)
{
    __shared__ unsigned short T[64 * 168];
    const int tid = threadIdx.x;
    const int b = blockIdx.x;
    const int px0 = blockIdx.y << 6;
    const float* xb = x + ((size_t)b * 144 << 10) + px0;

#pragma unroll 1
    for (int idx = tid; idx < 72 * 64; idx += 256) {
        const int c2 = idx >> 6, px = idx & 63;
        float a = xb[((size_t)(2 * c2) << 10) + px];
        float c = xb[((size_t)(2 * c2 + 1) << 10) + px];
        *(unsigned*)&T[px * 168 + 2 * c2] =
            (unsigned)f2bf(a) | ((unsigned)f2bf(c) << 16);
    }
#pragma unroll 1
    for (int idx = tid; idx < 64 * 8; idx += 256) {
        const int px = idx >> 3, pr = idx & 7;
        *(unsigned*)&T[px * 168 + 144 + pr * 2] = 0u;
    }
    __syncthreads();

#pragma unroll 1
    for (int idx = tid; idx < 64 * 20; idx += 256) {
        const int px = idx / 20;
        const int chunk = idx - px * 20;
        *(u16x8*)(xT0 + ((size_t)((b << 10) + px0 + px)) * 160 + chunk * 8) =
            *(const u16x8*)&T[px * 168 + chunk * 8];
    }
}

// ------------------------- ssfe conv: bf16 in (pitch 160) -> bf16 out ------
__global__ __launch_bounds__(256) void conv3x3_ssfe_kernel(
    const unsigned short* __restrict__ xT,
    const unsigned short* __restrict__ wrep,   // [9][144][160]
    const float* __restrict__ g, const float* __restrict__ bb,
    unsigned short* __restrict__ outT)
{
    constexpr int CINP = 160, PITCH = 168, NCHK = 20;
    __shared__ unsigned short X[130 * PITCH];
    const int tid = threadIdx.x;
    const int b = blockIdx.x, gr = blockIdx.y;
    const int pbase = gr << 6;
    const int gbase = pbase - 33;
    const int wid = tid >> 6, lane = tid & 63;
    const int ll = lane & 15, lq = lane >> 4;
    const unsigned short* xb = xT + ((size_t)b << 10) * CINP;

#pragma unroll 1
    for (int idx = tid; idx < 130 * NCHK; idx += 256) {
        const int row = idx / NCHK;
        const int chunk = idx - row * NCHK;
        const int gp = gbase + row;
        u16x8 v = {};
        if (gp >= 0 && gp < 1024)
            v = *(const u16x8*)(xb + (size_t)gp * CINP + chunk * 8);
        *(u16x8*)&X[row * PITCH + chunk * 8] = v;
    }
    __syncthreads();

    if (wid == 3) {
#pragma unroll
        for (int j = 0; j < 4; ++j) {
            const int px = pbase + j * 16 + ll;
            u16x4 z = {};
            *(u16x4*)(outT + ((size_t)((b << 10) + px)) * 160 + 144 + lq * 4) = z;
        }
        return;
    }

    const int co0w = wid * 48;
    f32x4 acc[3][4];
#pragma unroll
    for (int i = 0; i < 3; ++i)
#pragma unroll
        for (int j = 0; j < 4; ++j)
#pragma unroll
            for (int r = 0; r < 4; ++r) acc[i][j][r] = 0.f;

#pragma unroll
    for (int tap = 0; tap < 9; ++tap) {
        const int soff = (tap / 3) * 32 + (tap % 3);
        const int dx = tap % 3;
#pragma unroll
        for (int kc = 0; kc < CINP / 32; ++kc) {
            bf16x8 bfv[4];
#pragma unroll
            for (int j = 0; j < 4; ++j) {
                const int p = j * 16 + ll;
                bf16x8 v = *(const bf16x8*)&X[(p + soff) * PITCH + kc * 32 + lq * 8];
                const bool zed = (dx == 0 && (j & 1) == 0 && ll == 0) ||
                                 (dx == 2 && (j & 1) == 1 && ll == 15);
                if (zed) { bf16x8 z = {}; v = z; }
                bfv[j] = v;
            }
            const unsigned short* wb =
                wrep + ((size_t)tap * 144 + co0w) * CINP + kc * 32 + lq * 8;
#pragma unroll
            for (int i = 0; i < 3; ++i) {
                bf16x8 af = *(const bf16x8*)(wb + (size_t)(i * 16 + ll) * CINP);
#pragma unroll
                for (int j = 0; j < 4; ++j)
                    acc[i][j] = __builtin_amdgcn_mfma_f32_16x16x32_bf16(
                        af, bfv[j], acc[i][j], 0, 0, 0);
            }
        }
    }

#pragma unroll
    for (int i = 0; i < 3; ++i) {
        const int cob = co0w + i * 16 + lq * 4;
        float gv[4], bv[4];
#pragma unroll
        for (int r = 0; r < 4; ++r) { gv[r] = g[cob + r]; bv[r] = bb[cob + r]; }
#pragma unroll
        for (int j = 0; j < 4; ++j) {
            const int px = pbase + j * 16 + ll;
            u16x4 tp;
#pragma unroll
            for (int r = 0; r < 4; ++r)
                tp[r] = f2bf(fmaxf(acc[i][j][r] * gv[r] + bv[r], 0.f));
            *(u16x4*)(outT + ((size_t)((b << 10) + px)) * 160 + cob) = tp;
        }
    }
}

// ------------------------- conv3x3 bf16->bf16, 64px x 128co blocks ---------
template <int CINP>
__global__ __launch_bounds__(256) void conv3x3_lds_kernel(
    const unsigned short* __restrict__ xT,
    const unsigned short* __restrict__ wrep,
    const float* __restrict__ g, const float* __restrict__ bb,
    const unsigned short* __restrict__ resT,
    unsigned short* __restrict__ outT, int Cout)
{
    constexpr int PITCH = CINP + 8;
    constexpr int NCHK = CINP / 8;
    __shared__ unsigned short X[130 * PITCH];
    const int tid = threadIdx.x;
    const int b = blockIdx.x, gr = blockIdx.y;
    const int pbase = gr << 6;
    const int gbase = pbase - 33;
    const int wid = tid >> 6, lane = tid & 63;
    const int ll = lane & 15, lq = lane >> 4;
    const int co0w = wid << 5;
    const unsigned short* xb = xT + ((size_t)b << 10) * CINP;

#pragma unroll 1
    for (int idx = tid; idx < 130 * NCHK; idx += 256) {
        const int row = idx / NCHK;
        const int chunk = idx - row * NCHK;
        const int gp = gbase + row;
        u16x8 v = {};
        if (gp >= 0 && gp < 1024)
            v = *(const u16x8*)(xb + (size_t)gp * CINP + chunk * 8);
        *(u16x8*)&X[row * PITCH + chunk * 8] = v;
    }
    __syncthreads();

    f32x4 acc[2][4];
#pragma unroll
    for (int i = 0; i < 2; ++i)
#pragma unroll
        for (int j = 0; j < 4; ++j)
#pragma unroll
            for (int r = 0; r < 4; ++r) acc[i][j][r] = 0.f;

#pragma unroll
    for (int tap = 0; tap < 9; ++tap) {
        const int soff = (tap / 3) * 32 + (tap % 3);
        const int dx = tap % 3;
#pragma unroll
        for (int kc = 0; kc < CINP / 32; ++kc) {
            bf16x8 bfv[4];
#pragma unroll
            for (int j = 0; j < 4; ++j) {
                const int p = j * 16 + ll;
                bf16x8 v = *(const bf16x8*)&X[(p + soff) * PITCH + kc * 32 + lq * 8];
                const bool zed = (dx == 0 && (j & 1) == 0 && ll == 0) ||
                                 (dx == 2 && (j & 1) == 1 && ll == 15);
                if (zed) { bf16x8 z = {}; v = z; }
                bfv[j] = v;
            }
            const unsigned short* wb =
                wrep + ((size_t)tap * Cout + co0w) * CINP + kc * 32 + lq * 8;
#pragma unroll
            for (int i = 0; i < 2; ++i) {
                bf16x8 af = *(const bf16x8*)(wb + (size_t)(i * 16 + ll) * CINP);
#pragma unroll
                for (int j = 0; j < 4; ++j)
                    acc[i][j] = __builtin_amdgcn_mfma_f32_16x16x32_bf16(
                        af, bfv[j], acc[i][j], 0, 0, 0);
            }
        }
    }

#pragma unroll
    for (int i = 0; i < 2; ++i) {
        const int cob = co0w + i * 16 + lq * 4;
        float gv[4], bv[4];
#pragma unroll
        for (int r = 0; r < 4; ++r) { gv[r] = g[cob + r]; bv[r] = bb[cob + r]; }
#pragma unroll
        for (int j = 0; j < 4; ++j) {
            const int px = pbase + j * 16 + ll;
            const size_t rowT = ((size_t)((b << 10) + px)) << 7;
            u16x4 rv = {};
            if (resT) rv = *(const u16x4*)(resT + rowT + cob);
            u16x4 tp;
#pragma unroll
            for (int r = 0; r < 4; ++r) {
                float v = fmaxf(acc[i][j][r] * gv[r] + bv[r], 0.f);
                if (resT) v += bf2f(rv[r]);
                tp[r] = f2bf(v);
            }
            *(u16x4*)(outT + rowT + cob) = tp;
        }
    }
}

// ------------------------- conv3x3 (CIN=128) + fused pi 1x1 ---------------
template <int PI_COUT>
__global__ __launch_bounds__(256) void conv3x3_pi_kernel(
    const unsigned short* __restrict__ xT,
    const unsigned short* __restrict__ wrep,
    const float* __restrict__ g, const float* __restrict__ bb,
    const unsigned short* __restrict__ resT,
    unsigned short* __restrict__ outT,
    const unsigned short* __restrict__ wpi, const float* __restrict__ pi_b,
    const float* __restrict__ pig, const float* __restrict__ pibb,
    unsigned short* __restrict__ qTout, unsigned short* __restrict__ vout)
{
    constexpr int CINP = 128, PITCH = 136, NCHK = 16;
    __shared__ unsigned short X[130 * PITCH];   // head reused as Y[64][128]
    unsigned short* Y = X;
    const int tid = threadIdx.x;
    const int b = blockIdx.x, gr = blockIdx.y;
    const int pbase = gr << 6;
    const int gbase = pbase - 33;
    const int wid = tid >> 6, lane = tid & 63;
    const int ll = lane & 15, lq = lane >> 4;
    const int co0w = wid << 5;
    const unsigned short* xb = xT + ((size_t)b << 10) * CINP;

#pragma unroll 1
    for (int idx = tid; idx < 130 * NCHK; idx += 256) {
        const int row = idx / NCHK;
        const int chunk = idx - row * NCHK;
        const int gp = gbase + row;
        u16x8 v = {};
        if (gp >= 0 && gp < 1024)
            v = *(const u16x8*)(xb + (size_t)gp * CINP + chunk * 8);
        *(u16x8*)&X[row * PITCH + chunk * 8] = v;
    }
    __syncthreads();

    f32x4 acc[2][4];
#pragma unroll
    for (int i = 0; i < 2; ++i)
#pragma unroll
        for (int j = 0; j < 4; ++j)
#pragma unroll
            for (int r = 0; r < 4; ++r) acc[i][j][r] = 0.f;

#pragma unroll
    for (int tap = 0; tap < 9; ++tap) {
        const int soff = (tap / 3) * 32 + (tap % 3);
        const int dx = tap % 3;
#pragma unroll
        for (int kc = 0; kc < CINP / 32; ++kc) {
            bf16x8 bfv[4];
#pragma unroll
            for (int j = 0; j < 4; ++j) {
                const int p = j * 16 + ll;
                bf16x8 v = *(const bf16x8*)&X[(p + soff) * PITCH + kc * 32 + lq * 8];
                const bool zed = (dx == 0 && (j & 1) == 0 && ll == 0) ||
                                 (dx == 2 && (j & 1) == 1 && ll == 15);
                if (zed) { bf16x8 z = {}; v = z; }
                bfv[j] = v;
            }
            const unsigned short* wb =
                wrep + ((size_t)tap * 128 + co0w) * CINP + kc * 32 + lq * 8;
#pragma unroll
            for (int i = 0; i < 2; ++i) {
                bf16x8 af = *(const bf16x8*)(wb + (size_t)(i * 16 + ll) * CINP);
#pragma unroll
                for (int j = 0; j < 4; ++j)
                    acc[i][j] = __builtin_amdgcn_mfma_f32_16x16x32_bf16(
                        af, bfv[j], acc[i][j], 0, 0, 0);
            }
        }
    }
    __syncthreads();   // all waves done reading X; safe to overwrite with Y

    // conv epilogue: write outT (global) and Y (LDS, swizzled)
#pragma unroll
    for (int i = 0; i < 2; ++i) {
        const int cob = co0w + i * 16 + lq * 4;
        float gv[4], bv[4];
#pragma unroll
        for (int r = 0; r < 4; ++r) { gv[r] = g[cob + r]; bv[r] = bb[cob + r]; }
#pragma unroll
        for (int j = 0; j < 4; ++j) {
            const int pxl = j * 16 + ll;
            const int px = pbase + pxl;
            const size_t rowT = ((size_t)((b << 10) + px)) << 7;
            u16x4 rv = *(const u16x4*)(resT + rowT + cob);
            u16x4 tp;
#pragma unroll
            for (int r = 0; r < 4; ++r) {
                float v = fmaxf(acc[i][j][r] * gv[r] + bv[r], 0.f) + bf2f(rv[r]);
                tp[r] = f2bf(v);
            }
            *(u16x4*)(outT + rowT + cob) = tp;
            const int sw4 = ((pxl >> 2) & 3) << 4;
            *(u16x4*)&Y[pxl * 128 + (cob ^ sw4)] = tp;
        }
    }
    __syncthreads();

    // pi GEMM: out = wpi @ Y
    constexpr int NI = PI_COUT / 64;           // 4 (256-out) or 2 (128-out)
    const int co0p = wid * (PI_COUT / 4);      // 64*wid or 32*wid
    f32x4 acc2[NI][4];
#pragma unroll
    for (int i = 0; i < NI; ++i)
#pragma unroll
        for (int j = 0; j < 4; ++j)
#pragma unroll
            for (int r = 0; r < 4; ++r) acc2[i][j][r] = 0.f;

#pragma unroll
    for (int kk = 0; kk < 4; ++kk) {
        bf16x8 af[NI], bfv[4];
#pragma unroll
        for (int i = 0; i < NI; ++i)
            af[i] = *(const bf16x8*)(wpi + (size_t)(co0p + i * 16 + ll) * 128 + kk * 32 + lq * 8);
#pragma unroll
        for (int j = 0; j < 4; ++j) {
            const int pxl = j * 16 + ll;
            const int sw4 = ((pxl >> 2) & 3) << 4;
            bfv[j] = *(const bf16x8*)&Y[pxl * 128 + ((kk * 32 + lq * 8) ^ sw4)];
        }
#pragma unroll
        for (int i = 0; i < NI; ++i)
#pragma unroll
            for (int j = 0; j < 4; ++j)
                acc2[i][j] = __builtin_amdgcn_mfma_f32_16x16x32_bf16(af[i], bfv[j], acc2[i][j], 0, 0, 0);
    }

#pragma unroll
    for (int i = 0; i < NI; ++i) {
        const int cob = co0p + i * 16 + lq * 4;
        float b0v[4], gv[4], bv[4];
#pragma unroll
        for (int r = 0; r < 4; ++r) {
            b0v[r] = pi_b[cob + r];
            gv[r] = pig[cob + r];
            bv[r] = pibb[cob + r];
        }
#pragma unroll
        for (int j = 0; j < 4; ++j) {
            const int px = pbase + j * 16 + ll;
            float vv[4];
#pragma unroll
            for (int r = 0; r < 4; ++r)
                vv[r] = (acc2[i][j][r] + b0v[r]) * gv[r] + bv[r];
            if (PI_COUT == 256 && cob < 128) {
                u16x4 tp;
#pragma unroll
                for (int r = 0; r < 4; ++r) tp[r] = f2bf(vv[r]);
                *(u16x4*)(qTout + (((size_t)((b << 10) + px)) << 7) + cob) = tp;
            } else {
                const int cv = (PI_COUT == 256) ? cob - 128 : cob;
#pragma unroll
                for (int r = 0; r < 4; ++r)
                    vout[((size_t)(b * 128 + cv + r) << 10) + px] = f2bf(vv[r]);
            }
        }
    }
}

// ------------------------- cc 1x1 (160->128) + fused LayerNorm -------------
__global__ __launch_bounds__(256) void cc_ln_kernel(
    const unsigned short* __restrict__ xT, const unsigned short* __restrict__ wbf,
    const float* __restrict__ g, const float* __restrict__ bb,
    const float* __restrict__ ln_g, const float* __restrict__ ln_b,
    float* __restrict__ t, unsigned short* __restrict__ out_bf,
    unsigned short* __restrict__ outT)
{
    __shared__ float Ssum[4][64];
    __shared__ float Ssq[4][64];
    const int tid = threadIdx.x;
    const int b = blockIdx.x;
    const int n0 = blockIdx.y << 6;
    const int wid = tid >> 6, lane = tid & 63;
    const int ll = lane & 15, lq = lane >> 4;
    const unsigned short* xb = xT + (size_t)((b << 10) + n0) * 160;

    f32x4 acc[2][4];
#pragma unroll
    for (int i = 0; i < 2; ++i)
#pragma unroll
        for (int j = 0; j < 4; ++j)
#pragma unroll
            for (int r = 0; r < 4; ++r) acc[i][j][r] = 0.f;

#pragma unroll
    for (int kk = 0; kk < 5; ++kk) {
        bf16x8 af[2], bfv[4];
#pragma unroll
        for (int i = 0; i < 2; ++i)
            af[i] = *(const bf16x8*)(wbf + (size_t)(wid * 32 + i * 16 + ll) * 160 + kk * 32 + lq * 8);
#pragma unroll
        for (int j = 0; j < 4; ++j)
            bfv[j] = *(const bf16x8*)(xb + (size_t)(j * 16 + ll) * 160 + kk * 32 + lq * 8);
#pragma unroll
        for (int i = 0; i < 2; ++i)
#pragma unroll
            for (int j = 0; j < 4; ++j)
                acc[i][j] = __builtin_amdgcn_mfma_f32_16x16x32_bf16(af[i], bfv[j], acc[i][j], 0, 0, 0);
    }

    float vv[2][4][4];
    float sj[4] = {0.f, 0.f, 0.f, 0.f};
    float sqj[4] = {0.f, 0.f, 0.f, 0.f};
#pragma unroll
    for (int i = 0; i < 2; ++i) {
        const int cob = wid * 32 + i * 16 + lq * 4;
        float gv[4], bv[4];
#pragma unroll
        for (int r = 0; r < 4; ++r) { gv[r] = g[cob + r]; bv[r] = bb[cob + r]; }
#pragma unroll
        for (int j = 0; j < 4; ++j) {
            const int px = n0 + j * 16 + ll;
#pragma unroll
            for (int r = 0; r < 4; ++r) {
                const float val = fmaxf(acc[i][j][r] * gv[r] + bv[r], 0.f);
                vv[i][j][r] = val;
                t[((size_t)((b << 7) + cob + r) << 10) + px] = val;
                sj[j] += val;
                sqj[j] += val * val;
            }
        }
    }
#pragma unroll
    for (int j = 0; j < 4; ++j) {
        sj[j] += __shfl_xor(sj[j], 16);
        sj[j] += __shfl_xor(sj[j], 32);
        sqj[j] += __shfl_xor(sqj[j], 16);
        sqj[j] += __shfl_xor(sqj[j], 32);
    }
    if (lq == 0) {
#pragma unroll
        for (int j = 0; j < 4; ++j) {
            Ssum[wid][j * 16 + ll] = sj[j];
            Ssq[wid][j * 16 + ll] = sqj[j];
        }
    }
    __syncthreads();

    float mu[4], rst[4];
#pragma unroll
    for (int j = 0; j < 4; ++j) {
        const int p = j * 16 + ll;
        const float s = Ssum[0][p] + Ssum[1][p] + Ssum[2][p] + Ssum[3][p];
        const float sq = Ssq[0][p] + Ssq[1][p] + Ssq[2][p] + Ssq[3][p];
        mu[j] = s * 0.0078125f;
        rst[j] = rsqrtf(sq * 0.0078125f - mu[j] * mu[j] + 1e-5f);
    }

#pragma unroll
    for (int i = 0; i < 2; ++i) {
        const int cob = wid * 32 + i * 16 + lq * 4;
        float lg[4], lb[4];
#pragma unroll
        for (int r = 0; r < 4; ++r) { lg[r] = ln_g[cob + r]; lb[r] = ln_b[cob + r]; }
#pragma unroll
        for (int j = 0; j < 4; ++j) {
            const int px = n0 + j * 16 + ll;
            u16x4 tp;
#pragma unroll
            for (int r = 0; r < 4; ++r) {
                const float y = (vv[i][j][r] - mu[j]) * rst[j] * lg[r] + lb[r];
                const unsigned short h = f2bf(y);
                out_bf[((size_t)((b << 7) + cob + r) << 10) + px] = h;
                tp[r] = h;
            }
            *(u16x4*)(outT + (((size_t)((b << 10) + px)) << 7) + cob) = tp;
        }
    }
}

// ------------------------- Gram matrix + row sums (merged launch) ----------
__global__ __launch_bounds__(256) void gram_sums_kernel(
    const unsigned short* __restrict__ Xbf, float* __restrict__ G,
    float* __restrict__ S)
{
    __shared__ unsigned short Xs[128 * 128];
    const int tid = threadIdx.x;
    if (blockIdx.x >= 128) {
        const int b = blockIdx.x - 128;
        const int ch = tid >> 1, half = tid & 1;
        const unsigned short* p = Xbf + ((size_t)b << 17) + ((size_t)ch << 10) + half * 512;
        float s = 0.f;
#pragma unroll 4
        for (int i = 0; i < 64; ++i) {
            u16x8 v = *(const u16x8*)(p + i * 8);
#pragma unroll
            for (int e = 0; e < 8; ++e) s += bf2f(v[e]);
        }
        s += __shfl_xor(s, 1);
        if (half == 0) S[(b << 7) + ch] = s;
        return;
    }
    const int b = blockIdx.x >> 2;
    const int rg = blockIdx.x & 3;
    const int wid = tid >> 6, lane = tid & 63;
    const int lq = lane >> 4, ll = lane & 15;
    const unsigned short* Xb = Xbf + ((size_t)b << 17);

    f32x4 acc[2][2];
#pragma unroll
    for (int mi = 0; mi < 2; ++mi)
#pragma unroll
        for (int ci = 0; ci < 2; ++ci)
#pragma unroll
            for (int r = 0; r < 4; ++r) acc[mi][ci][r] = 0.f;

#pragma unroll 1
    for (int nt = 0; nt < 8; ++nt) {
        const int n0 = nt << 7;
#pragma unroll
        for (int p = 0; p < 8; ++p) {
            const int ch = (p << 4) + (tid >> 4);
            const int seg = (tid & 15) << 3;
            *(u16x8*)&Xs[ch * 128 + (seg ^ ((ch & 7) << 3))] =
                *(const u16x8*)(Xb + ((size_t)ch << 10) + n0 + seg);
        }
        __syncthreads();
#pragma unroll
        for (int ks = 0; ks < 4; ++ks) {
            bf16x8 af[2], bf_[2];
#pragma unroll
            for (int mi = 0; mi < 2; ++mi) {
                const int ar = (rg << 5) + mi * 16 + ll;
                af[mi] = *(const bf16x8*)&Xs[ar * 128 + ((ks * 32 + lq * 8) ^ ((ar & 7) << 3))];
            }
#pragma unroll
            for (int ci = 0; ci < 2; ++ci) {
                const int br = (wid << 5) + ci * 16 + ll;
                bf_[ci] = *(const bf16x8*)&Xs[br * 128 + ((ks * 32 + lq * 8) ^ ((br & 7) << 3))];
            }
#pragma unroll
            for (int mi = 0; mi < 2; ++mi)
#pragma unroll
                for (int ci = 0; ci < 2; ++ci)
                    acc[mi][ci] = __builtin_amdgcn_mfma_f32_16x16x32_bf16(
                        af[mi], bf_[ci], acc[mi][ci], 0, 0, 0);
        }
        __syncthreads();
    }
    float* Gb = G + ((size_t)b << 14);
#pragma unroll
    for (int mi = 0; mi < 2; ++mi)
#pragma unroll
        for (int ci = 0; ci < 2; ++ci)
#pragma unroll
            for (int r = 0; r < 4; ++r) {
                const int row = (rg << 5) + mi * 16 + lq * 4 + r;
                const int col = (wid << 5) + ci * 16 + ll;
                Gb[row * 128 + col] = acc[mi][ci][r];
            }
}

// ------------------------- GISSA stage-1 matrices (bf16 M1) ----------------
__global__ __launch_bounds__(64) void mats1_kernel(
    const float* __restrict__ G, const float* __restrict__ S,
    const float* __restrict__ qkv_w, const float* __restrict__ qkv_b,
    const float* __restrict__ g, const float* __restrict__ bb,
    unsigned short* __restrict__ M1, float* __restrict__ c1)
{
    const int lane = threadIdx.x;
    const int b = blockIdx.x >> 4, h = blockIdx.x & 15;
    const float* Gb = G + ((size_t)b << 14);
    const float* Sb = S + (b << 7);
    const int d = lane >> 3, e = lane & 7;
    const int qch = h * 8 + d, kch = 128 + h * 8 + e;
    const int qoff = (qch / 24) * 8, koff = (kch / 24) * 8;
    float wq[8], wk[8];
#pragma unroll
    for (int i = 0; i < 8; ++i) {
        wq[i] = qkv_w[qch * 8 + i];
        wk[i] = qkv_w[kch * 8 + i];
    }
    float s = 0.f;
#pragma unroll
    for (int i = 0; i < 8; ++i) {
        float gu = 0.f;
#pragma unroll
        for (int j = 0; j < 8; ++j) gu += Gb[(qoff + i) * 128 + koff + j] * wk[j];
        s += wq[i] * gu;
    }
    const float bq = qkv_b[qch], bk = qkv_b[kch];
    float swk = 0.f, swq = 0.f;
#pragma unroll
    for (int j = 0; j < 8; ++j) { swk += wk[j] * Sb[koff + j]; swq += wq[j] * Sb[qoff + j]; }
    s += bq * swk + bk * swq + 1024.f * bq * bk;
    s *= 0.35355339059327373f;
    float a = (s > 0.f) ? sqrtf(s + 1e-5f) : ((s < 0.f) ? -sqrtf(1e-5f - s) : 0.f);
    float mx = a;
    mx = fmaxf(mx, __shfl_xor(mx, 1));
    mx = fmaxf(mx, __shfl_xor(mx, 2));
    mx = fmaxf(mx, __shfl_xor(mx, 4));
    float p = __expf(a - mx);
    float den = p;
    den += __shfl_xor(den, 1);
    den += __shfl_xor(den, 2);
    den += __shfl_xor(den, 4);
    const float A = p / den;

    const int l = e;
    const int cp = d * 16 + h;
    float row[16];
#pragma unroll
    for (int j = 0; j < 16; ++j) row[j] = 0.f;
    float cacc = 0.f;
#pragma unroll
    for (int e2 = 0; e2 < 8; ++e2) {
        const float Ae = __shfl(A, d * 8 + e2);
        const int vch = 256 + h * 8 + e2;
        const int voff = (vch / 24) * 8;
        cacc += Ae * qkv_b[vch];
        if ((voff >> 4) == l) {
            const int base = voff & 15;
#pragma unroll
            for (int j = 0; j < 8; ++j) row[base + j] += Ae * qkv_w[vch * 8 + j];
        }
    }
    const int idc = h * 8 + d;
    if ((idc >> 4) == l) row[idc & 15] += 1.f;
    const float gg = g[cp];
    unsigned short* mrow = M1 + ((size_t)b << 14) + cp * 128 + l * 16;
#pragma unroll
    for (int j = 0; j < 16; ++j) mrow[j] = f2bf(gg * row[j]);
    if (l == 0) c1[(b << 7) + cp] = gg * cacc + bb[cp];
}

// ------------------------- GISSA stage-2 matrices (bf16 M2) ----------------
__global__ __launch_bounds__(256) void mats2_kernel(
    const float* __restrict__ G, const float* __restrict__ S,
    const float* __restrict__ qkv2_w, const float* __restrict__ qkv2_b,
    unsigned short* __restrict__ M2, float* __restrict__ c2)
{
    const int tid = threadIdx.x;
    const int b = blockIdx.x >> 3, d = blockIdx.x & 7;
    const float* Gb = G + ((size_t)b << 14);
    const float* Sb = S + (b << 7);
    const int h = tid >> 4, gq = tid & 15;
    const int q2ch = d * 16 + h, k2ch = 128 + d * 16 + gq;
    const int qoff = (q2ch / 48) * 16, koff = (k2ch / 48) * 16;
    float wq[16], wk[16];
#pragma unroll
    for (int i = 0; i < 16; ++i) {
        wq[i] = qkv2_w[q2ch * 16 + i];
        wk[i] = qkv2_w[k2ch * 16 + i];
    }
    float s = 0.f;
#pragma unroll
    for (int i = 0; i < 16; ++i) {
        float gu = 0.f;
#pragma unroll
        for (int j = 0; j < 16; ++j) gu += Gb[(qoff + i) * 128 + koff + j] * wk[j];
        s += wq[i] * gu;
    }
    const float bq = qkv2_b[q2ch], bk = qkv2_b[k2ch];
    float swk = 0.f, swq = 0.f;
#pragma unroll
    for (int j = 0; j < 16; ++j) { swk += wk[j] * Sb[koff + j]; swq += wq[j] * Sb[qoff + j]; }
    s += bq * swk + bk * swq + 1024.f * bq * bk;
    s *= 0.25f;
    float a = (s > 0.f) ? sqrtf(s + 1e-5f) : ((s < 0.f) ? -sqrtf(1e-5f - s) : 0.f);
    float mx = a;
    mx = fmaxf(mx, __shfl_xor(mx, 1));
    mx = fmaxf(mx, __shfl_xor(mx, 2));
    mx = fmaxf(mx, __shfl_xor(mx, 4));
    mx = fmaxf(mx, __shfl_xor(mx, 8));
    float p = __expf(a - mx);
    float den = p;
    den += __shfl_xor(den, 1);
    den += __shfl_xor(den, 2);
    den += __shfl_xor(den, 4);
    den += __shfl_xor(den, 8);
    const float A2 = p / den;

    const int l = gq;
    float row[8];
#pragma unroll
    for (int j = 0; j < 8; ++j) row[j] = 0.f;
    float cacc = 0.f;
#pragma unroll
    for (int g2 = 0; g2 < 16; ++g2) {
        const float Ag = __shfl(A2, (tid & 48) + g2);
        const int v2ch = 256 + d * 16 + g2;
        const int voff = (v2ch / 48) * 16;
        cacc += Ag * qkv2_b[v2ch];
        if ((l >> 1) == (voff >> 4)) {
            const int base = (l & 1) * 8;
#pragma unroll
            for (int j = 0; j < 8; ++j) row[j] += Ag * qkv2_w[v2ch * 16 + base + j];
        }
    }
    const int c = h * 8 + d;
    unsigned short* mrow = M2 + ((size_t)b << 14) + c * 128 + l * 8;
#pragma unroll
    for (int j = 0; j < 8; ++j) mrow[j] = f2bf(row[j]);
    if (l == 0) c2[(b << 7) + c] = cacc;
}

// ------------------------- apply1: y = M1 x + c1 (MFMA) --------------------
__global__ __launch_bounds__(256) void apply1_mfma_kernel(
    const unsigned short* __restrict__ curT, const unsigned short* __restrict__ M1bf,
    const float* __restrict__ c1, unsigned short* __restrict__ ybufb,
    unsigned short* __restrict__ yrbf, unsigned short* __restrict__ yrT)
{
    const int tid = threadIdx.x;
    const int b = blockIdx.x >> 3;
    const int n0 = (blockIdx.x & 7) << 7;
    const int wid = tid >> 6, lane = tid & 63;
    const int wr = wid >> 1, wc = wid & 1;
    const int ll = lane & 15, lq = lane >> 4;
    const unsigned short* Mb = M1bf + ((size_t)b << 14);
    const unsigned short* xb = curT + (((size_t)b << 10) + n0 + wc * 64) * 128;

    f32x4 acc[4][4];
#pragma unroll
    for (int i = 0; i < 4; ++i)
#pragma unroll
        for (int j = 0; j < 4; ++j)
#pragma unroll
            for (int r = 0; r < 4; ++r) acc[i][j][r] = 0.f;

#pragma unroll
    for (int kk = 0; kk < 4; ++kk) {
        bf16x8 af[4], bfv[4];
#pragma unroll
        for (int i = 0; i < 4; ++i)
            af[i] = *(const bf16x8*)(Mb + (size_t)(wr * 64 + i * 16 + ll) * 128 + kk * 32 + lq * 8);
#pragma unroll
        for (int j = 0; j < 4; ++j)
            bfv[j] = *(const bf16x8*)(xb + (size_t)(j * 16 + ll) * 128 + kk * 32 + lq * 8);
#pragma unroll
        for (int i = 0; i < 4; ++i)
#pragma unroll
            for (int j = 0; j < 4; ++j)
                acc[i][j] = __builtin_amdgcn_mfma_f32_16x16x32_bf16(af[i], bfv[j], acc[i][j], 0, 0, 0);
    }

#pragma unroll
    for (int i = 0; i < 4; ++i) {
        const int cob = wr * 64 + i * 16 + lq * 4;
        float c1v[4];
#pragma unroll
        for (int r = 0; r < 4; ++r) c1v[r] = c1[(b << 7) + cob + r];
#pragma unroll
        for (int j = 0; j < 4; ++j) {
            const int px = n0 + wc * 64 + j * 16 + ll;
            u16x4 tp;
#pragma unroll
            for (int r = 0; r < 4; ++r) {
                const int co = cob + r;
                const float v = acc[i][j][r] + c1v[r];
                const size_t oi = ((size_t)(b * 128 + co) << 10) + px;
                ybufb[oi] = f2bf(v);
                const unsigned short h = f2bf(fmaxf(v, 0.f));
                yrbf[oi] = h;
                tp[r] = h;
            }
            *(u16x4*)(yrT + (((size_t)b << 10) + px) * 128 + cob) = tp;
        }
    }
}

// ------------------------- apply2: t += M2 relu(y) + c2 + y (MFMA) ---------
__global__ __launch_bounds__(256) void apply2_mfma_kernel(
    const unsigned short* __restrict__ yrT, const unsigned short* __restrict__ M2bf,
    const float* __restrict__ c2, const unsigned short* __restrict__ ybufb,
    float* __restrict__ t)
{
    const int tid = threadIdx.x;
    const int b = blockIdx.x >> 3;
    const int n0 = (blockIdx.x & 7) << 7;
    const int wid = tid >> 6, lane = tid & 63;
    const int wr = wid >> 1, wc = wid & 1;
    const int ll = lane & 15, lq = lane >> 4;
    const unsigned short* Mb = M2bf + ((size_t)b << 14);
    const unsigned short* xb = yrT + (((size_t)b << 10) + n0 + wc * 64) * 128;

    f32x4 acc[4][4];
#pragma unroll
    for (int i = 0; i < 4; ++i)
#pragma unroll
        for (int j = 0; j < 4; ++j)
#pragma unroll
            for (int r = 0; r < 4; ++r) acc[i][j][r] = 0.f;

#pragma unroll
    for (int kk = 0; kk < 4; ++kk) {
        bf16x8 af[4], bfv[4];
#pragma unroll
        for (int i = 0; i < 4; ++i)
            af[i] = *(const bf16x8*)(Mb + (size_t)(wr * 64 + i * 16 + ll) * 128 + kk * 32 + lq * 8);
#pragma unroll
        for (int j = 0; j < 4; ++j)
            bfv[j] = *(const bf16x8*)(xb + (size_t)(j * 16 + ll) * 128 + kk * 32 + lq * 8);
#pragma unroll
        for (int i = 0; i < 4; ++i)
#pragma unroll
            for (int j = 0; j < 4; ++j)
                acc[i][j] = __builtin_amdgcn_mfma_f32_16x16x32_bf16(af[i], bfv[j], acc[i][j], 0, 0, 0);
    }

#pragma unroll
    for (int i = 0; i < 4; ++i) {
        const int cob = wr * 64 + i * 16 + lq * 4;
        float c2v[4];
#pragma unroll
        for (int r = 0; r < 4; ++r) c2v[r] = c2[(b << 7) + cob + r];
#pragma unroll
        for (int j = 0; j < 4; ++j) {
            const int px = n0 + wc * 64 + j * 16 + ll;
#pragma unroll
            for (int r = 0; r < 4; ++r) {
                const size_t oi = ((size_t)(b * 128 + cob + r) << 10) + px;
                t[oi] += acc[i][j][r] + c2v[r] + bf2f(ybufb[oi]);
            }
        }
    }
}

// ------------------------- fused LN2 + MLP via bf16 MFMA -------------------
__global__ __launch_bounds__(256) void mlp_mfma_kernel(
    float* __restrict__ t, const float* __restrict__ ln_g,
    const float* __restrict__ ln_b, const unsigned short* __restrict__ w1bf,
    const float* __restrict__ b1, const unsigned short* __restrict__ w2bf,
    const float* __restrict__ b2)
{
    __shared__ unsigned char lds[16384 + 65536];
    unsigned char* xnb = lds;
    unsigned char* hb = lds + 16384;

    const int tid = threadIdx.x;
    const int b = blockIdx.x >> 4;
    const int n0 = (blockIdx.x & 15) << 6;
    float* tb = t + ((size_t)b << 17) + n0;

    {
        const int px = tid >> 2, q = tid & 3;
        float v[32];
        float s = 0.f, sq = 0.f;
#pragma unroll
        for (int k = 0; k < 32; ++k) {
            float x = tb[((size_t)(q * 32 + k) << 10) + px];
            v[k] = x;
            s += x;
            sq += x * x;
        }
        s += __shfl_xor(s, 1); s += __shfl_xor(s, 2);
        sq += __shfl_xor(sq, 1); sq += __shfl_xor(sq, 2);
        const float mu = s * 0.0078125f;
        const float rstd = rsqrtf(sq * 0.0078125f - mu * mu + 1e-5f);
        const int sw = (px & 7) << 4;
#pragma unroll
        for (int cc = 0; cc < 4; ++cc) {
            u16x8 pk;
#pragma unroll
            for (int e = 0; e < 8; ++e) {
                int c = q * 32 + cc * 8 + e;
                float xv = (v[cc * 8 + e] - mu) * rstd * ln_g[c] + ln_b[c];
                pk[e] = f2bf(xv);
            }
            *(u16x8*)(xnb + px * 256 + ((q * 64 + cc * 16) ^ sw)) = pk;
        }
    }
    __syncthreads();

    const int wid = tid >> 6, lane = tid & 63;
    const int lr = lane & 15, lk = lane >> 4;

#pragma unroll 1
    for (int pass = 0; pass < 2; ++pass) {
        const int hidbase = (wid << 7) + (pass << 6);
        f32x4 acc[4][4];
#pragma unroll
        for (int i = 0; i < 4; ++i)
#pragma unroll
            for (int j = 0; j < 4; ++j)
#pragma unroll
                for (int r = 0; r < 4; ++r) acc[i][j][r] = 0.f;
#pragma unroll
        for (int kk = 0; kk < 4; ++kk) {
            bf16x8 af[4], bfr[4];
#pragma unroll
            for (int i = 0; i < 4; ++i)
                af[i] = *(const bf16x8*)(w1bf + (size_t)(hidbase + i * 16 + lr) * 128 + kk * 32 + lk * 8);
#pragma unroll
            for (int j = 0; j < 4; ++j) {
                const int px = j * 16 + lr;
                bfr[j] = *(const bf16x8*)(xnb + px * 256 + ((kk * 64 + lk * 16) ^ ((px & 7) << 4)));
            }
#pragma unroll
            for (int i = 0; i < 4; ++i)
#pragma unroll
                for (int j = 0; j < 4; ++j)
                    acc[i][j] = __builtin_amdgcn_mfma_f32_16x16x32_bf16(af[i], bfr[j], acc[i][j], 0, 0, 0);
        }
#pragma unroll
        for (int i = 0; i < 4; ++i) {
            const int hid0 = hidbase + i * 16 + lk * 4;
            float bi[4];
#pragma unroll
            for (int r = 0; r < 4; ++r) bi[r] = b1[hid0 + r];
#pragma unroll
            for (int j = 0; j < 4; ++j) {
                const int px = j * 16 + lr;
                u16x4 pk;
#pragma unroll
                for (int r = 0; r < 4; ++r) {
                    float x = acc[i][j][r] + bi[r];
                    float u = 1.5957691f * x * (1.f + 0.044715f * x * x);
                    float gv = x / (1.f + __expf(-u));
                    pk[r] = f2bf(gv);
                }
                *(u16x4*)(hb + px * 1024 + ((hid0 * 2) ^ ((px & 7) << 4))) = pk;
            }
        }
    }
    __syncthreads();

    f32x4 acc2[2][4];
#pragma unroll
    for (int i = 0; i < 2; ++i)
#pragma unroll
        for (int j = 0; j < 4; ++j)
#pragma unroll
            for (int r = 0; r < 4; ++r) acc2[i][j][r] = 0.f;
#pragma unroll 2
    for (int ks = 0; ks < 16; ++ks) {
        bf16x8 af[2], bfr[4];
#pragma unroll
        for (int i = 0; i < 2; ++i)
            af[i] = *(const bf16x8*)(w2bf + (size_t)((wid << 5) + i * 16 + lr) * 512 + ks * 32 + lk * 8);
#pragma unroll
        for (int j = 0; j < 4; ++j) {
            const int px = j * 16 + lr;
            bfr[j] = *(const bf16x8*)(hb + px * 1024 + ((ks * 64 + lk * 16) ^ ((px & 7) << 4)));
        }
#pragma unroll
        for (int i = 0; i < 2; ++i)
#pragma unroll
            for (int j = 0; j < 4; ++j)
                acc2[i][j] = __builtin_amdgcn_mfma_f32_16x16x32_bf16(af[i], bfr[j], acc2[i][j], 0, 0, 0);
    }
#pragma unroll
    for (int i = 0; i < 2; ++i) {
        const int cb = (wid << 5) + i * 16 + lk * 4;
        float b2v[4];
#pragma unroll
        for (int r = 0; r < 4; ++r) b2v[r] = b2[cb + r];
#pragma unroll
        for (int j = 0; j < 4; ++j) {
            const int px = j * 16 + lr;
#pragma unroll
            for (int r = 0; r < 4; ++r) {
                const size_t off = ((size_t)(cb + r) << 10) + px;
                tb[off] += acc2[i][j][r] + b2v[r];
            }
        }
    }
}

// ------------------------- flash SWSA + fused po GEMM (512 thr, dbuf) ------
// 128 q-rows per block (8 waves x 16); grid 256. K/V double-buffered in
// 128 KB LDS: tile t+1 staged while tile t computes; 2 barriers/tile.
// REUSE==0: online softmax + stats out. REUSE==1: stats-driven direct exp.
template <int REUSE>
__global__ __launch_bounds__(512) void swsa_po_kernel(
    const unsigned short* __restrict__ qT, const unsigned short* __restrict__ vbf,
    const unsigned short* __restrict__ wpo, const float* __restrict__ po_b,
    const unsigned short* __restrict__ resT,
    unsigned short* __restrict__ outT, unsigned short* __restrict__ outB,
    float fscale, float* __restrict__ statsM, float* __restrict__ statsL)
{
    __shared__ unsigned short K_lds[2][128 * 128];
    __shared__ unsigned short V_lds[2][128 * 128];
    const int tid = threadIdx.x;
    const int b = blockIdx.x & 31;
    const int n0 = (blockIdx.x >> 5) << 7;
    const int wid = tid >> 6, lane = tid & 63;     // wid 0..7
    const int lq = lane >> 4, ll = lane & 15;
    const unsigned short* qTb = qT + ((size_t)b << 17);
    const unsigned short* vb = vbf + ((size_t)b << 17);
    const int rowbase = n0 + wid * 16 + lq * 4;    // this lane's 4 q-rows

#define SWSA_STAGE(BUF, M0V)                                                  \
    for (int ch = tid; ch < 2048; ch += 512) {                                \
        const int rr = ch >> 4, e0 = (ch & 15) << 3;                          \
        const int sw = (rr & 7) << 3;                                         \
        *(u16x8*)&K_lds[BUF][rr * 128 + (e0 ^ sw)] =                          \
            *(const u16x8*)(qTb + ((size_t)((M0V) + rr) << 7) + e0);          \
        *(u16x8*)&V_lds[BUF][rr * 128 + (e0 ^ sw)] =                          \
            *(const u16x8*)(vb + ((size_t)rr << 10) + (M0V) + e0);            \
    }

    bf16x8 aq[4];
    {
        const int row = n0 + wid * 16 + ll;
#pragma unroll
        for (int kk = 0; kk < 4; ++kk)
            aq[kk] = *(const bf16x8*)(qTb + ((size_t)row << 7) + kk * 32 + lq * 8);
    }

    float mrun[4], lrun[4];
    if (REUSE) {
#pragma unroll
        for (int r = 0; r < 4; ++r) {
            mrun[r] = statsM[(b << 10) + rowbase + r];
            lrun[r] = statsL[(b << 10) + rowbase + r];
        }
    } else {
#pragma unroll
        for (int i = 0; i < 4; ++i) { mrun[i] = -INFINITY; lrun[i] = 0.f; }
    }
    f32x4 yacc[8];
#pragma unroll
    for (int cj = 0; cj < 8; ++cj)
#pragma unroll
        for (int r = 0; r < 4; ++r) yacc[cj][r] = 0.f;

    // prologue: stage tile 0 into buffer 0
    SWSA_STAGE(0, 0)

#pragma unroll 1
    for (int mt = 0; mt < 8; ++mt) {
        const int cur = mt & 1;
        __syncthreads();   // stage(mt) complete; PV(mt-1) reads complete

        // prefetch tile mt+1 into the other buffer (overlaps compute below)
        if (mt < 7) { SWSA_STAGE(1 - cur, (mt + 1) << 7) }

        // QK^T from K_lds[cur]
        f32x4 sacc[8];
#pragma unroll
        for (int j = 0; j < 8; ++j)
#pragma unroll
            for (int r = 0; r < 4; ++r) sacc[j][r] = 0.f;
#pragma unroll
        for (int j = 0; j < 8; ++j) {
            const int ml = j * 16 + ll;
            const int swk = (ml & 7) << 3;
#pragma unroll
            for (int kk = 0; kk < 4; ++kk) {
                bf16x8 bk = *(const bf16x8*)&K_lds[cur][ml * 128 + ((kk * 32 + lq * 8) ^ swk)];
                sacc[j] = __builtin_amdgcn_mfma_f32_16x16x32_bf16(aq[kk], bk, sacc[j], 0, 0, 0);
            }
        }
        __syncthreads();   // K reads done; K region of buf[cur] becomes P

        if (REUSE) {
#pragma unroll
            for (int r = 0; r < 4; ++r) {
                const int nbw = wid * 16 + lq * 4 + r;
                const int sw4 = ((nbw >> 2) & 3) << 4;
                const float mn = mrun[r];
#pragma unroll
                for (int j = 0; j < 8; ++j) {
                    float p = __expf(sacc[j][r] * 0.08838834764831845f - mn);
                    K_lds[cur][nbw * 128 + ((j * 16 + ll) ^ sw4)] = f2bf(p);
                }
            }
        } else {
            float pmax[4];
#pragma unroll
            for (int i = 0; i < 4; ++i) pmax[i] = -INFINITY;
#pragma unroll
            for (int j = 0; j < 8; ++j)
#pragma unroll
                for (int r = 0; r < 4; ++r) {
                    float s = sacc[j][r] * 0.08838834764831845f;
                    sacc[j][r] = s;
                    pmax[r] = fmaxf(pmax[r], s);
                }
            float alpha[4];
#pragma unroll
            for (int i = 0; i < 4; ++i) {
                float m = pmax[i];
                m = fmaxf(m, __shfl_xor(m, 1));
                m = fmaxf(m, __shfl_xor(m, 2));
                m = fmaxf(m, __shfl_xor(m, 4));
                m = fmaxf(m, __shfl_xor(m, 8));
                const float mn = fmaxf(mrun[i], m);
                alpha[i] = __expf(mrun[i] - mn);
                mrun[i] = mn;
            }
            float psum[4];
#pragma unroll
            for (int r = 0; r < 4; ++r) {
                const int nbw = wid * 16 + lq * 4 + r;
                const int sw4 = ((nbw >> 2) & 3) << 4;
                const float mn = mrun[r];
                float ps = 0.f;
#pragma unroll
                for (int j = 0; j < 8; ++j) {
                    float p = __expf(sacc[j][r] - mn);
                    ps += p;
                    K_lds[cur][nbw * 128 + ((j * 16 + ll) ^ sw4)] = f2bf(p);
                }
                psum[r] = ps;
            }
#pragma unroll
            for (int i = 0; i < 4; ++i) {
                float s = psum[i];
                s += __shfl_xor(s, 1);
                s += __shfl_xor(s, 2);
                s += __shfl_xor(s, 4);
                s += __shfl_xor(s, 8);
                lrun[i] = lrun[i] * alpha[i] + s;
            }
#pragma unroll
            for (int cj = 0; cj < 8; ++cj)
#pragma unroll
                for (int r = 0; r < 4; ++r) yacc[cj][r] *= alpha[r];
        }

        // PV: A = P (own rows, intra-wave dependency), B = V from LDS
        bf16x8 ap[4];
        {
            const int nb = wid * 16 + ll;
            const int sw4 = ((nb >> 2) & 3) << 4;
#pragma unroll
            for (int mk = 0; mk < 4; ++mk)
                ap[mk] = *(const bf16x8*)&K_lds[cur][nb * 128 + ((mk * 32 + lq * 8) ^ sw4)];
        }
#pragma unroll
        for (int cj = 0; cj < 8; ++cj) {
            const int cl = cj * 16 + ll;
            const int sw = (cl & 7) << 3;
#pragma unroll
            for (int mk = 0; mk < 4; ++mk) {
                bf16x8 bv = *(const bf16x8*)&V_lds[cur][cl * 128 + ((mk * 32 + lq * 8) ^ sw)];
                yacc[cj] = __builtin_amdgcn_mfma_f32_16x16x32_bf16(ap[mk], bv, yacc[cj], 0, 0, 0);
            }
        }
    }
    __syncthreads();   // last PV reads done

    if (!REUSE) {
        if (ll == 0) {
#pragma unroll
            for (int r = 0; r < 4; ++r) {
                statsM[(b << 10) + rowbase + r] = mrun[r];
                statsL[(b << 10) + rowbase + r] = lrun[r];
            }
        }
    }

    // ---- fused po: yv (normalized) -> K_lds[0] [128px][128c], then GEMM ---
    {
        float inv[4];
#pragma unroll
        for (int r = 0; r < 4; ++r) inv[r] = fscale / lrun[r];
        const int rw0 = wid * 16 + lq * 4;
#pragma unroll
        for (int cj = 0; cj < 8; ++cj) {
            const int c = cj * 16 + ll;
#pragma unroll
            for (int r = 0; r < 4; ++r) {
                const int row = rw0 + r;
                const int sw4 = ((row >> 2) & 3) << 4;
                K_lds[0][row * 128 + (c ^ sw4)] = f2bf(yacc[cj][r] * inv[r]);
            }
        }
    }
    __syncthreads();

    // po GEMM: each wave computes 16 co x 128 px.
    f32x4 acc2[8];
#pragma unroll
    for (int j = 0; j < 8; ++j)
#pragma unroll
        for (int r = 0; r < 4; ++r) acc2[j][r] = 0.f;
#pragma unroll
    for (int kk = 0; kk < 4; ++kk) {
        bf16x8 af = *(const bf16x8*)(wpo + (size_t)(wid * 16 + ll) * 128 + kk * 32 + lq * 8);
#pragma unroll
        for (int j = 0; j < 8; ++j) {
            const int row = j * 16 + ll;
            const int sw4 = ((row >> 2) & 3) << 4;
            bf16x8 bfv = *(const bf16x8*)&K_lds[0][row * 128 + ((kk * 32 + lq * 8) ^ sw4)];
            acc2[j] = __builtin_amdgcn_mfma_f32_16x16x32_bf16(af, bfv, acc2[j], 0, 0, 0);
        }
    }

    {
        const int cob = wid * 16 + lq * 4;
        float pob[4];
#pragma unroll
        for (int r = 0; r < 4; ++r) pob[r] = po_b[cob + r];
#pragma unroll
        for (int j = 0; j < 8; ++j) {
            const int px = n0 + j * 16 + ll;
            const size_t rowT = ((size_t)((b << 10) + px)) << 7;
            u16x4 rv = *(const u16x4*)(resT + rowT + cob);
            float vv[4];
#pragma unroll
            for (int r = 0; r < 4; ++r)
                vv[r] = acc2[j][r] + pob[r] + bf2f(rv[r]);
            if (outT) {
                u16x4 tp;
#pragma unroll
                for (int r = 0; r < 4; ++r) tp[r] = f2bf(vv[r]);
                *(u16x4*)(outT + rowT + cob) = tp;
            }
            if (outB) {
#pragma unroll
                for (int r = 0; r < 4; ++r)
                    outB[((size_t)(b * 128 + cob + r) << 10) + px] = f2bf(vv[r]);
            }
        }
    }
#undef SWSA_STAGE
}

// ------------------------- final: mean (stage 1) ---------------------------
// xc fp32 (ch-major), xp bf16 (ch-major)
__global__ __launch_bounds__(256) void mean_kernel(
    const float* __restrict__ xc, const unsigned short* __restrict__ xp,
    const float* __restrict__ lamuda, float* __restrict__ meanb)
{
    const int wid = threadIdx.x >> 6, lane = threadIdx.x & 63;
    const int row = (blockIdx.x << 2) + wid;
    const float lmd = 1.f / (1.f + __expf(-lamuda[0]));
    const float* a = xc + ((size_t)row << 10) + (lane << 2);
    const unsigned short* d = xp + ((size_t)row << 10) + (lane << 4);
    float s = 0.f;
#pragma unroll
    for (int i = 0; i < 4; ++i) {
        float4 va = *(const float4*)(a + (i << 8));
        s += lmd * (va.x + va.y + va.z + va.w);
    }
    float sp = 0.f;
#pragma unroll
    for (int i = 0; i < 2; ++i) {
        u16x8 v = *(const u16x8*)(d + i * 8);
#pragma unroll
        for (int e = 0; e < 8; ++e) sp += bf2f(v[e]);
    }
    s += (1.f - lmd) * sp;
#pragma unroll
    for (int o = 1; o < 64; o <<= 1) s += __shfl_xor(s, o);
    if (lane == 0) meanb[row] = s * (1.f / 1024.f);
}

// ------------------------- final: fc (stage 2) -----------------------------
__global__ __launch_bounds__(256) void fc_kernel(
    const float* __restrict__ meanb, const float* __restrict__ fc_w,
    float* __restrict__ outp)
{
    const int idx = blockIdx.x * 256 + threadIdx.x;
    if (idx >= 512) return;
    const int b = idx >> 4, o = idx & 15;
    float s = 0.f;
#pragma unroll 4
    for (int c = 0; c < 128; ++c) s += fc_w[o * 128 + c] * meanb[b * 128 + c];
    outp[b * 16 + o] = s;
}

// ---------------------------------------------------------------------------
extern "C" void kernel_launch(void* const* d_in, const int* in_sizes, int n_in,
                              void* d_out, int out_size, void* d_ws, size_t ws_size,
                              hipStream_t stream)
{
    (void)in_sizes; (void)n_in; (void)out_size; (void)ws_size;

    const float* x       = (const float*)d_in[0];
    const float* ssfe_w  = (const float*)d_in[1];
    const float* ssfe_g  = (const float*)d_in[2];
    const float* ssfe_b  = (const float*)d_in[3];
    const float* cc_w    = (const float*)d_in[4];
    const float* cc_g    = (const float*)d_in[5];
    const float* cc_b    = (const float*)d_in[6];
    const float* ln1_g   = (const float*)d_in[7];
    const float* ln1_b   = (const float*)d_in[8];
    const float* qkv_w   = (const float*)d_in[9];
    const float* qkv_b   = (const float*)d_in[10];
    const float* gbn_g   = (const float*)d_in[11];
    const float* gbn_b   = (const float*)d_in[12];
    const float* qkv2_w  = (const float*)d_in[13];
    const float* qkv2_b  = (const float*)d_in[14];
    const float* ln2_g   = (const float*)d_in[15];
    const float* ln2_b   = (const float*)d_in[16];
    const float* mlp_w1  = (const float*)d_in[17];
    const float* mlp_b1  = (const float*)d_in[18];
    const float* mlp_w2  = (const float*)d_in[19];
    const float* mlp_b2  = (const float*)d_in[20];
    const float* cs_w    = (const float*)d_in[21];
    const float* cs_g    = (const float*)d_in[22];
    const float* cs_b    = (const float*)d_in[23];
    const float* lfe0_w  = (const float*)d_in[24];
    const float* lfe0_g  = (const float*)d_in[25];
    const float* lfe0_b  = (const float*)d_in[26];
    const float* s0_pi_w = (const float*)d_in[27];
    const float* s0_pi_b = (const float*)d_in[28];
    const float* s0_bn_g = (const float*)d_in[29];
    const float* s0_bn_b = (const float*)d_in[30];
    const float* s0_po_w = (const float*)d_in[31];
    const float* s0_po_b = (const float*)d_in[32];
    const float* lfe1_w  = (const float*)d_in[33];
    const float* lfe1_g  = (const float*)d_in[34];
    const float* lfe1_b  = (const float*)d_in[35];
    const float* s1_pi_w = (const float*)d_in[36];
    const float* s1_pi_b = (const float*)d_in[37];
    const float* s1_bn_g = (const float*)d_in[38];
    const float* s1_bn_b = (const float*)d_in[39];
    const float* s1_po_w = (const float*)d_in[40];
    const float* s1_po_b = (const float*)d_in[41];
    const float* lamuda  = (const float*)d_in[42];
    const float* fc_w    = (const float*)d_in[43];
    float* out = (float*)d_out;
    float* ws = (float*)d_ws;

    // workspace regions (floats)
    float* xs = ws;                    // scratch (wlfe1 weights)
    float* t  = ws + 4718592;          // (B,128,N) residual stream / xc
    float* Qr = ws + 13107200;         // 12.58M floats, phase-overlaid
    float* P2 = ws + 25690112;         // (B,128,N)
    float* P3 = ws + 29884416;         // (B,128,N)

    // stem phase (Qr head): xT0 dead before cc_ln writes curbf/curT
    unsigned short* xT0 = (unsigned short*)Qr;                 // (B,1024,160)

    // GISSA phase (Qr)
    unsigned short* curbf = (unsigned short*)Qr;               // (B,128,1024)
    unsigned short* curT  = (unsigned short*)(Qr + 2097152);   // (B,1024,128)
    unsigned short* yrbf  = (unsigned short*)(Qr + 4194304);   // (B,128,1024)
    unsigned short* yrT   = (unsigned short*)(Qr + 6291456);   // (B,1024,128)
    unsigned short* xsT   = (unsigned short*)(Qr + 8388608);   // (B,1024,160)
    unsigned short* ybufb = (unsigned short*)P2;               // (B,128,1024) bf16

    // swsa phase (Qr overlay) — R15-proven aliasing
    unsigned short* xpT   = (unsigned short*)Qr;               // cs->lfe0 (+res)
    unsigned short* v0    = (unsigned short*)(Qr + 2097152);
    unsigned short* v1    = (unsigned short*)(Qr + 4194304);   // pi1->swsa1
    unsigned short* xp3T  = (unsigned short*)(Qr + 6291456);   // swsa0(po0)->lfe1 (+res)
    unsigned short* xp2T  = (unsigned short*)(Qr + 8388608);   // lfe0->pi0, swsa0-res
    unsigned short* xp4T  = (unsigned short*)(Qr + 8388608);   // lfe1->pi1, swsa1-res
    // qT0 lives in P2 (free after GISSA; ybufb dead after apply2)
    unsigned short* qT0   = (unsigned short*)P2;               // (B,1024,128)
    // swsa1 bf16 ch-major output (mean reads it); P3 scratch is dead by then
    unsigned short* xpb   = (unsigned short*)P3;               // (B,128,1024) bf16

    // permanently-free Qr tail: packed 1x1+mlp weights + meanb + swsa stats
    unsigned short* linw  = (unsigned short*)(Qr + 11010048);  // 233472 u16
    unsigned short* wcc   = linw;                 // [128][160]
    unsigned short* wpi0  = linw + 20480;         // [256][128]
    unsigned short* wpi1  = linw + 53248;         // [128][128]
    unsigned short* wpo0  = linw + 69632;         // [128][128]
    unsigned short* wpo1  = linw + 86016;         // [128][128]
    unsigned short* w1bf  = linw + 102400;        // [512][128]
    unsigned short* w2bf  = linw + 167936;        // [128][512]
    float* meanb  = Qr + 11200000;                // 4096 floats
    float* statsM = Qr + 11204096;                // 32768 floats (B*N)
    float* statsL = Qr + 11236864;                // 32768 floats

    // small mats in P3 (dead before swsa1 writes P3)
    float* Gbuf  = P3 + 1048576;
    float* Sbuf  = P3 + 1572864;
    unsigned short* M1bf = (unsigned short*)(P3 + 1576960);
    float* c1buf = P3 + 1839104;
    unsigned short* M2bf = (unsigned short*)(P3 + 1843200);
    float* c2buf = P3 + 2105344;

    unsigned short* wssfe = (unsigned short*)P3;             // 9*144*160
    unsigned short* wcs   = (unsigned short*)(P3 + 131072);  // 9*128*160
    unsigned short* wlfe0 = (unsigned short*)(P3 + 262144);  // 9*128*128
    unsigned short* wlfe1 = (unsigned short*)xs;             // 9*128*128

    const dim3 blk(256);

    prepack_convs<<<dim3((686592 + 255) / 256), blk, 0, stream>>>(
        ssfe_w, cs_w, lfe0_w, lfe1_w, wssfe, wcs, wlfe0, wlfe1);
    prepack_lins<<<dim3((233472 + 255) / 256), blk, 0, stream>>>(
        cc_w, s0_pi_w, s1_pi_w, s0_po_w, s1_po_w, mlp_w1, mlp_w2, linw);

    // x -> bf16 px-major; xsT = cbr3(xT0, ssfe)
    cvt_xT_kernel<<<dim3(32, 16), blk, 0, stream>>>(x, xT0);
    conv3x3_ssfe_kernel<<<dim3(32, 16), blk, 0, stream>>>(
        xT0, wssfe, ssfe_g, ssfe_b, xsT);

    // ---- cc 1x1 + fused LN1: t (fp32), curbf, curT ----
    cc_ln_kernel<<<dim3(32, 16), blk, 0, stream>>>(
        xsT, wcc, cc_g, cc_b, ln1_g, ln1_b, t, curbf, curT);

    // ---- GISSA via Gram trick ----
    gram_sums_kernel<<<dim3(160), blk, 0, stream>>>(curbf, Gbuf, Sbuf);
    mats1_kernel<<<dim3(512), dim3(64), 0, stream>>>(Gbuf, Sbuf, qkv_w, qkv_b, gbn_g, gbn_b, M1bf, c1buf);
    apply1_mfma_kernel<<<dim3(256), blk, 0, stream>>>(curT, M1bf, c1buf, ybufb, yrbf, yrT);
    gram_sums_kernel<<<dim3(160), blk, 0, stream>>>(yrbf, Gbuf, Sbuf);
    mats2_kernel<<<dim3(256), blk, 0, stream>>>(Gbuf, Sbuf, qkv2_w, qkv2_b, M2bf, c2buf);
    apply2_mfma_kernel<<<dim3(256), blk, 0, stream>>>(yrT, M2bf, c2buf, ybufb, t);

    mlp_mfma_kernel<<<dim3(512), blk, 0, stream>>>(t, ln2_g, ln2_b, w1bf, mlp_b1, w2bf, mlp_b2);

    // ---- xp branch, all-bf16 ----
    conv3x3_lds_kernel<160><<<dim3(32, 16), blk, 0, stream>>>(
        xsT, wcs, cs_g, cs_b, nullptr, xpT, 128);
    conv3x3_pi_kernel<256><<<dim3(32, 16), blk, 0, stream>>>(
        xpT, wlfe0, lfe0_g, lfe0_b, xpT, xp2T,
        wpi0, s0_pi_b, s0_bn_g, s0_bn_b, qT0, v0);
    // swsa0 + po0 (+stats): xp3T = po0(softmax(qq^T)v0) + po_b + xp2T
    swsa_po_kernel<0><<<dim3(256), dim3(512), 0, stream>>>(
        qT0, v0, wpo0, s0_po_b, xp2T, xp3T, nullptr, 1.0f, statsM, statsL);
    conv3x3_pi_kernel<128><<<dim3(32, 16), blk, 0, stream>>>(
        xp3T, wlfe1, lfe1_g, lfe1_b, xp3T, xp4T,
        wpi1, s1_pi_b, s1_bn_g, s1_bn_b, nullptr, v1);
    // swsa1 + po1 (stats reuse): xpb (bf16 ch-major) = po1(...) + po_b + xp4T
    swsa_po_kernel<1><<<dim3(256), dim3(512), 0, stream>>>(
        qT0, v1, wpo1, s1_po_b, xp4T, nullptr, xpb, 0.08838834764831845f, statsM, statsL);

    mean_kernel<<<dim3(1024), blk, 0, stream>>>(t, xpb, lamuda, meanb);
    fc_kernel<<<dim3(2), blk, 0, stream>>>(meanb, fc_w, out);
}

// Round 22
// 369.061 us; speedup vs baseline: 1.6142x; 1.0187x over previous
//
#include <hip/hip_runtime.h>
#include <math.h>

// ---------------------------------------------------------------------------
// EATN forward. Layout: activations (B, C, N), N = 1024 contiguous.
// B=32, C=128 (144 stem), HEADS=16, HD=8.
// Round 22: conv kernels widened to 128-px blocks (512 thr, 194-row halo
// stage = 1.52x redundancy vs 2.03x; half the blocks; weight re-reads
// halved). swsa/GISSA/mlp identical to R21.
// ---------------------------------------------------------------------------

static constexpr int NPIX = 1024;

typedef __attribute__((ext_vector_type(8))) short bf16x8;
typedef __attribute__((ext_vector_type(4))) float f32x4;
typedef __attribute__((ext_vector_type(8))) unsigned short u16x8;
typedef __attribute__((ext_vector_type(4))) unsigned short u16x4;

static __device__ __forceinline__ unsigned short f2bf(float f) {
    unsigned u = __builtin_bit_cast(unsigned, f);
    unsigned r = (u + 0x7fffu + ((u >> 16) & 1u)) >> 16;
    return (unsigned short)r;
}
static __device__ __forceinline__ float bf2f(unsigned short u) {
    unsigned v = ((unsigned)u) << 16;
    return __builtin_bit_cast(float, v);
}

// ------------------------- conv weight prepack (all 4, one launch) ---------
__global__ __launch_bounds__(256) void prepack_convs(
    const float* __restrict__ ssfe_w, const float* __restrict__ cs_w,
    const float* __restrict__ lfe0_w, const float* __restrict__ lfe1_w,
    unsigned short* __restrict__ wssfe, unsigned short* __restrict__ wcs,
    unsigned short* __restrict__ wlfe0, unsigned short* __restrict__ wlfe1)
{
    int idx = blockIdx.x * 256 + threadIdx.x;
    const float* src;
    unsigned short* dst;
    int k, Cout, CIN, CINP;
    if (idx < 207360) {
        src = ssfe_w; dst = wssfe; k = idx; Cout = 144; CIN = 144; CINP = 160;
    } else if (idx < 391680) {
        src = cs_w; dst = wcs; k = idx - 207360; Cout = 128; CIN = 144; CINP = 160;
    } else if (idx < 539136) {
        src = lfe0_w; dst = wlfe0; k = idx - 391680; Cout = 128; CIN = 128; CINP = 128;
    } else if (idx < 686592) {
        src = lfe1_w; dst = wlfe1; k = idx - 539136; Cout = 128; CIN = 128; CINP = 128;
    } else return;
    int ci = k % CINP;
    int rem = k / CINP;
    int co = rem % Cout;
    int tap = rem / Cout;
    float v = (ci < CIN) ? src[((size_t)co * CIN + ci) * 9 + tap] : 0.f;
    dst[k] = f2bf(v);
}

// ------------------------- 1x1 + mlp weights prepack (one launch) ----------
__global__ __launch_bounds__(256) void prepack_lins(
    const float* __restrict__ cc_w, const float* __restrict__ pi0_w,
    const float* __restrict__ pi1_w, const float* __restrict__ po0_w,
    const float* __restrict__ po1_w, const float* __restrict__ w1,
    const float* __restrict__ w2, unsigned short* __restrict__ o)
{
    int idx = blockIdx.x * 256 + threadIdx.x;
    if (idx >= 233472) return;
    float v;
    if (idx < 20480) {
        int ci = idx % 160, co = idx / 160;
        v = (ci < 144) ? cc_w[co * 144 + ci] : 0.f;
    } else if (idx < 53248) {
        v = pi0_w[idx - 20480];
    } else if (idx < 69632) {
        v = pi1_w[idx - 53248];
    } else if (idx < 86016) {
        v = po0_w[idx - 69632];
    } else if (idx < 102400) {
        v = po1_w[idx - 86016];
    } else if (idx < 167936) {
        v = w1[idx - 102400];
    } else {
        v = w2[idx - 167936];
    }
    o[idx] = f2bf(v);
}

// ------------------------- x fp32 (B,144,1024) -> bf16 px-major (B,1024,160)
__global__ __launch_bounds__(256) void cvt_xT_kernel(
    const float* __restrict__ x, unsigned short* __restrict__ xT0)
{
    __shared__ unsigned short T[64 * 168];
    const int tid = threadIdx.x;
    const int b = blockIdx.x;
    const int px0 = blockIdx.y << 6;
    const float* xb = x + ((size_t)b * 144 << 10) + px0;

#pragma unroll 1
    for (int idx = tid; idx < 72 * 64; idx += 256) {
        const int c2 = idx >> 6, px = idx & 63;
        float a = xb[((size_t)(2 * c2) << 10) + px];
        float c = xb[((size_t)(2 * c2 + 1) << 10) + px];
        *(unsigned*)&T[px * 168 + 2 * c2] =
            (unsigned)f2bf(a) | ((unsigned)f2bf(c) << 16);
    }
#pragma unroll 1
    for (int idx = tid; idx < 64 * 8; idx += 256) {
        const int px = idx >> 3, pr = idx & 7;
        *(unsigned*)&T[px * 168 + 144 + pr * 2] = 0u;
    }
    __syncthreads();

#pragma unroll 1
    for (int idx = tid; idx < 64 * 20; idx += 256) {
        const int px = idx / 20;
        const int chunk = idx - px * 20;
        *(u16x8*)(xT0 + ((size_t)((b << 10) + px0 + px)) * 160 + chunk * 8) =
            *(const u16x8*)&T[px * 168 + chunk * 8];
    }
}

// ------------------------- ssfe conv: 128-px blocks (512 thr) --------------
// waves 0..5: (h = wid/3, co-band = wid%3 of 48); waves 6,7: pad ch 144..159.
__global__ __launch_bounds__(512) void conv3x3_ssfe_kernel(
    const unsigned short* __restrict__ xT,
    const unsigned short* __restrict__ wrep,   // [9][144][160]
    const float* __restrict__ g, const float* __restrict__ bb,
    unsigned short* __restrict__ outT)
{
    constexpr int CINP = 160, PITCH = 168, NCHK = 20;
    __shared__ unsigned short X[194 * PITCH];
    const int tid = threadIdx.x;
    const int b = blockIdx.x, gr = blockIdx.y;
    const int pbase = gr << 7;
    const int gbase = pbase - 33;
    const int wid = tid >> 6, lane = tid & 63;
    const int ll = lane & 15, lq = lane >> 4;
    const unsigned short* xb = xT + ((size_t)b << 10) * CINP;

#pragma unroll 1
    for (int idx = tid; idx < 194 * NCHK; idx += 512) {
        const int row = idx / NCHK;
        const int chunk = idx - row * NCHK;
        const int gp = gbase + row;
        u16x8 v = {};
        if (gp >= 0 && gp < 1024)
            v = *(const u16x8*)(xb + (size_t)gp * CINP + chunk * 8);
        *(u16x8*)&X[row * PITCH + chunk * 8] = v;
    }
    __syncthreads();

    if (wid >= 6) {
        const int poff = (wid - 6) * 64;
#pragma unroll
        for (int j = 0; j < 4; ++j) {
            const int px = pbase + poff + j * 16 + ll;
            u16x4 z = {};
            *(u16x4*)(outT + ((size_t)((b << 10) + px)) * 160 + 144 + lq * 4) = z;
        }
        return;
    }

    const int h = wid / 3;
    const int poff = h * 64;
    const int co0w = (wid - h * 3) * 48;
    f32x4 acc[3][4];
#pragma unroll
    for (int i = 0; i < 3; ++i)
#pragma unroll
        for (int j = 0; j < 4; ++j)
#pragma unroll
            for (int r = 0; r < 4; ++r) acc[i][j][r] = 0.f;

#pragma unroll
    for (int tap = 0; tap < 9; ++tap) {
        const int soff = (tap / 3) * 32 + (tap % 3);
        const int dx = tap % 3;
#pragma unroll
        for (int kc = 0; kc < CINP / 32; ++kc) {
            bf16x8 bfv[4];
#pragma unroll
            for (int j = 0; j < 4; ++j) {
                const int p = poff + j * 16 + ll;
                bf16x8 v = *(const bf16x8*)&X[(p + soff) * PITCH + kc * 32 + lq * 8];
                const bool zed = (dx == 0 && (j & 1) == 0 && ll == 0) ||
                                 (dx == 2 && (j & 1) == 1 && ll == 15);
                if (zed) { bf16x8 z = {}; v = z; }
                bfv[j] = v;
            }
            const unsigned short* wb =
                wrep + ((size_t)tap * 144 + co0w) * CINP + kc * 32 + lq * 8;
#pragma unroll
            for (int i = 0; i < 3; ++i) {
                bf16x8 af = *(const bf16x8*)(wb + (size_t)(i * 16 + ll) * CINP);
#pragma unroll
                for (int j = 0; j < 4; ++j)
                    acc[i][j] = __builtin_amdgcn_mfma_f32_16x16x32_bf16(
                        af, bfv[j], acc[i][j], 0, 0, 0);
            }
        }
    }

#pragma unroll
    for (int i = 0; i < 3; ++i) {
        const int cob = co0w + i * 16 + lq * 4;
        float gv[4], bv[4];
#pragma unroll
        for (int r = 0; r < 4; ++r) { gv[r] = g[cob + r]; bv[r] = bb[cob + r]; }
#pragma unroll
        for (int j = 0; j < 4; ++j) {
            const int px = pbase + poff + j * 16 + ll;
            u16x4 tp;
#pragma unroll
            for (int r = 0; r < 4; ++r)
                tp[r] = f2bf(fmaxf(acc[i][j][r] * gv[r] + bv[r], 0.f));
            *(u16x4*)(outT + ((size_t)((b << 10) + px)) * 160 + cob) = tp;
        }
    }
}

// ------------------------- conv3x3 128-px blocks (512 thr) -----------------
// waves: h = wid>>2 (px half), co-band = (wid&3)*32.
template <int CINP>
__global__ __launch_bounds__(512) void conv3x3_lds_kernel(
    const unsigned short* __restrict__ xT,
    const unsigned short* __restrict__ wrep,
    const float* __restrict__ g, const float* __restrict__ bb,
    const unsigned short* __restrict__ resT,
    unsigned short* __restrict__ outT, int Cout)
{
    constexpr int PITCH = CINP + 8;
    constexpr int NCHK = CINP / 8;
    __shared__ unsigned short X[194 * PITCH];
    const int tid = threadIdx.x;
    const int b = blockIdx.x, gr = blockIdx.y;
    const int pbase = gr << 7;
    const int gbase = pbase - 33;
    const int wid = tid >> 6, lane = tid & 63;
    const int ll = lane & 15, lq = lane >> 4;
    const int poff = (wid >> 2) * 64;
    const int co0w = (wid & 3) << 5;
    const unsigned short* xb = xT + ((size_t)b << 10) * CINP;

#pragma unroll 1
    for (int idx = tid; idx < 194 * NCHK; idx += 512) {
        const int row = idx / NCHK;
        const int chunk = idx - row * NCHK;
        const int gp = gbase + row;
        u16x8 v = {};
        if (gp >= 0 && gp < 1024)
            v = *(const u16x8*)(xb + (size_t)gp * CINP + chunk * 8);
        *(u16x8*)&X[row * PITCH + chunk * 8] = v;
    }
    __syncthreads();

    f32x4 acc[2][4];
#pragma unroll
    for (int i = 0; i < 2; ++i)
#pragma unroll
        for (int j = 0; j < 4; ++j)
#pragma unroll
            for (int r = 0; r < 4; ++r) acc[i][j][r] = 0.f;

#pragma unroll
    for (int tap = 0; tap < 9; ++tap) {
        const int soff = (tap / 3) * 32 + (tap % 3);
        const int dx = tap % 3;
#pragma unroll
        for (int kc = 0; kc < CINP / 32; ++kc) {
            bf16x8 bfv[4];
#pragma unroll
            for (int j = 0; j < 4; ++j) {
                const int p = poff + j * 16 + ll;
                bf16x8 v = *(const bf16x8*)&X[(p + soff) * PITCH + kc * 32 + lq * 8];
                const bool zed = (dx == 0 && (j & 1) == 0 && ll == 0) ||
                                 (dx == 2 && (j & 1) == 1 && ll == 15);
                if (zed) { bf16x8 z = {}; v = z; }
                bfv[j] = v;
            }
            const unsigned short* wb =
                wrep + ((size_t)tap * Cout + co0w) * CINP + kc * 32 + lq * 8;
#pragma unroll
            for (int i = 0; i < 2; ++i) {
                bf16x8 af = *(const bf16x8*)(wb + (size_t)(i * 16 + ll) * CINP);
#pragma unroll
                for (int j = 0; j < 4; ++j)
                    acc[i][j] = __builtin_amdgcn_mfma_f32_16x16x32_bf16(
                        af, bfv[j], acc[i][j], 0, 0, 0);
            }
        }
    }

#pragma unroll
    for (int i = 0; i < 2; ++i) {
        const int cob = co0w + i * 16 + lq * 4;
        float gv[4], bv[4];
#pragma unroll
        for (int r = 0; r < 4; ++r) { gv[r] = g[cob + r]; bv[r] = bb[cob + r]; }
#pragma unroll
        for (int j = 0; j < 4; ++j) {
            const int px = pbase + poff + j * 16 + ll;
            const size_t rowT = ((size_t)((b << 10) + px)) << 7;
            u16x4 rv = {};
            if (resT) rv = *(const u16x4*)(resT + rowT + cob);
            u16x4 tp;
#pragma unroll
            for (int r = 0; r < 4; ++r) {
                float v = fmaxf(acc[i][j][r] * gv[r] + bv[r], 0.f);
                if (resT) v += bf2f(rv[r]);
                tp[r] = f2bf(v);
            }
            *(u16x4*)(outT + rowT + cob) = tp;
        }
    }
}

// ------------------------- conv3x3 + fused pi, 128-px blocks (512 thr) -----
// conv: waves (h = wid>>2, co = (wid&3)*32). Y[128][128] reuses X head.
// pi: waves (h = wid>>2, co0p = (wid&3)*(PI_COUT/4)).
template <int PI_COUT>
__global__ __launch_bounds__(512) void conv3x3_pi_kernel(
    const unsigned short* __restrict__ xT,
    const unsigned short* __restrict__ wrep,
    const float* __restrict__ g, const float* __restrict__ bb,
    const unsigned short* __restrict__ resT,
    unsigned short* __restrict__ outT,
    const unsigned short* __restrict__ wpi, const float* __restrict__ pi_b,
    const float* __restrict__ pig, const float* __restrict__ pibb,
    unsigned short* __restrict__ qTout, unsigned short* __restrict__ vout)
{
    constexpr int CINP = 128, PITCH = 136, NCHK = 16;
    __shared__ unsigned short X[194 * PITCH];   // head reused as Y[128][128]
    unsigned short* Y = X;
    const int tid = threadIdx.x;
    const int b = blockIdx.x, gr = blockIdx.y;
    const int pbase = gr << 7;
    const int gbase = pbase - 33;
    const int wid = tid >> 6, lane = tid & 63;
    const int ll = lane & 15, lq = lane >> 4;
    const int poff = (wid >> 2) * 64;
    const int co0w = (wid & 3) << 5;
    const unsigned short* xb = xT + ((size_t)b << 10) * CINP;

#pragma unroll 1
    for (int idx = tid; idx < 194 * NCHK; idx += 512) {
        const int row = idx / NCHK;
        const int chunk = idx - row * NCHK;
        const int gp = gbase + row;
        u16x8 v = {};
        if (gp >= 0 && gp < 1024)
            v = *(const u16x8*)(xb + (size_t)gp * CINP + chunk * 8);
        *(u16x8*)&X[row * PITCH + chunk * 8] = v;
    }
    __syncthreads();

    f32x4 acc[2][4];
#pragma unroll
    for (int i = 0; i < 2; ++i)
#pragma unroll
        for (int j = 0; j < 4; ++j)
#pragma unroll
            for (int r = 0; r < 4; ++r) acc[i][j][r] = 0.f;

#pragma unroll
    for (int tap = 0; tap < 9; ++tap) {
        const int soff = (tap / 3) * 32 + (tap % 3);
        const int dx = tap % 3;
#pragma unroll
        for (int kc = 0; kc < CINP / 32; ++kc) {
            bf16x8 bfv[4];
#pragma unroll
            for (int j = 0; j < 4; ++j) {
                const int p = poff + j * 16 + ll;
                bf16x8 v = *(const bf16x8*)&X[(p + soff) * PITCH + kc * 32 + lq * 8];
                const bool zed = (dx == 0 && (j & 1) == 0 && ll == 0) ||
                                 (dx == 2 && (j & 1) == 1 && ll == 15);
                if (zed) { bf16x8 z = {}; v = z; }
                bfv[j] = v;
            }
            const unsigned short* wb =
                wrep + ((size_t)tap * 128 + co0w) * CINP + kc * 32 + lq * 8;
#pragma unroll
            for (int i = 0; i < 2; ++i) {
                bf16x8 af = *(const bf16x8*)(wb + (size_t)(i * 16 + ll) * CINP);
#pragma unroll
                for (int j = 0; j < 4; ++j)
                    acc[i][j] = __builtin_amdgcn_mfma_f32_16x16x32_bf16(
                        af, bfv[j], acc[i][j], 0, 0, 0);
            }
        }
    }
    __syncthreads();   // all waves done reading X; safe to overwrite with Y

    // conv epilogue: write outT (global) and Y (LDS, swizzled)
#pragma unroll
    for (int i = 0; i < 2; ++i) {
        const int cob = co0w + i * 16 + lq * 4;
        float gv[4], bv[4];
#pragma unroll
        for (int r = 0; r < 4; ++r) { gv[r] = g[cob + r]; bv[r] = bb[cob + r]; }
#pragma unroll
        for (int j = 0; j < 4; ++j) {
            const int pxl = poff + j * 16 + ll;
            const int px = pbase + pxl;
            const size_t rowT = ((size_t)((b << 10) + px)) << 7;
            u16x4 rv = *(const u16x4*)(resT + rowT + cob);
            u16x4 tp;
#pragma unroll
            for (int r = 0; r < 4; ++r) {
                float v = fmaxf(acc[i][j][r] * gv[r] + bv[r], 0.f) + bf2f(rv[r]);
                tp[r] = f2bf(v);
            }
            *(u16x4*)(outT + rowT + cob) = tp;
            const int sw4 = ((pxl >> 2) & 3) << 4;
            *(u16x4*)&Y[pxl * 128 + (cob ^ sw4)] = tp;
        }
    }
    __syncthreads();

    // pi GEMM: out = wpi @ Y
    constexpr int NI = PI_COUT / 64;           // 4 (256-out) or 2 (128-out)
    const int co0p = (wid & 3) * (PI_COUT / 4);
    f32x4 acc2[NI][4];
#pragma unroll
    for (int i = 0; i < NI; ++i)
#pragma unroll
        for (int j = 0; j < 4; ++j)
#pragma unroll
            for (int r = 0; r < 4; ++r) acc2[i][j][r] = 0.f;

#pragma unroll
    for (int kk = 0; kk < 4; ++kk) {
        bf16x8 af[NI], bfv[4];
#pragma unroll
        for (int i = 0; i < NI; ++i)
            af[i] = *(const bf16x8*)(wpi + (size_t)(co0p + i * 16 + ll) * 128 + kk * 32 + lq * 8);
#pragma unroll
        for (int j = 0; j < 4; ++j) {
            const int pxl = poff + j * 16 + ll;
            const int sw4 = ((pxl >> 2) & 3) << 4;
            bfv[j] = *(const bf16x8*)&Y[pxl * 128 + ((kk * 32 + lq * 8) ^ sw4)];
        }
#pragma unroll
        for (int i = 0; i < NI; ++i)
#pragma unroll
            for (int j = 0; j < 4; ++j)
                acc2[i][j] = __builtin_amdgcn_mfma_f32_16x16x32_bf16(af[i], bfv[j], acc2[i][j], 0, 0, 0);
    }

#pragma unroll
    for (int i = 0; i < NI; ++i) {
        const int cob = co0p + i * 16 + lq * 4;
        float b0v[4], gv[4], bv[4];
#pragma unroll
        for (int r = 0; r < 4; ++r) {
            b0v[r] = pi_b[cob + r];
            gv[r] = pig[cob + r];
            bv[r] = pibb[cob + r];
        }
#pragma unroll
        for (int j = 0; j < 4; ++j) {
            const int px = pbase + poff + j * 16 + ll;
            float vv[4];
#pragma unroll
            for (int r = 0; r < 4; ++r)
                vv[r] = (acc2[i][j][r] + b0v[r]) * gv[r] + bv[r];
            if (PI_COUT == 256 && cob < 128) {
                u16x4 tp;
#pragma unroll
                for (int r = 0; r < 4; ++r) tp[r] = f2bf(vv[r]);
                *(u16x4*)(qTout + (((size_t)((b << 10) + px)) << 7) + cob) = tp;
            } else {
                const int cv = (PI_COUT == 256) ? cob - 128 : cob;
#pragma unroll
                for (int r = 0; r < 4; ++r)
                    vout[((size_t)(b * 128 + cv + r) << 10) + px] = f2bf(vv[r]);
            }
        }
    }
}

// ------------------------- cc 1x1 (160->128) + fused LayerNorm -------------
__global__ __launch_bounds__(256) void cc_ln_kernel(
    const unsigned short* __restrict__ xT, const unsigned short* __restrict__ wbf,
    const float* __restrict__ g, const float* __restrict__ bb,
    const float* __restrict__ ln_g, const float* __restrict__ ln_b,
    float* __restrict__ t, unsigned short* __restrict__ out_bf,
    unsigned short* __restrict__ outT)
{
    __shared__ float Ssum[4][64];
    __shared__ float Ssq[4][64];
    const int tid = threadIdx.x;
    const int b = blockIdx.x;
    const int n0 = blockIdx.y << 6;
    const int wid = tid >> 6, lane = tid & 63;
    const int ll = lane & 15, lq = lane >> 4;
    const unsigned short* xb = xT + (size_t)((b << 10) + n0) * 160;

    f32x4 acc[2][4];
#pragma unroll
    for (int i = 0; i < 2; ++i)
#pragma unroll
        for (int j = 0; j < 4; ++j)
#pragma unroll
            for (int r = 0; r < 4; ++r) acc[i][j][r] = 0.f;

#pragma unroll
    for (int kk = 0; kk < 5; ++kk) {
        bf16x8 af[2], bfv[4];
#pragma unroll
        for (int i = 0; i < 2; ++i)
            af[i] = *(const bf16x8*)(wbf + (size_t)(wid * 32 + i * 16 + ll) * 160 + kk * 32 + lq * 8);
#pragma unroll
        for (int j = 0; j < 4; ++j)
            bfv[j] = *(const bf16x8*)(xb + (size_t)(j * 16 + ll) * 160 + kk * 32 + lq * 8);
#pragma unroll
        for (int i = 0; i < 2; ++i)
#pragma unroll
            for (int j = 0; j < 4; ++j)
                acc[i][j] = __builtin_amdgcn_mfma_f32_16x16x32_bf16(af[i], bfv[j], acc[i][j], 0, 0, 0);
    }

    float vv[2][4][4];
    float sj[4] = {0.f, 0.f, 0.f, 0.f};
    float sqj[4] = {0.f, 0.f, 0.f, 0.f};
#pragma unroll
    for (int i = 0; i < 2; ++i) {
        const int cob = wid * 32 + i * 16 + lq * 4;
        float gv[4], bv[4];
#pragma unroll
        for (int r = 0; r < 4; ++r) { gv[r] = g[cob + r]; bv[r] = bb[cob + r]; }
#pragma unroll
        for (int j = 0; j < 4; ++j) {
            const int px = n0 + j * 16 + ll;
#pragma unroll
            for (int r = 0; r < 4; ++r) {
                const float val = fmaxf(acc[i][j][r] * gv[r] + bv[r], 0.f);
                vv[i][j][r] = val;
                t[((size_t)((b << 7) + cob + r) << 10) + px] = val;
                sj[j] += val;
                sqj[j] += val * val;
            }
        }
    }
#pragma unroll
    for (int j = 0; j < 4; ++j) {
        sj[j] += __shfl_xor(sj[j], 16);
        sj[j] += __shfl_xor(sj[j], 32);
        sqj[j] += __shfl_xor(sqj[j], 16);
        sqj[j] += __shfl_xor(sqj[j], 32);
    }
    if (lq == 0) {
#pragma unroll
        for (int j = 0; j < 4; ++j) {
            Ssum[wid][j * 16 + ll] = sj[j];
            Ssq[wid][j * 16 + ll] = sqj[j];
        }
    }
    __syncthreads();

    float mu[4], rst[4];
#pragma unroll
    for (int j = 0; j < 4; ++j) {
        const int p = j * 16 + ll;
        const float s = Ssum[0][p] + Ssum[1][p] + Ssum[2][p] + Ssum[3][p];
        const float sq = Ssq[0][p] + Ssq[1][p] + Ssq[2][p] + Ssq[3][p];
        mu[j] = s * 0.0078125f;
        rst[j] = rsqrtf(sq * 0.0078125f - mu[j] * mu[j] + 1e-5f);
    }

#pragma unroll
    for (int i = 0; i < 2; ++i) {
        const int cob = wid * 32 + i * 16 + lq * 4;
        float lg[4], lb[4];
#pragma unroll
        for (int r = 0; r < 4; ++r) { lg[r] = ln_g[cob + r]; lb[r] = ln_b[cob + r]; }
#pragma unroll
        for (int j = 0; j < 4; ++j) {
            const int px = n0 + j * 16 + ll;
            u16x4 tp;
#pragma unroll
            for (int r = 0; r < 4; ++r) {
                const float y = (vv[i][j][r] - mu[j]) * rst[j] * lg[r] + lb[r];
                const unsigned short h = f2bf(y);
                out_bf[((size_t)((b << 7) + cob + r) << 10) + px] = h;
                tp[r] = h;
            }
            *(u16x4*)(outT + (((size_t)((b << 10) + px)) << 7) + cob) = tp;
        }
    }
}

// ------------------------- Gram matrix + row sums (merged launch) ----------
__global__ __launch_bounds__(256) void gram_sums_kernel(
    const unsigned short* __restrict__ Xbf, float* __restrict__ G,
    float* __restrict__ S)
{
    __shared__ unsigned short Xs[128 * 128];
    const int tid = threadIdx.x;
    if (blockIdx.x >= 128) {
        const int b = blockIdx.x - 128;
        const int ch = tid >> 1, half = tid & 1;
        const unsigned short* p = Xbf + ((size_t)b << 17) + ((size_t)ch << 10) + half * 512;
        float s = 0.f;
#pragma unroll 4
        for (int i = 0; i < 64; ++i) {
            u16x8 v = *(const u16x8*)(p + i * 8);
#pragma unroll
            for (int e = 0; e < 8; ++e) s += bf2f(v[e]);
        }
        s += __shfl_xor(s, 1);
        if (half == 0) S[(b << 7) + ch] = s;
        return;
    }
    const int b = blockIdx.x >> 2;
    const int rg = blockIdx.x & 3;
    const int wid = tid >> 6, lane = tid & 63;
    const int lq = lane >> 4, ll = lane & 15;
    const unsigned short* Xb = Xbf + ((size_t)b << 17);

    f32x4 acc[2][2];
#pragma unroll
    for (int mi = 0; mi < 2; ++mi)
#pragma unroll
        for (int ci = 0; ci < 2; ++ci)
#pragma unroll
            for (int r = 0; r < 4; ++r) acc[mi][ci][r] = 0.f;

#pragma unroll 1
    for (int nt = 0; nt < 8; ++nt) {
        const int n0 = nt << 7;
#pragma unroll
        for (int p = 0; p < 8; ++p) {
            const int ch = (p << 4) + (tid >> 4);
            const int seg = (tid & 15) << 3;
            *(u16x8*)&Xs[ch * 128 + (seg ^ ((ch & 7) << 3))] =
                *(const u16x8*)(Xb + ((size_t)ch << 10) + n0 + seg);
        }
        __syncthreads();
#pragma unroll
        for (int ks = 0; ks < 4; ++ks) {
            bf16x8 af[2], bf_[2];
#pragma unroll
            for (int mi = 0; mi < 2; ++mi) {
                const int ar = (rg << 5) + mi * 16 + ll;
                af[mi] = *(const bf16x8*)&Xs[ar * 128 + ((ks * 32 + lq * 8) ^ ((ar & 7) << 3))];
            }
#pragma unroll
            for (int ci = 0; ci < 2; ++ci) {
                const int br = (wid << 5) + ci * 16 + ll;
                bf_[ci] = *(const bf16x8*)&Xs[br * 128 + ((ks * 32 + lq * 8) ^ ((br & 7) << 3))];
            }
#pragma unroll
            for (int mi = 0; mi < 2; ++mi)
#pragma unroll
                for (int ci = 0; ci < 2; ++ci)
                    acc[mi][ci] = __builtin_amdgcn_mfma_f32_16x16x32_bf16(
                        af[mi], bf_[ci], acc[mi][ci], 0, 0, 0);
        }
        __syncthreads();
    }
    float* Gb = G + ((size_t)b << 14);
#pragma unroll
    for (int mi = 0; mi < 2; ++mi)
#pragma unroll
        for (int ci = 0; ci < 2; ++ci)
#pragma unroll
            for (int r = 0; r < 4; ++r) {
                const int row = (rg << 5) + mi * 16 + lq * 4 + r;
                const int col = (wid << 5) + ci * 16 + ll;
                Gb[row * 128 + col] = acc[mi][ci][r];
            }
}

// ------------------------- GISSA stage-1 matrices (bf16 M1) ----------------
__global__ __launch_bounds__(64) void mats1_kernel(
    const float* __restrict__ G, const float* __restrict__ S,
    const float* __restrict__ qkv_w, const float* __restrict__ qkv_b,
    const float* __restrict__ g, const float* __restrict__ bb,
    unsigned short* __restrict__ M1, float* __restrict__ c1)
{
    const int lane = threadIdx.x;
    const int b = blockIdx.x >> 4, h = blockIdx.x & 15;
    const float* Gb = G + ((size_t)b << 14);
    const float* Sb = S + (b << 7);
    const int d = lane >> 3, e = lane & 7;
    const int qch = h * 8 + d, kch = 128 + h * 8 + e;
    const int qoff = (qch / 24) * 8, koff = (kch / 24) * 8;
    float wq[8], wk[8];
#pragma unroll
    for (int i = 0; i < 8; ++i) {
        wq[i] = qkv_w[qch * 8 + i];
        wk[i] = qkv_w[kch * 8 + i];
    }
    float s = 0.f;
#pragma unroll
    for (int i = 0; i < 8; ++i) {
        float gu = 0.f;
#pragma unroll
        for (int j = 0; j < 8; ++j) gu += Gb[(qoff + i) * 128 + koff + j] * wk[j];
        s += wq[i] * gu;
    }
    const float bq = qkv_b[qch], bk = qkv_b[kch];
    float swk = 0.f, swq = 0.f;
#pragma unroll
    for (int j = 0; j < 8; ++j) { swk += wk[j] * Sb[koff + j]; swq += wq[j] * Sb[qoff + j]; }
    s += bq * swk + bk * swq + 1024.f * bq * bk;
    s *= 0.35355339059327373f;
    float a = (s > 0.f) ? sqrtf(s + 1e-5f) : ((s < 0.f) ? -sqrtf(1e-5f - s) : 0.f);
    float mx = a;
    mx = fmaxf(mx, __shfl_xor(mx, 1));
    mx = fmaxf(mx, __shfl_xor(mx, 2));
    mx = fmaxf(mx, __shfl_xor(mx, 4));
    float p = __expf(a - mx);
    float den = p;
    den += __shfl_xor(den, 1);
    den += __shfl_xor(den, 2);
    den += __shfl_xor(den, 4);
    const float A = p / den;

    const int l = e;
    const int cp = d * 16 + h;
    float row[16];
#pragma unroll
    for (int j = 0; j < 16; ++j) row[j] = 0.f;
    float cacc = 0.f;
#pragma unroll
    for (int e2 = 0; e2 < 8; ++e2) {
        const float Ae = __shfl(A, d * 8 + e2);
        const int vch = 256 + h * 8 + e2;
        const int voff = (vch / 24) * 8;
        cacc += Ae * qkv_b[vch];
        if ((voff >> 4) == l) {
            const int base = voff & 15;
#pragma unroll
            for (int j = 0; j < 8; ++j) row[base + j] += Ae * qkv_w[vch * 8 + j];
        }
    }
    const int idc = h * 8 + d;
    if ((idc >> 4) == l) row[idc & 15] += 1.f;
    const float gg = g[cp];
    unsigned short* mrow = M1 + ((size_t)b << 14) + cp * 128 + l * 16;
#pragma unroll
    for (int j = 0; j < 16; ++j) mrow[j] = f2bf(gg * row[j]);
    if (l == 0) c1[(b << 7) + cp] = gg * cacc + bb[cp];
}

// ------------------------- GISSA stage-2 matrices (bf16 M2) ----------------
__global__ __launch_bounds__(256) void mats2_kernel(
    const float* __restrict__ G, const float* __restrict__ S,
    const float* __restrict__ qkv2_w, const float* __restrict__ qkv2_b,
    unsigned short* __restrict__ M2, float* __restrict__ c2)
{
    const int tid = threadIdx.x;
    const int b = blockIdx.x >> 3, d = blockIdx.x & 7;
    const float* Gb = G + ((size_t)b << 14);
    const float* Sb = S + (b << 7);
    const int h = tid >> 4, gq = tid & 15;
    const int q2ch = d * 16 + h, k2ch = 128 + d * 16 + gq;
    const int qoff = (q2ch / 48) * 16, koff = (k2ch / 48) * 16;
    float wq[16], wk[16];
#pragma unroll
    for (int i = 0; i < 16; ++i) {
        wq[i] = qkv2_w[q2ch * 16 + i];
        wk[i] = qkv2_w[k2ch * 16 + i];
    }
    float s = 0.f;
#pragma unroll
    for (int i = 0; i < 16; ++i) {
        float gu = 0.f;
#pragma unroll
        for (int j = 0; j < 16; ++j) gu += Gb[(qoff + i) * 128 + koff + j] * wk[j];
        s += wq[i] * gu;
    }
    const float bq = qkv2_b[q2ch], bk = qkv2_b[k2ch];
    float swk = 0.f, swq = 0.f;
#pragma unroll
    for (int j = 0; j < 16; ++j) { swk += wk[j] * Sb[koff + j]; swq += wq[j] * Sb[qoff + j]; }
    s += bq * swk + bk * swq + 1024.f * bq * bk;
    s *= 0.25f;
    float a = (s > 0.f) ? sqrtf(s + 1e-5f) : ((s < 0.f) ? -sqrtf(1e-5f - s) : 0.f);
    float mx = a;
    mx = fmaxf(mx, __shfl_xor(mx, 1));
    mx = fmaxf(mx, __shfl_xor(mx, 2));
    mx = fmaxf(mx, __shfl_xor(mx, 4));
    mx = fmaxf(mx, __shfl_xor(mx, 8));
    float p = __expf(a - mx);
    float den = p;
    den += __shfl_xor(den, 1);
    den += __shfl_xor(den, 2);
    den += __shfl_xor(den, 4);
    den += __shfl_xor(den, 8);
    const float A2 = p / den;

    const int l = gq;
    float row[8];
#pragma unroll
    for (int j = 0; j < 8; ++j) row[j] = 0.f;
    float cacc = 0.f;
#pragma unroll
    for (int g2 = 0; g2 < 16; ++g2) {
        const float Ag = __shfl(A2, (tid & 48) + g2);
        const int v2ch = 256 + d * 16 + g2;
        const int voff = (v2ch / 48) * 16;
        cacc += Ag * qkv2_b[v2ch];
        if ((l >> 1) == (voff >> 4)) {
            const int base = (l & 1) * 8;
#pragma unroll
            for (int j = 0; j < 8; ++j) row[j] += Ag * qkv2_w[v2ch * 16 + base + j];
        }
    }
    const int c = h * 8 + d;
    unsigned short* mrow = M2 + ((size_t)b << 14) + c * 128 + l * 8;
#pragma unroll
    for (int j = 0; j < 8; ++j) mrow[j] = f2bf(row[j]);
    if (l == 0) c2[(b << 7) + c] = cacc;
}

// ------------------------- apply1: y = M1 x + c1 (MFMA) --------------------
__global__ __launch_bounds__(256) void apply1_mfma_kernel(
    const unsigned short* __restrict__ curT, const unsigned short* __restrict__ M1bf,
    const float* __restrict__ c1, unsigned short* __restrict__ ybufb,
    unsigned short* __restrict__ yrbf, unsigned short* __restrict__ yrT)
{
    const int tid = threadIdx.x;
    const int b = blockIdx.x >> 3;
    const int n0 = (blockIdx.x & 7) << 7;
    const int wid = tid >> 6, lane = tid & 63;
    const int wr = wid >> 1, wc = wid & 1;
    const int ll = lane & 15, lq = lane >> 4;
    const unsigned short* Mb = M1bf + ((size_t)b << 14);
    const unsigned short* xb = curT + (((size_t)b << 10) + n0 + wc * 64) * 128;

    f32x4 acc[4][4];
#pragma unroll
    for (int i = 0; i < 4; ++i)
#pragma unroll
        for (int j = 0; j < 4; ++j)
#pragma unroll
            for (int r = 0; r < 4; ++r) acc[i][j][r] = 0.f;

#pragma unroll
    for (int kk = 0; kk < 4; ++kk) {
        bf16x8 af[4], bfv[4];
#pragma unroll
        for (int i = 0; i < 4; ++i)
            af[i] = *(const bf16x8*)(Mb + (size_t)(wr * 64 + i * 16 + ll) * 128 + kk * 32 + lq * 8);
#pragma unroll
        for (int j = 0; j < 4; ++j)
            bfv[j] = *(const bf16x8*)(xb + (size_t)(j * 16 + ll) * 128 + kk * 32 + lq * 8);
#pragma unroll
        for (int i = 0; i < 4; ++i)
#pragma unroll
            for (int j = 0; j < 4; ++j)
                acc[i][j] = __builtin_amdgcn_mfma_f32_16x16x32_bf16(af[i], bfv[j], acc[i][j], 0, 0, 0);
    }

#pragma unroll
    for (int i = 0; i < 4; ++i) {
        const int cob = wr * 64 + i * 16 + lq * 4;
        float c1v[4];
#pragma unroll
        for (int r = 0; r < 4; ++r) c1v[r] = c1[(b << 7) + cob + r];
#pragma unroll
        for (int j = 0; j < 4; ++j) {
            const int px = n0 + wc * 64 + j * 16 + ll;
            u16x4 tp;
#pragma unroll
            for (int r = 0; r < 4; ++r) {
                const int co = cob + r;
                const float v = acc[i][j][r] + c1v[r];
                const size_t oi = ((size_t)(b * 128 + co) << 10) + px;
                ybufb[oi] = f2bf(v);
                const unsigned short h = f2bf(fmaxf(v, 0.f));
                yrbf[oi] = h;
                tp[r] = h;
            }
            *(u16x4*)(yrT + (((size_t)b << 10) + px) * 128 + cob) = tp;
        }
    }
}

// ------------------------- apply2: t += M2 relu(y) + c2 + y (MFMA) ---------
__global__ __launch_bounds__(256) void apply2_mfma_kernel(
    const unsigned short* __restrict__ yrT, const unsigned short* __restrict__ M2bf,
    const float* __restrict__ c2, const unsigned short* __restrict__ ybufb,
    float* __restrict__ t)
{
    const int tid = threadIdx.x;
    const int b = blockIdx.x >> 3;
    const int n0 = (blockIdx.x & 7) << 7;
    const int wid = tid >> 6, lane = tid & 63;
    const int wr = wid >> 1, wc = wid & 1;
    const int ll = lane & 15, lq = lane >> 4;
    const unsigned short* Mb = M2bf + ((size_t)b << 14);
    const unsigned short* xb = yrT + (((size_t)b << 10) + n0 + wc * 64) * 128;

    f32x4 acc[4][4];
#pragma unroll
    for (int i = 0; i < 4; ++i)
#pragma unroll
        for (int j = 0; j < 4; ++j)
#pragma unroll
            for (int r = 0; r < 4; ++r) acc[i][j][r] = 0.f;

#pragma unroll
    for (int kk = 0; kk < 4; ++kk) {
        bf16x8 af[4], bfv[4];
#pragma unroll
        for (int i = 0; i < 4; ++i)
            af[i] = *(const bf16x8*)(Mb + (size_t)(wr * 64 + i * 16 + ll) * 128 + kk * 32 + lq * 8);
#pragma unroll
        for (int j = 0; j < 4; ++j)
            bfv[j] = *(const bf16x8*)(xb + (size_t)(j * 16 + ll) * 128 + kk * 32 + lq * 8);
#pragma unroll
        for (int i = 0; i < 4; ++i)
#pragma unroll
            for (int j = 0; j < 4; ++j)
                acc[i][j] = __builtin_amdgcn_mfma_f32_16x16x32_bf16(af[i], bfv[j], acc[i][j], 0, 0, 0);
    }

#pragma unroll
    for (int i = 0; i < 4; ++i) {
        const int cob = wr * 64 + i * 16 + lq * 4;
        float c2v[4];
#pragma unroll
        for (int r = 0; r < 4; ++r) c2v[r] = c2[(b << 7) + cob + r];
#pragma unroll
        for (int j = 0; j < 4; ++j) {
            const int px = n0 + wc * 64 + j * 16 + ll;
#pragma unroll
            for (int r = 0; r < 4; ++r) {
                const size_t oi = ((size_t)(b * 128 + cob + r) << 10) + px;
                t[oi] += acc[i][j][r] + c2v[r] + bf2f(ybufb[oi]);
            }
        }
    }
}

// ------------------------- fused LN2 + MLP via bf16 MFMA -------------------
__global__ __launch_bounds__(256) void mlp_mfma_kernel(
    float* __restrict__ t, const float* __restrict__ ln_g,
    const float* __restrict__ ln_b, const unsigned short* __restrict__ w1bf,
    const float* __restrict__ b1, const unsigned short* __restrict__ w2bf,
    const float* __restrict__ b2)
{
    __shared__ unsigned char lds[16384 + 65536];
    unsigned char* xnb = lds;
    unsigned char* hb = lds + 16384;

    const int tid = threadIdx.x;
    const int b = blockIdx.x >> 4;
    const int n0 = (blockIdx.x & 15) << 6;
    float* tb = t + ((size_t)b << 17) + n0;

    {
        const int px = tid >> 2, q = tid & 3;
        float v[32];
        float s = 0.f, sq = 0.f;
#pragma unroll
        for (int k = 0; k < 32; ++k) {
            float x = tb[((size_t)(q * 32 + k) << 10) + px];
            v[k] = x;
            s += x;
            sq += x * x;
        }
        s += __shfl_xor(s, 1); s += __shfl_xor(s, 2);
        sq += __shfl_xor(sq, 1); sq += __shfl_xor(sq, 2);
        const float mu = s * 0.0078125f;
        const float rstd = rsqrtf(sq * 0.0078125f - mu * mu + 1e-5f);
        const int sw = (px & 7) << 4;
#pragma unroll
        for (int cc = 0; cc < 4; ++cc) {
            u16x8 pk;
#pragma unroll
            for (int e = 0; e < 8; ++e) {
                int c = q * 32 + cc * 8 + e;
                float xv = (v[cc * 8 + e] - mu) * rstd * ln_g[c] + ln_b[c];
                pk[e] = f2bf(xv);
            }
            *(u16x8*)(xnb + px * 256 + ((q * 64 + cc * 16) ^ sw)) = pk;
        }
    }
    __syncthreads();

    const int wid = tid >> 6, lane = tid & 63;
    const int lr = lane & 15, lk = lane >> 4;

#pragma unroll 1
    for (int pass = 0; pass < 2; ++pass) {
        const int hidbase = (wid << 7) + (pass << 6);
        f32x4 acc[4][4];
#pragma unroll
        for (int i = 0; i < 4; ++i)
#pragma unroll
            for (int j = 0; j < 4; ++j)
#pragma unroll
                for (int r = 0; r < 4; ++r) acc[i][j][r] = 0.f;
#pragma unroll
        for (int kk = 0; kk < 4; ++kk) {
            bf16x8 af[4], bfr[4];
#pragma unroll
            for (int i = 0; i < 4; ++i)
                af[i] = *(const bf16x8*)(w1bf + (size_t)(hidbase + i * 16 + lr) * 128 + kk * 32 + lk * 8);
#pragma unroll
            for (int j = 0; j < 4; ++j) {
                const int px = j * 16 + lr;
                bfr[j] = *(const bf16x8*)(xnb + px * 256 + ((kk * 64 + lk * 16) ^ ((px & 7) << 4)));
            }
#pragma unroll
            for (int i = 0; i < 4; ++i)
#pragma unroll
                for (int j = 0; j < 4; ++j)
                    acc[i][j] = __builtin_amdgcn_mfma_f32_16x16x32_bf16(af[i], bfr[j], acc[i][j], 0, 0, 0);
        }
#pragma unroll
        for (int i = 0; i < 4; ++i) {
            const int hid0 = hidbase + i * 16 + lk * 4;
            float bi[4];
#pragma unroll
            for (int r = 0; r < 4; ++r) bi[r] = b1[hid0 + r];
#pragma unroll
            for (int j = 0; j < 4; ++j) {
                const int px = j * 16 + lr;
                u16x4 pk;
#pragma unroll
                for (int r = 0; r < 4; ++r) {
                    float x = acc[i][j][r] + bi[r];
                    float u = 1.5957691f * x * (1.f + 0.044715f * x * x);
                    float gv = x / (1.f + __expf(-u));
                    pk[r] = f2bf(gv);
                }
                *(u16x4*)(hb + px * 1024 + ((hid0 * 2) ^ ((px & 7) << 4))) = pk;
            }
        }
    }
    __syncthreads();

    f32x4 acc2[2][4];
#pragma unroll
    for (int i = 0; i < 2; ++i)
#pragma unroll
        for (int j = 0; j < 4; ++j)
#pragma unroll
            for (int r = 0; r < 4; ++r) acc2[i][j][r] = 0.f;
#pragma unroll 2
    for (int ks = 0; ks < 16; ++ks) {
        bf16x8 af[2], bfr[4];
#pragma unroll
        for (int i = 0; i < 2; ++i)
            af[i] = *(const bf16x8*)(w2bf + (size_t)((wid << 5) + i * 16 + lr) * 512 + ks * 32 + lk * 8);
#pragma unroll
        for (int j = 0; j < 4; ++j) {
            const int px = j * 16 + lr;
            bfr[j] = *(const bf16x8*)(hb + px * 1024 + ((ks * 64 + lk * 16) ^ ((px & 7) << 4)));
        }
#pragma unroll
        for (int i = 0; i < 2; ++i)
#pragma unroll
            for (int j = 0; j < 4; ++j)
                acc2[i][j] = __builtin_amdgcn_mfma_f32_16x16x32_bf16(af[i], bfr[j], acc2[i][j], 0, 0, 0);
    }
#pragma unroll
    for (int i = 0; i < 2; ++i) {
        const int cb = (wid << 5) + i * 16 + lk * 4;
        float b2v[4];
#pragma unroll
        for (int r = 0; r < 4; ++r) b2v[r] = b2[cb + r];
#pragma unroll
        for (int j = 0; j < 4; ++j) {
            const int px = j * 16 + lr;
#pragma unroll
            for (int r = 0; r < 4; ++r) {
                const size_t off = ((size_t)(cb + r) << 10) + px;
                tb[off] += acc2[i][j][r] + b2v[r];
            }
        }
    }
}

// ------------------------- flash SWSA + fused po GEMM (512 thr, dbuf) ------
template <int REUSE>
__global__ __launch_bounds__(512) void swsa_po_kernel(
    const unsigned short* __restrict__ qT, const unsigned short* __restrict__ vbf,
    const unsigned short* __restrict__ wpo, const float* __restrict__ po_b,
    const unsigned short* __restrict__ resT,
    unsigned short* __restrict__ outT, unsigned short* __restrict__ outB,
    float fscale, float* __restrict__ statsM, float* __restrict__ statsL)
{
    __shared__ unsigned short K_lds[2][128 * 128];
    __shared__ unsigned short V_lds[2][128 * 128];
    const int tid = threadIdx.x;
    const int b = blockIdx.x & 31;
    const int n0 = (blockIdx.x >> 5) << 7;
    const int wid = tid >> 6, lane = tid & 63;     // wid 0..7
    const int lq = lane >> 4, ll = lane & 15;
    const unsigned short* qTb = qT + ((size_t)b << 17);
    const unsigned short* vb = vbf + ((size_t)b << 17);
    const int rowbase = n0 + wid * 16 + lq * 4;    // this lane's 4 q-rows

#define SWSA_STAGE(BUF, M0V)                                                  \
    for (int ch = tid; ch < 2048; ch += 512) {                                \
        const int rr = ch >> 4, e0 = (ch & 15) << 3;                          \
        const int sw = (rr & 7) << 3;                                         \
        *(u16x8*)&K_lds[BUF][rr * 128 + (e0 ^ sw)] =                          \
            *(const u16x8*)(qTb + ((size_t)((M0V) + rr) << 7) + e0);          \
        *(u16x8*)&V_lds[BUF][rr * 128 + (e0 ^ sw)] =                          \
            *(const u16x8*)(vb + ((size_t)rr << 10) + (M0V) + e0);            \
    }

    bf16x8 aq[4];
    {
        const int row = n0 + wid * 16 + ll;
#pragma unroll
        for (int kk = 0; kk < 4; ++kk)
            aq[kk] = *(const bf16x8*)(qTb + ((size_t)row << 7) + kk * 32 + lq * 8);
    }

    float mrun[4], lrun[4];
    if (REUSE) {
#pragma unroll
        for (int r = 0; r < 4; ++r) {
            mrun[r] = statsM[(b << 10) + rowbase + r];
            lrun[r] = statsL[(b << 10) + rowbase + r];
        }
    } else {
#pragma unroll
        for (int i = 0; i < 4; ++i) { mrun[i] = -INFINITY; lrun[i] = 0.f; }
    }
    f32x4 yacc[8];
#pragma unroll
    for (int cj = 0; cj < 8; ++cj)
#pragma unroll
        for (int r = 0; r < 4; ++r) yacc[cj][r] = 0.f;

    // prologue: stage tile 0 into buffer 0
    SWSA_STAGE(0, 0)

#pragma unroll 1
    for (int mt = 0; mt < 8; ++mt) {
        const int cur = mt & 1;
        __syncthreads();   // stage(mt) complete; PV(mt-1) reads complete

        // prefetch tile mt+1 into the other buffer (overlaps compute below)
        if (mt < 7) { SWSA_STAGE(1 - cur, (mt + 1) << 7) }

        // QK^T from K_lds[cur]
        f32x4 sacc[8];
#pragma unroll
        for (int j = 0; j < 8; ++j)
#pragma unroll
            for (int r = 0; r < 4; ++r) sacc[j][r] = 0.f;
#pragma unroll
        for (int j = 0; j < 8; ++j) {
            const int ml = j * 16 + ll;
            const int swk = (ml & 7) << 3;
#pragma unroll
            for (int kk = 0; kk < 4; ++kk) {
                bf16x8 bk = *(const bf16x8*)&K_lds[cur][ml * 128 + ((kk * 32 + lq * 8) ^ swk)];
                sacc[j] = __builtin_amdgcn_mfma_f32_16x16x32_bf16(aq[kk], bk, sacc[j], 0, 0, 0);
            }
        }
        __syncthreads();   // K reads done; K region of buf[cur] becomes P

        if (REUSE) {
#pragma unroll
            for (int r = 0; r < 4; ++r) {
                const int nbw = wid * 16 + lq * 4 + r;
                const int sw4 = ((nbw >> 2) & 3) << 4;
                const float mn = mrun[r];
#pragma unroll
                for (int j = 0; j < 8; ++j) {
                    float p = __expf(sacc[j][r] * 0.08838834764831845f - mn);
                    K_lds[cur][nbw * 128 + ((j * 16 + ll) ^ sw4)] = f2bf(p);
                }
            }
        } else {
            float pmax[4];
#pragma unroll
            for (int i = 0; i < 4; ++i) pmax[i] = -INFINITY;
#pragma unroll
            for (int j = 0; j < 8; ++j)
#pragma unroll
                for (int r = 0; r < 4; ++r) {
                    float s = sacc[j][r] * 0.08838834764831845f;
                    sacc[j][r] = s;
                    pmax[r] = fmaxf(pmax[r], s);
                }
            float alpha[4];
#pragma unroll
            for (int i = 0; i < 4; ++i) {
                float m = pmax[i];
                m = fmaxf(m, __shfl_xor(m, 1));
                m = fmaxf(m, __shfl_xor(m, 2));
                m = fmaxf(m, __shfl_xor(m, 4));
                m = fmaxf(m, __shfl_xor(m, 8));
                const float mn = fmaxf(mrun[i], m);
                alpha[i] = __expf(mrun[i] - mn);
                mrun[i] = mn;
            }
            float psum[4];
#pragma unroll
            for (int r = 0; r < 4; ++r) {
                const int nbw = wid * 16 + lq * 4 + r;
                const int sw4 = ((nbw >> 2) & 3) << 4;
                const float mn = mrun[r];
                float ps = 0.f;
#pragma unroll
                for (int j = 0; j < 8; ++j) {
                    float p = __expf(sacc[j][r] - mn);
                    ps += p;
                    K_lds[cur][nbw * 128 + ((j * 16 + ll) ^ sw4)] = f2bf(p);
                }
                psum[r] = ps;
            }
#pragma unroll
            for (int i = 0; i < 4; ++i) {
                float s = psum[i];
                s += __shfl_xor(s, 1);
                s += __shfl_xor(s, 2);
                s += __shfl_xor(s, 4);
                s += __shfl_xor(s, 8);
                lrun[i] = lrun[i] * alpha[i] + s;
            }
#pragma unroll
            for (int cj = 0; cj < 8; ++cj)
#pragma unroll
                for (int r = 0; r < 4; ++r) yacc[cj][r] *= alpha[r];
        }

        // PV: A = P (own rows, intra-wave dependency), B = V from LDS
        bf16x8 ap[4];
        {
            const int nb = wid * 16 + ll;
            const int sw4 = ((nb >> 2) & 3) << 4;
#pragma unroll
            for (int mk = 0; mk < 4; ++mk)
                ap[mk] = *(const bf16x8*)&K_lds[cur][nb * 128 + ((mk * 32 + lq * 8) ^ sw4)];
        }
#pragma unroll
        for (int cj = 0; cj < 8; ++cj) {
            const int cl = cj * 16 + ll;
            const int sw = (cl & 7) << 3;
#pragma unroll
            for (int mk = 0; mk < 4; ++mk) {
                bf16x8 bv = *(const bf16x8*)&V_lds[cur][cl * 128 + ((mk * 32 + lq * 8) ^ sw)];
                yacc[cj] = __builtin_amdgcn_mfma_f32_16x16x32_bf16(ap[mk], bv, yacc[cj], 0, 0, 0);
            }
        }
    }
    __syncthreads();   // last PV reads done

    if (!REUSE) {
        if (ll == 0) {
#pragma unroll
            for (int r = 0; r < 4; ++r) {
                statsM[(b << 10) + rowbase + r] = mrun[r];
                statsL[(b << 10) + rowbase + r] = lrun[r];
            }
        }
    }

    // ---- fused po: yv (normalized) -> K_lds[0] [128px][128c], then GEMM ---
    {
        float inv[4];
#pragma unroll
        for (int r = 0; r < 4; ++r) inv[r] = fscale / lrun[r];
        const int rw0 = wid * 16 + lq * 4;
#pragma unroll
        for (int cj = 0; cj < 8; ++cj) {
            const int c = cj * 16 + ll;
#pragma unroll
            for (int r = 0; r < 4; ++r) {
                const int row = rw0 + r;
                const int sw4 = ((row >> 2) & 3) << 4;
                K_lds[0][row * 128 + (c ^ sw4)] = f2bf(yacc[cj][r] * inv[r]);
            }
        }
    }
    __syncthreads();

    // po GEMM: each wave computes 16 co x 128 px.
    f32x4 acc2[8];
#pragma unroll
    for (int j = 0; j < 8; ++j)
#pragma unroll
        for (int r = 0; r < 4; ++r) acc2[j][r] = 0.f;
#pragma unroll
    for (int kk = 0; kk < 4; ++kk) {
        bf16x8 af = *(const bf16x8*)(wpo + (size_t)(wid * 16 + ll) * 128 + kk * 32 + lq * 8);
#pragma unroll
        for (int j = 0; j < 8; ++j) {
            const int row = j * 16 + ll;
            const int sw4 = ((row >> 2) & 3) << 4;
            bf16x8 bfv = *(const bf16x8*)&K_lds[0][row * 128 + ((kk * 32 + lq * 8) ^ sw4)];
            acc2[j] = __builtin_amdgcn_mfma_f32_16x16x32_bf16(af, bfv, acc2[j], 0, 0, 0);
        }
    }

    {
        const int cob = wid * 16 + lq * 4;
        float pob[4];
#pragma unroll
        for (int r = 0; r < 4; ++r) pob[r] = po_b[cob + r];
#pragma unroll
        for (int j = 0; j < 8; ++j) {
            const int px = n0 + j * 16 + ll;
            const size_t rowT = ((size_t)((b << 10) + px)) << 7;
            u16x4 rv = *(const u16x4*)(resT + rowT + cob);
            float vv[4];
#pragma unroll
            for (int r = 0; r < 4; ++r)
                vv[r] = acc2[j][r] + pob[r] + bf2f(rv[r]);
            if (outT) {
                u16x4 tp;
#pragma unroll
                for (int r = 0; r < 4; ++r) tp[r] = f2bf(vv[r]);
                *(u16x4*)(outT + rowT + cob) = tp;
            }
            if (outB) {
#pragma unroll
                for (int r = 0; r < 4; ++r)
                    outB[((size_t)(b * 128 + cob + r) << 10) + px] = f2bf(vv[r]);
            }
        }
    }
#undef SWSA_STAGE
}

// ------------------------- final: mean (stage 1) ---------------------------
__global__ __launch_bounds__(256) void mean_kernel(
    const float* __restrict__ xc, const unsigned short* __restrict__ xp,
    const float* __restrict__ lamuda, float* __restrict__ meanb)
{
    const int wid = threadIdx.x >> 6, lane = threadIdx.x & 63;
    const int row = (blockIdx.x << 2) + wid;
    const float lmd = 1.f / (1.f + __expf(-lamuda[0]));
    const float* a = xc + ((size_t)row << 10) + (lane << 2);
    const unsigned short* d = xp + ((size_t)row << 10) + (lane << 4);
    float s = 0.f;
#pragma unroll
    for (int i = 0; i < 4; ++i) {
        float4 va = *(const float4*)(a + (i << 8));
        s += lmd * (va.x + va.y + va.z + va.w);
    }
    float sp = 0.f;
#pragma unroll
    for (int i = 0; i < 2; ++i) {
        u16x8 v = *(const u16x8*)(d + i * 8);
#pragma unroll
        for (int e = 0; e < 8; ++e) sp += bf2f(v[e]);
    }
    s += (1.f - lmd) * sp;
#pragma unroll
    for (int o = 1; o < 64; o <<= 1) s += __shfl_xor(s, o);
    if (lane == 0) meanb[row] = s * (1.f / 1024.f);
}

// ------------------------- final: fc (stage 2) -----------------------------
__global__ __launch_bounds__(256) void fc_kernel(
    const float* __restrict__ meanb, const float* __restrict__ fc_w,
    float* __restrict__ outp)
{
    const int idx = blockIdx.x * 256 + threadIdx.x;
    if (idx >= 512) return;
    const int b = idx >> 4, o = idx & 15;
    float s = 0.f;
#pragma unroll 4
    for (int c = 0; c < 128; ++c) s += fc_w[o * 128 + c] * meanb[b * 128 + c];
    outp[b * 16 + o] = s;
}

// ---------------------------------------------------------------------------
extern "C" void kernel_launch(void* const* d_in, const int* in_sizes, int n_in,
                              void* d_out, int out_size, void* d_ws, size_t ws_size,
                              hipStream_t stream)
{
    (void)in_sizes; (void)n_in; (void)out_size; (void)ws_size;

    const float* x       = (const float*)d_in[0];
    const float* ssfe_w  = (const float*)d_in[1];
    const float* ssfe_g  = (const float*)d_in[2];
    const float* ssfe_b  = (const float*)d_in[3];
    const float* cc_w    = (const float*)d_in[4];
    const float* cc_g    = (const float*)d_in[5];
    const float* cc_b    = (const float*)d_in[6];
    const float* ln1_g   = (const float*)d_in[7];
    const float* ln1_b   = (const float*)d_in[8];
    const float* qkv_w   = (const float*)d_in[9];
    const float* qkv_b   = (const float*)d_in[10];
    const float* gbn_g   = (const float*)d_in[11];
    const float* gbn_b   = (const float*)d_in[12];
    const float* qkv2_w  = (const float*)d_in[13];
    const float* qkv2_b  = (const float*)d_in[14];
    const float* ln2_g   = (const float*)d_in[15];
    const float* ln2_b   = (const float*)d_in[16];
    const float* mlp_w1  = (const float*)d_in[17];
    const float* mlp_b1  = (const float*)d_in[18];
    const float* mlp_w2  = (const float*)d_in[19];
    const float* mlp_b2  = (const float*)d_in[20];
    const float* cs_w    = (const float*)d_in[21];
    const float* cs_g    = (const float*)d_in[22];
    const float* cs_b    = (const float*)d_in[23];
    const float* lfe0_w  = (const float*)d_in[24];
    const float* lfe0_g  = (const float*)d_in[25];
    const float* lfe0_b  = (const float*)d_in[26];
    const float* s0_pi_w = (const float*)d_in[27];
    const float* s0_pi_b = (const float*)d_in[28];
    const float* s0_bn_g = (const float*)d_in[29];
    const float* s0_bn_b = (const float*)d_in[30];
    const float* s0_po_w = (const float*)d_in[31];
    const float* s0_po_b = (const float*)d_in[32];
    const float* lfe1_w  = (const float*)d_in[33];
    const float* lfe1_g  = (const float*)d_in[34];
    const float* lfe1_b  = (const float*)d_in[35];
    const float* s1_pi_w = (const float*)d_in[36];
    const float* s1_pi_b = (const float*)d_in[37];
    const float* s1_bn_g = (const float*)d_in[38];
    const float* s1_bn_b = (const float*)d_in[39];
    const float* s1_po_w = (const float*)d_in[40];
    const float* s1_po_b = (const float*)d_in[41];
    const float* lamuda  = (const float*)d_in[42];
    const float* fc_w    = (const float*)d_in[43];
    float* out = (float*)d_out;
    float* ws = (float*)d_ws;

    // workspace regions (floats)
    float* xs = ws;                    // scratch (wlfe1 weights)
    float* t  = ws + 4718592;          // (B,128,N) residual stream / xc
    float* Qr = ws + 13107200;         // 12.58M floats, phase-overlaid
    float* P2 = ws + 25690112;         // (B,128,N)
    float* P3 = ws + 29884416;         // (B,128,N)

    // stem phase (Qr head): xT0 dead before cc_ln writes curbf/curT
    unsigned short* xT0 = (unsigned short*)Qr;                 // (B,1024,160)

    // GISSA phase (Qr)
    unsigned short* curbf = (unsigned short*)Qr;               // (B,128,1024)
    unsigned short* curT  = (unsigned short*)(Qr + 2097152);   // (B,1024,128)
    unsigned short* yrbf  = (unsigned short*)(Qr + 4194304);   // (B,128,1024)
    unsigned short* yrT   = (unsigned short*)(Qr + 6291456);   // (B,1024,128)
    unsigned short* xsT   = (unsigned short*)(Qr + 8388608);   // (B,1024,160)
    unsigned short* ybufb = (unsigned short*)P2;               // (B,128,1024) bf16

    // swsa phase (Qr overlay) — R15-proven aliasing
    unsigned short* xpT   = (unsigned short*)Qr;               // cs->lfe0 (+res)
    unsigned short* v0    = (unsigned short*)(Qr + 2097152);
    unsigned short* v1    = (unsigned short*)(Qr + 4194304);   // pi1->swsa1
    unsigned short* xp3T  = (unsigned short*)(Qr + 6291456);   // swsa0(po0)->lfe1 (+res)
    unsigned short* xp2T  = (unsigned short*)(Qr + 8388608);   // lfe0->pi0, swsa0-res
    unsigned short* xp4T  = (unsigned short*)(Qr + 8388608);   // lfe1->pi1, swsa1-res
    // qT0 lives in P2 (free after GISSA; ybufb dead after apply2)
    unsigned short* qT0   = (unsigned short*)P2;               // (B,1024,128)
    // swsa1 bf16 ch-major output (mean reads it); P3 scratch is dead by then
    unsigned short* xpb   = (unsigned short*)P3;               // (B,128,1024) bf16

    // permanently-free Qr tail: packed 1x1+mlp weights + meanb + swsa stats
    unsigned short* linw  = (unsigned short*)(Qr + 11010048);  // 233472 u16
    unsigned short* wcc   = linw;                 // [128][160]
    unsigned short* wpi0  = linw + 20480;         // [256][128]
    unsigned short* wpi1  = linw + 53248;         // [128][128]
    unsigned short* wpo0  = linw + 69632;         // [128][128]
    unsigned short* wpo1  = linw + 86016;         // [128][128]
    unsigned short* w1bf  = linw + 102400;        // [512][128]
    unsigned short* w2bf  = linw + 167936;        // [128][512]
    float* meanb  = Qr + 11200000;                // 4096 floats
    float* statsM = Qr + 11204096;                // 32768 floats (B*N)
    float* statsL = Qr + 11236864;                // 32768 floats

    // small mats in P3 (dead before swsa1 writes P3)
    float* Gbuf  = P3 + 1048576;
    float* Sbuf  = P3 + 1572864;
    unsigned short* M1bf = (unsigned short*)(P3 + 1576960);
    float* c1buf = P3 + 1839104;
    unsigned short* M2bf = (unsigned short*)(P3 + 1843200);
    float* c2buf = P3 + 2105344;

    unsigned short* wssfe = (unsigned short*)P3;             // 9*144*160
    unsigned short* wcs   = (unsigned short*)(P3 + 131072);  // 9*128*160
    unsigned short* wlfe0 = (unsigned short*)(P3 + 262144);  // 9*128*128
    unsigned short* wlfe1 = (unsigned short*)xs;             // 9*128*128

    const dim3 blk(256);

    prepack_convs<<<dim3((686592 + 255) / 256), blk, 0, stream>>>(
        ssfe_w, cs_w, lfe0_w, lfe1_w, wssfe, wcs, wlfe0, wlfe1);
    prepack_lins<<<dim3((233472 + 255) / 256), blk, 0, stream>>>(
        cc_w, s0_pi_w, s1_pi_w, s0_po_w, s1_po_w, mlp_w1, mlp_w2, linw);

    // x -> bf16 px-major; xsT = cbr3(xT0, ssfe)
    cvt_xT_kernel<<<dim3(32, 16), blk, 0, stream>>>(x, xT0);
    conv3x3_ssfe_kernel<<<dim3(32, 8), dim3(512), 0, stream>>>(
        xT0, wssfe, ssfe_g, ssfe_b, xsT);

    // ---- cc 1x1 + fused LN1: t (fp32), curbf, curT ----
    cc_ln_kernel<<<dim3(32, 16), blk, 0, stream>>>(
        xsT, wcc, cc_g, cc_b, ln1_g, ln1_b, t, curbf, curT);

    // ---- GISSA via Gram trick ----
    gram_sums_kernel<<<dim3(160), blk, 0, stream>>>(curbf, Gbuf, Sbuf);
    mats1_kernel<<<dim3(512), dim3(64), 0, stream>>>(Gbuf, Sbuf, qkv_w, qkv_b, gbn_g, gbn_b, M1bf, c1buf);
    apply1_mfma_kernel<<<dim3(256), blk, 0, stream>>>(curT, M1bf, c1buf, ybufb, yrbf, yrT);
    gram_sums_kernel<<<dim3(160), blk, 0, stream>>>(yrbf, Gbuf, Sbuf);
    mats2_kernel<<<dim3(256), blk, 0, stream>>>(Gbuf, Sbuf, qkv2_w, qkv2_b, M2bf, c2buf);
    apply2_mfma_kernel<<<dim3(256), blk, 0, stream>>>(yrT, M2bf, c2buf, ybufb, t);

    mlp_mfma_kernel<<<dim3(512), blk, 0, stream>>>(t, ln2_g, ln2_b, w1bf, mlp_b1, w2bf, mlp_b2);

    // ---- xp branch, all-bf16 ----
    conv3x3_lds_kernel<160><<<dim3(32, 8), dim3(512), 0, stream>>>(
        xsT, wcs, cs_g, cs_b, nullptr, xpT, 128);
    conv3x3_pi_kernel<256><<<dim3(32, 8), dim3(512), 0, stream>>>(
        xpT, wlfe0, lfe0_g, lfe0_b, xpT, xp2T,
        wpi0, s0_pi_b, s0_bn_g, s0_bn_b, qT0, v0);
    // swsa0 + po0 (+stats): xp3T = po0(softmax(qq^T)v0) + po_b + xp2T
    swsa_po_kernel<0><<<dim3(256), dim3(512), 0, stream>>>(
        qT0, v0, wpo0, s0_po_b, xp2T, xp3T, nullptr, 1.0f, statsM, statsL);
    conv3x3_pi_kernel<128><<<dim3(32, 8), dim3(512), 0, stream>>>(
        xp3T, wlfe1, lfe1_g, lfe1_b, xp3T, xp4T,
        wpi1, s1_pi_b, s1_bn_g, s1_bn_b, nullptr, v1);
    // swsa1 + po1 (stats reuse): xpb (bf16 ch-major) = po1(...) + po_b + xp4T
    swsa_po_kernel<1><<<dim3(256), dim3(512), 0, stream>>>(
        qT0, v1, wpo1, s1_po_b, xp4T, nullptr, xpb, 0.08838834764831845f, statsM, statsL);

    mean_kernel<<<dim3(1024), blk, 0, stream>>>(t, xpb, lamuda, meanb);
    fc_kernel<<<dim3(2), blk, 0, stream>>>(meanb, fc_w, out);
}